// Round 4
// baseline (743.557 us; speedup 1.0000x reference)
//
#include <hip/hip_runtime.h>

#define NN 100000
#define NE 1600000

// bucketing for two-level CSR sort
#define BSH 9                      // 512 nodes per bucket
#define BSZ (1 << BSH)
#define NB  196                    // ceil(NN / 512)
#define CHUNK 6250                 // NE / 256

// folded-weight buffer layout (float offsets)
#define OFF_C0   0
#define OFF_D0   64
#define OFF_WPL0 80
#define OFF_BPL0 6224
#define OFF_C1   6288
#define OFF_D1   6544
#define OFF_WPL1 6608
#define OFF_BPL1 31184
#define WBUF_TOT 31248

// ---- bf16 helpers (RNE pack, cheap unpack) ----
__device__ inline unsigned pack_bf16x2(float a, float b) {
  unsigned ua = __float_as_uint(a), ub = __float_as_uint(b);
  ua += 0x7fffu + ((ua >> 16) & 1u);
  ub += 0x7fffu + ((ub >> 16) & 1u);
  return (ua >> 16) | (ub & 0xffff0000u);
}
__device__ inline float bf_lo(unsigned p) { return __uint_as_float(p << 16); }
__device__ inline float bf_hi(unsigned p) { return __uint_as_float(p & 0xffff0000u); }
__device__ inline float bf_s(unsigned short u) { return __uint_as_float(((unsigned)u) << 16); }

// ---------------- weight folding ----------------
__global__ void k_prep(const float* __restrict__ We0, const float* __restrict__ be0,
                       const float* __restrict__ Wpre0, const float* __restrict__ bpre0,
                       const float* __restrict__ Wpost0, const float* __restrict__ bpost0,
                       const float* __restrict__ Wlin0, const float* __restrict__ blin0,
                       const float* __restrict__ We1, const float* __restrict__ be1,
                       const float* __restrict__ Wpre1, const float* __restrict__ bpre1,
                       const float* __restrict__ Wpost1, const float* __restrict__ bpost1,
                       const float* __restrict__ Wlin1, const float* __restrict__ blin1,
                       float* __restrict__ wbuf) {
  int id = blockIdx.x * 256 + threadIdx.x;
  if (id >= WBUF_TOT) return;
  float a = 0.f;
  if (id < OFF_D0) {
    int j = id >> 4, f = id & 15;
    for (int t = 0; t < 16; t++) a = fmaf(We0[j*16+t], Wpre0[(32+t)*16+f], a);
  } else if (id < OFF_WPL0) {
    int f = id - OFF_D0; a = bpre0[f];
    for (int t = 0; t < 16; t++) a = fmaf(be0[t], Wpre0[(32+t)*16+f], a);
  } else if (id < OFF_BPL0) {
    int r = id - OFF_WPL0; int k = r >> 6, o = r & 63;
    for (int j = 0; j < 64; j++) a = fmaf(Wpost0[k*64+j], Wlin0[j*64+o], a);
  } else if (id < OFF_C1) {
    int o = id - OFF_BPL0; a = blin0[o];
    for (int j = 0; j < 64; j++) a = fmaf(bpost0[j], Wlin0[j*64+o], a);
  } else if (id < OFF_D1) {
    int r = id - OFF_C1; int j = r >> 6, f = r & 63;
    for (int t = 0; t < 64; t++) a = fmaf(We1[j*64+t], Wpre1[(128+t)*64+f], a);
  } else if (id < OFF_WPL1) {
    int f = id - OFF_D1; a = bpre1[f];
    for (int t = 0; t < 64; t++) a = fmaf(be1[t], Wpre1[(128+t)*64+f], a);
  } else if (id < OFF_BPL1) {
    int r = id - OFF_WPL1; int k = r >> 6, o = r & 63;
    for (int j = 0; j < 64; j++) a = fmaf(Wpost1[k*64+j], Wlin1[j*64+o], a);
  } else {
    int o = id - OFF_BPL1; a = blin1[o];
    for (int j = 0; j < 64; j++) a = fmaf(bpost1[j], Wlin1[j*64+o], a);
  }
  wbuf[id] = a;
}

// ---------------- CSR build ----------------
__global__ void k_hist(const int* __restrict__ dst, int* __restrict__ cnt) {
  int i = blockIdx.x * 256 + threadIdx.x;
  if (i < NE) atomicAdd(&cnt[dst[i]], 1);
}

__global__ void k_scan1(const int* __restrict__ deg, int* __restrict__ partial,
                        int* __restrict__ bsums) {
  __shared__ int lds[256];
  int i = blockIdx.x * 256 + threadIdx.x;
  int v = (i < NN) ? deg[i] : 0;
  lds[threadIdx.x] = v;
  __syncthreads();
  for (int off = 1; off < 256; off <<= 1) {
    int t = (threadIdx.x >= off) ? lds[threadIdx.x - off] : 0;
    __syncthreads();
    lds[threadIdx.x] += t;
    __syncthreads();
  }
  if (i < NN) partial[i] = lds[threadIdx.x];
  if (threadIdx.x == 255) bsums[blockIdx.x] = lds[255];
}

__global__ void k_scan2(const int* __restrict__ bsums, int* __restrict__ boff, int nb) {
  __shared__ int lds[512];
  int v = ((int)threadIdx.x < nb) ? bsums[threadIdx.x] : 0;
  lds[threadIdx.x] = v;
  __syncthreads();
  for (int off = 1; off < 512; off <<= 1) {
    int t = (threadIdx.x >= off) ? lds[threadIdx.x - off] : 0;
    __syncthreads();
    lds[threadIdx.x] += t;
    __syncthreads();
  }
  if ((int)threadIdx.x < nb) boff[threadIdx.x] = lds[threadIdx.x] - v;  // exclusive
}

__global__ void k_scan3(const int* __restrict__ partial, const int* __restrict__ boff,
                        const int* __restrict__ deg, int* __restrict__ rowptr,
                        int* __restrict__ fill) {
  int i = blockIdx.x * 256 + threadIdx.x;
  if (i < NN) {
    int incl = partial[i] + boff[blockIdx.x];
    rowptr[i + 1] = incl;
    fill[i] = incl - deg[i];
  }
  if (i == 0) rowptr[0] = 0;
}

__global__ void k_binit(const int* __restrict__ rowptr, int* __restrict__ gfill) {
  int b = threadIdx.x;
  if (b < NB) {
    int n0 = b << BSH;
    gfill[b] = rowptr[n0 > NN ? NN : n0];
  }
}

// pass 1: LDS-binned coarse sort
__global__ __launch_bounds__(256) void k_bin(const int* __restrict__ dst,
                                             int* __restrict__ gfill,
                                             int2* __restrict__ rec) {
  __shared__ int hcnt[NB];
  __shared__ int hbase[NB];
  const int t = threadIdx.x;
  for (int b = t; b < NB; b += 256) hcnt[b] = 0;
  __syncthreads();
  const int lo = blockIdx.x * CHUNK, hi = lo + CHUNK;
  for (int i = lo + t; i < hi; i += 256)
    atomicAdd(&hcnt[dst[i] >> BSH], 1);
  __syncthreads();
  for (int b = t; b < NB; b += 256) {
    int c = hcnt[b];
    hbase[b] = c > 0 ? atomicAdd(&gfill[b], c) : 0;
    hcnt[b] = 0;
  }
  __syncthreads();
  for (int i = lo + t; i < hi; i += 256) {
    int d = dst[i];
    int b = d >> BSH;
    int lp = atomicAdd(&hcnt[b], 1);
    rec[hbase[b] + lp] = make_int2(d, i);
  }
}

// pass 2: in-bucket scatter (L2-resident window)
__global__ __launch_bounds__(256) void k_scatter2(const int2* __restrict__ rec,
                                                  const int* __restrict__ rowptr,
                                                  int* __restrict__ perm) {
  __shared__ int lfill[BSZ];
  const int b = blockIdx.x;
  const int n0 = b << BSH;
  const int n1 = (n0 + BSZ < NN) ? n0 + BSZ : NN;
  const int t = threadIdx.x;
  for (int n = n0 + t; n < n1; n += 256) lfill[n - n0] = rowptr[n];
  __syncthreads();
  const int lo = rowptr[n0], hi = rowptr[n1];
  for (int i = lo + t; i < hi; i += 256) {
    int2 r = rec[i];
    int pos = atomicAdd(&lfill[r.x - n0], 1);
    perm[pos] = r.y;
  }
}

// pass 3: gather-permute
__global__ void k_permute(const int* __restrict__ perm, const int* __restrict__ src,
                          const float4* __restrict__ ea, int* __restrict__ col,
                          float4* __restrict__ eap) {
  int i = blockIdx.x * 256 + threadIdx.x;
  if (i < NE) {
    int eid = perm[i];
    col[i] = src[eid];
    eap[i] = ea[eid];
  }
}

// ---------------- layer 0 node pre-projection ----------------
__global__ void k_pre0(const float* __restrict__ x, const float* __restrict__ Wpre0,
                       float* __restrict__ xA0, float* __restrict__ xB0) {
  int t = blockIdx.x * 256 + threadIdx.x;   // NN*32 threads
  int node = t >> 5, k = t & 31;
  int f = k & 15;
  const float* W = Wpre0 + (k < 16 ? 0 : 256);
  const float* xr = x + (size_t)node * 16;
  float a = 0.f;
#pragma unroll
  for (int j = 0; j < 16; j++) a = fmaf(xr[j], W[j*16+f], a);
  if (k < 16) xA0[(size_t)node*16+f] = a; else xB0[(size_t)node*16+f] = a;
}

// ---------------- layer 0 aggregation ----------------
__global__ __launch_bounds__(256) void k_agg0(const float* __restrict__ x,
                                              const float* __restrict__ xA0,
                                              const float* __restrict__ xB0,
                                              const int* __restrict__ rowptr,
                                              const int* __restrict__ col,
                                              const float4* __restrict__ eap,
                                              const float* __restrict__ wbuf,
                                              float* __restrict__ vec96) {
  const int w = threadIdx.x >> 6, lane = threadIdx.x & 63;
  const int g = lane >> 4, f = lane & 15;
  const int node = blockIdx.x * 4 + w;
  const int start = rowptr[node], end = rowptr[node + 1];
  const int cnt = end - start;
  const float c0 = wbuf[OFF_C0 + f],      c1v = wbuf[OFF_C0 + 16 + f];
  const float c2v = wbuf[OFF_C0 + 32 + f], c3v = wbuf[OFF_C0 + 48 + f];
  float s = 0.f, sq = 0.f, mx = -__builtin_inff(), mn = __builtin_inff();
  for (int p = start + g; p < end; p += 4) {
    int si = col[p];
    float4 e0 = eap[p];
    float v = xB0[(size_t)si * 16 + f];
    v = fmaf(e0.x, c0, v); v = fmaf(e0.y, c1v, v);
    v = fmaf(e0.z, c2v, v); v = fmaf(e0.w, c3v, v);
    s += v; sq = fmaf(v, v, sq); mx = fmaxf(mx, v); mn = fminf(mn, v);
  }
  s  += __shfl_xor(s, 16);  s  += __shfl_xor(s, 32);
  sq += __shfl_xor(sq, 16); sq += __shfl_xor(sq, 32);
  mx = fmaxf(mx, __shfl_xor(mx, 16)); mx = fmaxf(mx, __shfl_xor(mx, 32));
  mn = fminf(mn, __shfl_xor(mn, 16)); mn = fminf(mn, __shfl_xor(mn, 32));
  const float c = xA0[(size_t)node * 16 + f] + wbuf[OFF_D0 + f];
  float sum_m, mean_m, mx_m, mn_m, std_m;
  if (cnt > 0) {
    float inv = 1.f / (float)cnt;
    float meanv = s * inv;
    sum_m = fmaf((float)cnt, c, s);
    mean_m = meanv + c;
    mx_m = mx + c; mn_m = mn + c;
    float var = fmaf(-meanv, meanv, sq * inv);
    std_m = sqrtf(fmaxf(var, 0.f) + 1e-5f);
  } else {
    sum_m = 0.f; mean_m = 0.f; mx_m = 0.f; mn_m = 0.f; std_m = sqrtf(1e-5f);
  }
  if (g == 0) {
    float* vr = vec96 + (size_t)node * 96;
    vr[f]      = x[(size_t)node * 16 + f];
    vr[16 + f] = sum_m;
    vr[32 + f] = mean_m;
    vr[48 + f] = mx_m;
    vr[64 + f] = mn_m;
    vr[80 + f] = std_m;
  }
}

// ---------------- layer 1 aggregation: bf16 xB1 rows, 2 edges/wave-iter ----------------
// xB1b: [NN][32] uints (64 bf16/row, 128B). agg320b: [NN][320] bf16.
__global__ __launch_bounds__(256) void k_agg1(const float* __restrict__ xA1,
                                              const unsigned* __restrict__ xB1b,
                                              const int* __restrict__ rowptr,
                                              const int* __restrict__ col,
                                              const float4* __restrict__ eap,
                                              const float* __restrict__ wbuf,
                                              unsigned short* __restrict__ agg320b) {
  const int w = threadIdx.x >> 6, lane = threadIdx.x & 63;
  const int half = lane >> 5, l = lane & 31;
  const int node = blockIdx.x * 4 + w;
  const int start = rowptr[node], end = rowptr[node + 1];
  const int cnt = end - start;
  const float2 c0 = *(const float2*)(wbuf + OFF_C1 + 2 * l);
  const float2 c1 = *(const float2*)(wbuf + OFF_C1 + 64 + 2 * l);
  const float2 c2 = *(const float2*)(wbuf + OFF_C1 + 128 + 2 * l);
  const float2 c3 = *(const float2*)(wbuf + OFF_C1 + 192 + 2 * l);
  float s0 = 0.f, s1 = 0.f, q0 = 0.f, q1 = 0.f;
  float mx0 = -__builtin_inff(), mx1 = -__builtin_inff();
  float mn0 = __builtin_inff(), mn1 = __builtin_inff();
  for (int p = start; p < end; p += 2) {
    int pe = p + half;
    if (pe < end) {
      int si = col[pe];
      float4 e = eap[pe];
      unsigned pk = xB1b[(size_t)si * 32 + l];
      float v0 = bf_lo(pk), v1 = bf_hi(pk);
      v0 = fmaf(e.x, c0.x, v0); v0 = fmaf(e.y, c1.x, v0);
      v0 = fmaf(e.z, c2.x, v0); v0 = fmaf(e.w, c3.x, v0);
      v1 = fmaf(e.x, c0.y, v1); v1 = fmaf(e.y, c1.y, v1);
      v1 = fmaf(e.z, c2.y, v1); v1 = fmaf(e.w, c3.y, v1);
      s0 += v0; q0 = fmaf(v0, v0, q0); mx0 = fmaxf(mx0, v0); mn0 = fminf(mn0, v0);
      s1 += v1; q1 = fmaf(v1, v1, q1); mx1 = fmaxf(mx1, v1); mn1 = fminf(mn1, v1);
    }
  }
  s0 += __shfl_xor(s0, 32); s1 += __shfl_xor(s1, 32);
  q0 += __shfl_xor(q0, 32); q1 += __shfl_xor(q1, 32);
  mx0 = fmaxf(mx0, __shfl_xor(mx0, 32)); mx1 = fmaxf(mx1, __shfl_xor(mx1, 32));
  mn0 = fminf(mn0, __shfl_xor(mn0, 32)); mn1 = fminf(mn1, __shfl_xor(mn1, 32));
  if (half == 0) {
    const float2 xa = *(const float2*)(xA1 + (size_t)node * 64 + 2 * l);
    const float2 dd = *(const float2*)(wbuf + OFF_D1 + 2 * l);
    float ca = xa.x + dd.x, cb = xa.y + dd.y;
    float sum0, mean0, maxv0, minv0, std0, sum1, mean1, maxv1, minv1, std1;
    if (cnt > 0) {
      float inv = 1.f / (float)cnt;
      float m0 = s0 * inv, m1 = s1 * inv;
      sum0 = fmaf((float)cnt, ca, s0); sum1 = fmaf((float)cnt, cb, s1);
      mean0 = m0 + ca; mean1 = m1 + cb;
      maxv0 = mx0 + ca; maxv1 = mx1 + cb;
      minv0 = mn0 + ca; minv1 = mn1 + cb;
      float var0 = fmaf(-m0, m0, q0 * inv), var1 = fmaf(-m1, m1, q1 * inv);
      std0 = sqrtf(fmaxf(var0, 0.f) + 1e-5f);
      std1 = sqrtf(fmaxf(var1, 0.f) + 1e-5f);
    } else {
      sum0 = sum1 = mean0 = mean1 = maxv0 = maxv1 = minv0 = minv1 = 0.f;
      std0 = std1 = sqrtf(1e-5f);
    }
    unsigned short* ar = agg320b + (size_t)node * 320;
    *(unsigned*)(ar + 2 * l)       = pack_bf16x2(sum0, sum1);
    *(unsigned*)(ar + 64 + 2 * l)  = pack_bf16x2(mean0, mean1);
    *(unsigned*)(ar + 128 + 2 * l) = pack_bf16x2(maxv0, maxv1);
    *(unsigned*)(ar + 192 + 2 * l) = pack_bf16x2(minv0, minv1);
    *(unsigned*)(ar + 256 + 2 * l) = pack_bf16x2(std0, std1);
  }
}

// ---------------- tiled fp32 GEMM: C[n,64] = [A1|A2][n,KT] @ B[KT,64] ----
// A2MODE: 0 = fp32, 1 = bf16 rows of width KT-K1.  OMODE: 0 = fp32 C, 1 = bf16 C.
template <int KT, int K1, bool RELU, int OMODE, int A2MODE>
__global__ __launch_bounds__(256) void k_gemm(const float* __restrict__ A1,
                                              const void* __restrict__ A2,
                                              const float* __restrict__ B,
                                              const float* __restrict__ bias,
                                              void* __restrict__ C, int n) {
  __shared__ float As[32][128];
  __shared__ float Bs[32][64];
  const int tid = threadIdx.x;
  const int tm = tid & 31, tf = tid >> 5;
  const int m0 = blockIdx.x * 128;
  float acc[4][8];
#pragma unroll
  for (int i = 0; i < 4; i++)
#pragma unroll
    for (int j = 0; j < 8; j++) acc[i][j] = 0.f;

  for (int k0 = 0; k0 < KT; k0 += 32) {
    {
      int ml = tid & 127;
      int m = m0 + ml;
      int qh = tid >> 7;
      if (m < n) {
#pragma unroll
        for (int q = 0; q < 4; q++) {
          int kk = qh * 16 + q * 4;
          int kg = k0 + kk;
          float4 v;
          if (kg < K1) {
            v = *(const float4*)(A1 + (size_t)m * K1 + kg);
          } else if (A2MODE == 0) {
            v = *(const float4*)((const float*)A2 + (size_t)m * (KT - K1) + (kg - K1));
          } else {
            const unsigned short* a2 = (const unsigned short*)A2;
            ushort4 uv = *(const ushort4*)(a2 + (size_t)m * (KT - K1) + (kg - K1));
            v.x = bf_s(uv.x); v.y = bf_s(uv.y); v.z = bf_s(uv.z); v.w = bf_s(uv.w);
          }
          As[kk + 0][ml] = v.x; As[kk + 1][ml] = v.y;
          As[kk + 2][ml] = v.z; As[kk + 3][ml] = v.w;
        }
      } else {
#pragma unroll
        for (int q = 0; q < 4; q++) {
          int kk = qh * 16 + q * 4;
          As[kk][ml] = 0.f; As[kk + 1][ml] = 0.f; As[kk + 2][ml] = 0.f; As[kk + 3][ml] = 0.f;
        }
      }
    }
    {
      int kb = tid >> 3;
      int fb = (tid & 7) * 8;
      const float4* br = (const float4*)(B + (size_t)(k0 + kb) * 64 + fb);
      float4 b0 = br[0], b1 = br[1];
      *(float4*)&Bs[kb][fb] = b0;
      *(float4*)&Bs[kb][fb + 4] = b1;
    }
    __syncthreads();
#pragma unroll 8
    for (int k = 0; k < 32; k++) {
      float av[4], bv[8];
      *(float4*)&av[0] = *(const float4*)&As[k][tm * 4];
      *(float4*)&bv[0] = *(const float4*)&Bs[k][tf * 8];
      *(float4*)&bv[4] = *(const float4*)&Bs[k][tf * 8 + 4];
#pragma unroll
      for (int i = 0; i < 4; i++)
#pragma unroll
        for (int j = 0; j < 8; j++) acc[i][j] = fmaf(av[i], bv[j], acc[i][j]);
    }
    __syncthreads();
  }
  float bb[8];
#pragma unroll
  for (int j = 0; j < 8; j++) bb[j] = bias ? bias[tf * 8 + j] : 0.f;
#pragma unroll
  for (int i = 0; i < 4; i++) {
    int m = m0 + tm * 4 + i;
    if (m < n) {
      float vv[8];
#pragma unroll
      for (int j = 0; j < 8; j++) {
        float v = acc[i][j] + bb[j];
        vv[j] = RELU ? fmaxf(v, 0.f) : v;
      }
      if (OMODE == 0) {
        float4* cp = (float4*)((float*)C + (size_t)m * 64 + tf * 8);
        cp[0] = make_float4(vv[0], vv[1], vv[2], vv[3]);
        cp[1] = make_float4(vv[4], vv[5], vv[6], vv[7]);
      } else {
        uint4 pk;
        pk.x = pack_bf16x2(vv[0], vv[1]); pk.y = pack_bf16x2(vv[2], vv[3]);
        pk.z = pack_bf16x2(vv[4], vv[5]); pk.w = pack_bf16x2(vv[6], vv[7]);
        *(uint4*)((unsigned short*)C + (size_t)m * 64 + tf * 8) = pk;
      }
    }
  }
}

// ---------------- GCN prep: hgs = (h2 @ Wg) * dinv ----------------
__global__ void k_gcnprep(const float* __restrict__ h2, const float* __restrict__ Wg,
                          const int* __restrict__ rowptr,
                          float* __restrict__ hgs, float* __restrict__ dinv) {
  int t = blockIdx.x * 256 + threadIdx.x;   // NN*16 threads
  int node = t >> 4, f = t & 15;
  const float* hr = h2 + (size_t)node * 64;
  float a = 0.f;
#pragma unroll
  for (int j = 0; j < 64; j++) a = fmaf(hr[j], Wg[j * 16 + f], a);
  int dg = rowptr[node + 1] - rowptr[node] + 1;  // +1 self loop
  float dv = 1.0f / sqrtf((float)dg);
  hgs[(size_t)node * 16 + f] = a * dv;
  if (f == 0) dinv[node] = dv;
}

// ---------------- GCN aggregate + MLP head ----------------
__global__ __launch_bounds__(256) void k_head(const float* __restrict__ x,
                                              const float* __restrict__ hgs,
                                              const float* __restrict__ dinv,
                                              const int* __restrict__ rowptr,
                                              const int* __restrict__ col,
                                              const float* __restrict__ bg,
                                              const float* __restrict__ Wh1,
                                              const float* __restrict__ bh1,
                                              const float* __restrict__ Wh2,
                                              const float* __restrict__ bh2,
                                              float* __restrict__ out) {
  __shared__ float zb[4][32];
  __shared__ float o1b[4][10];
  const int w = threadIdx.x >> 6, lane = threadIdx.x & 63;
  const int g = lane >> 4, f = lane & 15;
  const int node = blockIdx.x * 4 + w;
  const int start = rowptr[node], end = rowptr[node + 1];
  float s = 0.f;
  for (int p = start + g; p < end; p += 4) {
    int si = col[p];
    s += hgs[(size_t)si * 16 + f];
  }
  s += __shfl_xor(s, 16); s += __shfl_xor(s, 32);
  if (g == 0) {
    float gout = (s + hgs[(size_t)node * 16 + f]) * dinv[node] + bg[f];
    zb[w][f] = gout;
    zb[w][16 + f] = x[(size_t)node * 16 + f];
  }
  __syncthreads();
  if (lane < 10) {
    float a = bh1[lane];
#pragma unroll
    for (int k = 0; k < 32; k++) a = fmaf(zb[w][k], Wh1[k * 10 + lane], a);
    o1b[w][lane] = fmaxf(a, 0.f);
  }
  __syncthreads();
  if (lane < 10) {
    float a = bh2[lane];
#pragma unroll
    for (int j = 0; j < 10; j++) a = fmaf(o1b[w][j], Wh2[j * 10 + lane], a);
    out[(size_t)node * 10 + lane] = a;
  }
}

// ---------------- launcher ----------------
extern "C" void kernel_launch(void* const* d_in, const int* in_sizes, int n_in,
                              void* d_out, int out_size, void* d_ws, size_t ws_size,
                              hipStream_t stream) {
  const float* x      = (const float*)d_in[0];
  const int*   ei     = (const int*)d_in[1];
  const float* eattr  = (const float*)d_in[2];
  const float* We0    = (const float*)d_in[3];
  const float* be0    = (const float*)d_in[4];
  const float* Wpre0  = (const float*)d_in[5];
  const float* bpre0  = (const float*)d_in[6];
  const float* Wpost0 = (const float*)d_in[7];
  const float* bpost0 = (const float*)d_in[8];
  const float* Wlin0  = (const float*)d_in[9];
  const float* blin0  = (const float*)d_in[10];
  const float* We1    = (const float*)d_in[11];
  const float* be1    = (const float*)d_in[12];
  const float* Wpre1  = (const float*)d_in[13];
  const float* bpre1  = (const float*)d_in[14];
  const float* Wpost1 = (const float*)d_in[15];
  const float* bpost1 = (const float*)d_in[16];
  const float* Wlin1  = (const float*)d_in[17];
  const float* blin1  = (const float*)d_in[18];
  const float* Wg     = (const float*)d_in[19];
  const float* bg     = (const float*)d_in[20];
  const float* Wh1    = (const float*)d_in[21];
  const float* bh1    = (const float*)d_in[22];
  const float* Wh2    = (const float*)d_in[23];
  const float* bh2    = (const float*)d_in[24];
  const int* srcI = ei;
  const int* dstI = ei + NE;
  float* out = (float*)d_out;

  char* base = (char*)d_ws;
  size_t off = 0;
  auto take = [&](size_t bytes) -> char* {
    char* p = base + off;
    off += (bytes + 255) & ~(size_t)255;
    return p;
  };
  int* cnt     = (int*)take((size_t)NN * 4);
  int* rowptr  = (int*)take((size_t)(NN + 1) * 4);
  int* fill    = (int*)take((size_t)NN * 4);
  int* partial = (int*)take((size_t)NN * 4);
  int* bsums   = (int*)take(512 * 4);
  int* boff    = (int*)take(512 * 4);
  int* gfill   = (int*)take(512 * 4);
  int* col     = (int*)take((size_t)NE * 4);
  float4* eap  = (float4*)take((size_t)NE * 16);     // 25.6MB; aliased by h2 later
  float* h2    = (float*)eap;                        // h2 [NN,64], alive after eap dies
  float* wbuf  = (float*)take((size_t)WBUF_TOT * 4);
  float* h     = (float*)take((size_t)NN * 64 * 4);
  int*   perm  = (int*)h;                            // perm [NE] = 6.4MB, dead before h written
  float* xA1   = (float*)take((size_t)NN * 64 * 4);
  int2*  rec   = (int2*)take((size_t)NE * 8);        // 12.8MB
  unsigned* xB1b = (unsigned*)rec;                   // xB1 bf16 [NN,64] = 12.8MB, after rec dies
  // region Z (128MB): vec96/xA0/xB0 early -> agg320b (64MB) mid -> hgs/dinv late
  char* Z = take((size_t)NN * 320 * 4);
  unsigned short* agg320b = (unsigned short*)Z;
  float* vec96  = (float*)Z;
  float* xA0    = (float*)(Z + (size_t)NN * 96 * 4);
  float* xB0    = (float*)(Z + (size_t)NN * 96 * 4 + (size_t)NN * 16 * 4);
  float* hgs    = (float*)Z;
  float* dinv   = (float*)(Z + (size_t)NN * 16 * 4);

  hipMemsetAsync(cnt, 0, (size_t)NN * 4, stream);
  k_prep<<<(WBUF_TOT + 255) / 256, 256, 0, stream>>>(
      We0, be0, Wpre0, bpre0, Wpost0, bpost0, Wlin0, blin0,
      We1, be1, Wpre1, bpre1, Wpost1, bpost1, Wlin1, blin1, wbuf);
  k_hist<<<(NE + 255) / 256, 256, 0, stream>>>(dstI, cnt);
  k_scan1<<<391, 256, 0, stream>>>(cnt, partial, bsums);
  k_scan2<<<1, 512, 0, stream>>>(bsums, boff, 391);
  k_scan3<<<391, 256, 0, stream>>>(partial, boff, cnt, rowptr, fill);
  k_binit<<<1, 256, 0, stream>>>(rowptr, gfill);
  k_bin<<<256, 256, 0, stream>>>(dstI, gfill, rec);
  k_scatter2<<<NB, 256, 0, stream>>>(rec, rowptr, perm);
  k_permute<<<(NE + 255) / 256, 256, 0, stream>>>(perm, srcI, (const float4*)eattr,
                                                  col, eap);
  k_pre0<<<NN * 32 / 256, 256, 0, stream>>>(x, Wpre0, xA0, xB0);
  k_agg0<<<NN / 4, 256, 0, stream>>>(x, xA0, xB0, rowptr, col, eap, wbuf, vec96);
  k_gemm<96, 96, true, 0, 0><<<(NN + 127) / 128, 256, 0, stream>>>(
      vec96, vec96, wbuf + OFF_WPL0, wbuf + OFF_BPL0, h, NN);
  k_gemm<64, 64, false, 0, 0><<<(NN + 127) / 128, 256, 0, stream>>>(
      h, h, Wpre1, nullptr, xA1, NN);
  k_gemm<64, 64, false, 1, 0><<<(NN + 127) / 128, 256, 0, stream>>>(
      h, h, Wpre1 + 64 * 64, nullptr, xB1b, NN);       // bf16 out, overlays rec
  k_agg1<<<NN / 4, 256, 0, stream>>>(xA1, xB1b, rowptr, col, eap, wbuf, agg320b);
  k_gemm<384, 64, true, 0, 1><<<(NN + 127) / 128, 256, 0, stream>>>(
      h, agg320b, wbuf + OFF_WPL1, wbuf + OFF_BPL1, h2, NN);
  k_gcnprep<<<NN * 16 / 256, 256, 0, stream>>>(h2, Wg, rowptr, hgs, dinv);
  k_head<<<NN / 4, 256, 0, stream>>>(x, hgs, dinv, rowptr, col, bg, Wh1, bh1,
                                     Wh2, bh2, out);
}

// Round 5
// 718.562 us; speedup vs baseline: 1.0348x; 1.0348x over previous
//
#include <hip/hip_runtime.h>

#define NN 100000
#define NE 1600000

// bucketing for two-level CSR sort
#define BSH 9                      // 512 nodes per bucket
#define BSZ (1 << BSH)
#define NB  196                    // ceil(NN / 512)
#define CHUNK 6250                 // NE / 256

// folded-weight buffer layout (float offsets)
#define OFF_C0   0
#define OFF_D0   64
#define OFF_WPL0 80
#define OFF_BPL0 6224
#define OFF_C1   6288
#define OFF_D1   6544
#define OFF_WPL1 6608
#define OFF_BPL1 31184
#define WBUF_TOT 31248

// ---- bf16 helpers (RNE pack, cheap unpack) ----
__device__ inline unsigned pack_bf16x2(float a, float b) {
  unsigned ua = __float_as_uint(a), ub = __float_as_uint(b);
  ua += 0x7fffu + ((ua >> 16) & 1u);
  ub += 0x7fffu + ((ub >> 16) & 1u);
  return (ua >> 16) | (ub & 0xffff0000u);
}
__device__ inline unsigned short pack_bf16(float a) {
  unsigned ua = __float_as_uint(a);
  ua += 0x7fffu + ((ua >> 16) & 1u);
  return (unsigned short)(ua >> 16);
}
__device__ inline float bf_s(unsigned short u) { return __uint_as_float(((unsigned)u) << 16); }

// ---------------- weight folding ----------------
__global__ void k_prep(const float* __restrict__ We0, const float* __restrict__ be0,
                       const float* __restrict__ Wpre0, const float* __restrict__ bpre0,
                       const float* __restrict__ Wpost0, const float* __restrict__ bpost0,
                       const float* __restrict__ Wlin0, const float* __restrict__ blin0,
                       const float* __restrict__ We1, const float* __restrict__ be1,
                       const float* __restrict__ Wpre1, const float* __restrict__ bpre1,
                       const float* __restrict__ Wpost1, const float* __restrict__ bpost1,
                       const float* __restrict__ Wlin1, const float* __restrict__ blin1,
                       float* __restrict__ wbuf) {
  int id = blockIdx.x * 256 + threadIdx.x;
  if (id >= WBUF_TOT) return;
  float a = 0.f;
  if (id < OFF_D0) {
    int j = id >> 4, f = id & 15;
    for (int t = 0; t < 16; t++) a = fmaf(We0[j*16+t], Wpre0[(32+t)*16+f], a);
  } else if (id < OFF_WPL0) {
    int f = id - OFF_D0; a = bpre0[f];
    for (int t = 0; t < 16; t++) a = fmaf(be0[t], Wpre0[(32+t)*16+f], a);
  } else if (id < OFF_BPL0) {
    int r = id - OFF_WPL0; int k = r >> 6, o = r & 63;
    for (int j = 0; j < 64; j++) a = fmaf(Wpost0[k*64+j], Wlin0[j*64+o], a);
  } else if (id < OFF_C1) {
    int o = id - OFF_BPL0; a = blin0[o];
    for (int j = 0; j < 64; j++) a = fmaf(bpost0[j], Wlin0[j*64+o], a);
  } else if (id < OFF_D1) {
    int r = id - OFF_C1; int j = r >> 6, f = r & 63;
    for (int t = 0; t < 64; t++) a = fmaf(We1[j*64+t], Wpre1[(128+t)*64+f], a);
  } else if (id < OFF_WPL1) {
    int f = id - OFF_D1; a = bpre1[f];
    for (int t = 0; t < 64; t++) a = fmaf(be1[t], Wpre1[(128+t)*64+f], a);
  } else if (id < OFF_BPL1) {
    int r = id - OFF_WPL1; int k = r >> 6, o = r & 63;
    for (int j = 0; j < 64; j++) a = fmaf(Wpost1[k*64+j], Wlin1[j*64+o], a);
  } else {
    int o = id - OFF_BPL1; a = blin1[o];
    for (int j = 0; j < 64; j++) a = fmaf(bpost1[j], Wlin1[j*64+o], a);
  }
  wbuf[id] = a;
}

// ---------------- CSR build ----------------
__global__ void k_hist(const int* __restrict__ dst, int* __restrict__ cnt) {
  int i = blockIdx.x * 256 + threadIdx.x;
  if (i < NE) atomicAdd(&cnt[dst[i]], 1);
}

__global__ void k_scan1(const int* __restrict__ deg, int* __restrict__ partial,
                        int* __restrict__ bsums) {
  __shared__ int lds[256];
  int i = blockIdx.x * 256 + threadIdx.x;
  int v = (i < NN) ? deg[i] : 0;
  lds[threadIdx.x] = v;
  __syncthreads();
  for (int off = 1; off < 256; off <<= 1) {
    int t = (threadIdx.x >= off) ? lds[threadIdx.x - off] : 0;
    __syncthreads();
    lds[threadIdx.x] += t;
    __syncthreads();
  }
  if (i < NN) partial[i] = lds[threadIdx.x];
  if (threadIdx.x == 255) bsums[blockIdx.x] = lds[255];
}

__global__ void k_scan2(const int* __restrict__ bsums, int* __restrict__ boff, int nb) {
  __shared__ int lds[512];
  int v = ((int)threadIdx.x < nb) ? bsums[threadIdx.x] : 0;
  lds[threadIdx.x] = v;
  __syncthreads();
  for (int off = 1; off < 512; off <<= 1) {
    int t = (threadIdx.x >= off) ? lds[threadIdx.x - off] : 0;
    __syncthreads();
    lds[threadIdx.x] += t;
    __syncthreads();
  }
  if ((int)threadIdx.x < nb) boff[threadIdx.x] = lds[threadIdx.x] - v;  // exclusive
}

__global__ void k_scan3(const int* __restrict__ partial, const int* __restrict__ boff,
                        const int* __restrict__ deg, int* __restrict__ rowptr,
                        int* __restrict__ fill) {
  int i = blockIdx.x * 256 + threadIdx.x;
  if (i < NN) {
    int incl = partial[i] + boff[blockIdx.x];
    rowptr[i + 1] = incl;
    fill[i] = incl - deg[i];
  }
  if (i == 0) rowptr[0] = 0;
}

__global__ void k_binit(const int* __restrict__ rowptr, int* __restrict__ gfill) {
  int b = threadIdx.x;
  if (b < NB) {
    int n0 = b << BSH;
    gfill[b] = rowptr[n0 > NN ? NN : n0];
  }
}

// pass 1: LDS-binned coarse sort
__global__ __launch_bounds__(256) void k_bin(const int* __restrict__ dst,
                                             int* __restrict__ gfill,
                                             int2* __restrict__ rec) {
  __shared__ int hcnt[NB];
  __shared__ int hbase[NB];
  const int t = threadIdx.x;
  for (int b = t; b < NB; b += 256) hcnt[b] = 0;
  __syncthreads();
  const int lo = blockIdx.x * CHUNK, hi = lo + CHUNK;
  for (int i = lo + t; i < hi; i += 256)
    atomicAdd(&hcnt[dst[i] >> BSH], 1);
  __syncthreads();
  for (int b = t; b < NB; b += 256) {
    int c = hcnt[b];
    hbase[b] = c > 0 ? atomicAdd(&gfill[b], c) : 0;
    hcnt[b] = 0;
  }
  __syncthreads();
  for (int i = lo + t; i < hi; i += 256) {
    int d = dst[i];
    int b = d >> BSH;
    int lp = atomicAdd(&hcnt[b], 1);
    rec[hbase[b] + lp] = make_int2(d, i);
  }
}

// pass 2: in-bucket scatter (L2-resident window)
__global__ __launch_bounds__(256) void k_scatter2(const int2* __restrict__ rec,
                                                  const int* __restrict__ rowptr,
                                                  int* __restrict__ perm) {
  __shared__ int lfill[BSZ];
  const int b = blockIdx.x;
  const int n0 = b << BSH;
  const int n1 = (n0 + BSZ < NN) ? n0 + BSZ : NN;
  const int t = threadIdx.x;
  for (int n = n0 + t; n < n1; n += 256) lfill[n - n0] = rowptr[n];
  __syncthreads();
  const int lo = rowptr[n0], hi = rowptr[n1];
  for (int i = lo + t; i < hi; i += 256) {
    int2 r = rec[i];
    int pos = atomicAdd(&lfill[r.x - n0], 1);
    perm[pos] = r.y;
  }
}

// pass 3: gather-permute
__global__ void k_permute(const int* __restrict__ perm, const int* __restrict__ src,
                          const float4* __restrict__ ea, int* __restrict__ col,
                          float4* __restrict__ eap) {
  int i = blockIdx.x * 256 + threadIdx.x;
  if (i < NE) {
    int eid = perm[i];
    col[i] = src[eid];
    eap[i] = ea[eid];
  }
}

// ---------------- layer 0 node pre-projection ----------------
__global__ void k_pre0(const float* __restrict__ x, const float* __restrict__ Wpre0,
                       float* __restrict__ xA0, float* __restrict__ xB0) {
  int t = blockIdx.x * 256 + threadIdx.x;   // NN*32 threads
  int node = t >> 5, k = t & 31;
  int f = k & 15;
  const float* W = Wpre0 + (k < 16 ? 0 : 256);
  const float* xr = x + (size_t)node * 16;
  float a = 0.f;
#pragma unroll
  for (int j = 0; j < 16; j++) a = fmaf(xr[j], W[j*16+f], a);
  if (k < 16) xA0[(size_t)node*16+f] = a; else xB0[(size_t)node*16+f] = a;
}

// ---------------- layer 0 aggregation ----------------
__global__ __launch_bounds__(256) void k_agg0(const float* __restrict__ x,
                                              const float* __restrict__ xA0,
                                              const float* __restrict__ xB0,
                                              const int* __restrict__ rowptr,
                                              const int* __restrict__ col,
                                              const float4* __restrict__ eap,
                                              const float* __restrict__ wbuf,
                                              float* __restrict__ vec96) {
  const int w = threadIdx.x >> 6, lane = threadIdx.x & 63;
  const int g = lane >> 4, f = lane & 15;
  const int node = blockIdx.x * 4 + w;
  const int start = rowptr[node], end = rowptr[node + 1];
  const int cnt = end - start;
  const float c0 = wbuf[OFF_C0 + f],      c1v = wbuf[OFF_C0 + 16 + f];
  const float c2v = wbuf[OFF_C0 + 32 + f], c3v = wbuf[OFF_C0 + 48 + f];
  float s = 0.f, sq = 0.f, mx = -__builtin_inff(), mn = __builtin_inff();
  for (int p = start + g; p < end; p += 4) {
    int si = col[p];
    float4 e0 = eap[p];
    float v = xB0[(size_t)si * 16 + f];
    v = fmaf(e0.x, c0, v); v = fmaf(e0.y, c1v, v);
    v = fmaf(e0.z, c2v, v); v = fmaf(e0.w, c3v, v);
    s += v; sq = fmaf(v, v, sq); mx = fmaxf(mx, v); mn = fminf(mn, v);
  }
  s  += __shfl_xor(s, 16);  s  += __shfl_xor(s, 32);
  sq += __shfl_xor(sq, 16); sq += __shfl_xor(sq, 32);
  mx = fmaxf(mx, __shfl_xor(mx, 16)); mx = fmaxf(mx, __shfl_xor(mx, 32));
  mn = fminf(mn, __shfl_xor(mn, 16)); mn = fminf(mn, __shfl_xor(mn, 32));
  const float c = xA0[(size_t)node * 16 + f] + wbuf[OFF_D0 + f];
  float sum_m, mean_m, mx_m, mn_m, std_m;
  if (cnt > 0) {
    float inv = 1.f / (float)cnt;
    float meanv = s * inv;
    sum_m = fmaf((float)cnt, c, s);
    mean_m = meanv + c;
    mx_m = mx + c; mn_m = mn + c;
    float var = fmaf(-meanv, meanv, sq * inv);
    std_m = sqrtf(fmaxf(var, 0.f) + 1e-5f);
  } else {
    sum_m = 0.f; mean_m = 0.f; mx_m = 0.f; mn_m = 0.f; std_m = sqrtf(1e-5f);
  }
  if (g == 0) {
    float* vr = vec96 + (size_t)node * 96;
    vr[f]      = x[(size_t)node * 16 + f];
    vr[16 + f] = sum_m;
    vr[32 + f] = mean_m;
    vr[48 + f] = mx_m;
    vr[64 + f] = mn_m;
    vr[80 + f] = std_m;
  }
}

// ---------------- layer 1 aggregation: lane-per-feature, 4-edge unroll ----------------
// xB1b: [NN][64] bf16 (128B rows). agg320b: [NN][320] bf16.
// col/eap addresses are wave-uniform -> scalar loads; xB1b is one coalesced
// 128B ushort load per edge; no cross-lane reduction needed.
__global__ __launch_bounds__(256) void k_agg1(const float* __restrict__ xA1,
                                              const unsigned short* __restrict__ xB1b,
                                              const int* __restrict__ rowptr,
                                              const int* __restrict__ col,
                                              const float4* __restrict__ eap,
                                              const float* __restrict__ wbuf,
                                              unsigned short* __restrict__ agg320b) {
  const int w = threadIdx.x >> 6, f = threadIdx.x & 63;
  const int node = blockIdx.x * 4 + w;
  const int start = rowptr[node], end = rowptr[node + 1];
  const int cnt = end - start;
  const float c0 = wbuf[OFF_C1 + f],       c1v = wbuf[OFF_C1 + 64 + f];
  const float c2v = wbuf[OFF_C1 + 128 + f], c3v = wbuf[OFF_C1 + 192 + f];
  float s = 0.f, sq = 0.f, mx = -__builtin_inff(), mn = __builtin_inff();
  int p = start;
  for (; p + 3 < end; p += 4) {
    int i0 = col[p], i1 = col[p + 1], i2 = col[p + 2], i3 = col[p + 3];
    float4 e0 = eap[p], e1 = eap[p + 1], e2 = eap[p + 2], e3 = eap[p + 3];
    float v0 = bf_s(xB1b[(size_t)i0 * 64 + f]);
    float v1 = bf_s(xB1b[(size_t)i1 * 64 + f]);
    float v2 = bf_s(xB1b[(size_t)i2 * 64 + f]);
    float v3 = bf_s(xB1b[(size_t)i3 * 64 + f]);
    v0 = fmaf(e0.x, c0, v0); v0 = fmaf(e0.y, c1v, v0);
    v0 = fmaf(e0.z, c2v, v0); v0 = fmaf(e0.w, c3v, v0);
    v1 = fmaf(e1.x, c0, v1); v1 = fmaf(e1.y, c1v, v1);
    v1 = fmaf(e1.z, c2v, v1); v1 = fmaf(e1.w, c3v, v1);
    v2 = fmaf(e2.x, c0, v2); v2 = fmaf(e2.y, c1v, v2);
    v2 = fmaf(e2.z, c2v, v2); v2 = fmaf(e2.w, c3v, v2);
    v3 = fmaf(e3.x, c0, v3); v3 = fmaf(e3.y, c1v, v3);
    v3 = fmaf(e3.z, c2v, v3); v3 = fmaf(e3.w, c3v, v3);
    s += v0; sq = fmaf(v0, v0, sq);
    s += v1; sq = fmaf(v1, v1, sq);
    s += v2; sq = fmaf(v2, v2, sq);
    s += v3; sq = fmaf(v3, v3, sq);
    mx = fmaxf(mx, fmaxf(fmaxf(v0, v1), fmaxf(v2, v3)));
    mn = fminf(mn, fminf(fminf(v0, v1), fminf(v2, v3)));
  }
  for (; p < end; p++) {
    int i0 = col[p];
    float4 e0 = eap[p];
    float v0 = bf_s(xB1b[(size_t)i0 * 64 + f]);
    v0 = fmaf(e0.x, c0, v0); v0 = fmaf(e0.y, c1v, v0);
    v0 = fmaf(e0.z, c2v, v0); v0 = fmaf(e0.w, c3v, v0);
    s += v0; sq = fmaf(v0, v0, sq); mx = fmaxf(mx, v0); mn = fminf(mn, v0);
  }
  const float c = xA1[(size_t)node * 64 + f] + wbuf[OFF_D1 + f];
  float sum_m, mean_m, mx_m, mn_m, std_m;
  if (cnt > 0) {
    float inv = 1.f / (float)cnt;
    float meanv = s * inv;
    sum_m = fmaf((float)cnt, c, s);
    mean_m = meanv + c;
    mx_m = mx + c; mn_m = mn + c;
    float var = fmaf(-meanv, meanv, sq * inv);
    std_m = sqrtf(fmaxf(var, 0.f) + 1e-5f);
  } else {
    sum_m = 0.f; mean_m = 0.f; mx_m = 0.f; mn_m = 0.f; std_m = sqrtf(1e-5f);
  }
  unsigned short* ar = agg320b + (size_t)node * 320;
  ar[f]       = pack_bf16(sum_m);
  ar[64 + f]  = pack_bf16(mean_m);
  ar[128 + f] = pack_bf16(mx_m);
  ar[192 + f] = pack_bf16(mn_m);
  ar[256 + f] = pack_bf16(std_m);
}

// ---------------- tiled fp32 GEMM: C[n,64] = [A1|A2][n,KT] @ B[KT,64] ----
// A2MODE: 0 = fp32, 1 = bf16 rows of width KT-K1.  OMODE: 0 = fp32 C, 1 = bf16 C.
template <int KT, int K1, bool RELU, int OMODE, int A2MODE>
__global__ __launch_bounds__(256) void k_gemm(const float* __restrict__ A1,
                                              const void* __restrict__ A2,
                                              const float* __restrict__ B,
                                              const float* __restrict__ bias,
                                              void* __restrict__ C, int n) {
  __shared__ float As[32][128];
  __shared__ float Bs[32][64];
  const int tid = threadIdx.x;
  const int tm = tid & 31, tf = tid >> 5;
  const int m0 = blockIdx.x * 128;
  float acc[4][8];
#pragma unroll
  for (int i = 0; i < 4; i++)
#pragma unroll
    for (int j = 0; j < 8; j++) acc[i][j] = 0.f;

  for (int k0 = 0; k0 < KT; k0 += 32) {
    {
      int ml = tid & 127;
      int m = m0 + ml;
      int qh = tid >> 7;
      if (m < n) {
#pragma unroll
        for (int q = 0; q < 4; q++) {
          int kk = qh * 16 + q * 4;
          int kg = k0 + kk;
          float4 v;
          if (kg < K1) {
            v = *(const float4*)(A1 + (size_t)m * K1 + kg);
          } else if (A2MODE == 0) {
            v = *(const float4*)((const float*)A2 + (size_t)m * (KT - K1) + (kg - K1));
          } else {
            const unsigned short* a2 = (const unsigned short*)A2;
            ushort4 uv = *(const ushort4*)(a2 + (size_t)m * (KT - K1) + (kg - K1));
            v.x = bf_s(uv.x); v.y = bf_s(uv.y); v.z = bf_s(uv.z); v.w = bf_s(uv.w);
          }
          As[kk + 0][ml] = v.x; As[kk + 1][ml] = v.y;
          As[kk + 2][ml] = v.z; As[kk + 3][ml] = v.w;
        }
      } else {
#pragma unroll
        for (int q = 0; q < 4; q++) {
          int kk = qh * 16 + q * 4;
          As[kk][ml] = 0.f; As[kk + 1][ml] = 0.f; As[kk + 2][ml] = 0.f; As[kk + 3][ml] = 0.f;
        }
      }
    }
    {
      int kb = tid >> 3;
      int fb = (tid & 7) * 8;
      const float4* br = (const float4*)(B + (size_t)(k0 + kb) * 64 + fb);
      float4 b0 = br[0], b1 = br[1];
      *(float4*)&Bs[kb][fb] = b0;
      *(float4*)&Bs[kb][fb + 4] = b1;
    }
    __syncthreads();
#pragma unroll 8
    for (int k = 0; k < 32; k++) {
      float av[4], bv[8];
      *(float4*)&av[0] = *(const float4*)&As[k][tm * 4];
      *(float4*)&bv[0] = *(const float4*)&Bs[k][tf * 8];
      *(float4*)&bv[4] = *(const float4*)&Bs[k][tf * 8 + 4];
#pragma unroll
      for (int i = 0; i < 4; i++)
#pragma unroll
        for (int j = 0; j < 8; j++) acc[i][j] = fmaf(av[i], bv[j], acc[i][j]);
    }
    __syncthreads();
  }
  float bb[8];
#pragma unroll
  for (int j = 0; j < 8; j++) bb[j] = bias ? bias[tf * 8 + j] : 0.f;
#pragma unroll
  for (int i = 0; i < 4; i++) {
    int m = m0 + tm * 4 + i;
    if (m < n) {
      float vv[8];
#pragma unroll
      for (int j = 0; j < 8; j++) {
        float v = acc[i][j] + bb[j];
        vv[j] = RELU ? fmaxf(v, 0.f) : v;
      }
      if (OMODE == 0) {
        float4* cp = (float4*)((float*)C + (size_t)m * 64 + tf * 8);
        cp[0] = make_float4(vv[0], vv[1], vv[2], vv[3]);
        cp[1] = make_float4(vv[4], vv[5], vv[6], vv[7]);
      } else {
        uint4 pk;
        pk.x = pack_bf16x2(vv[0], vv[1]); pk.y = pack_bf16x2(vv[2], vv[3]);
        pk.z = pack_bf16x2(vv[4], vv[5]); pk.w = pack_bf16x2(vv[6], vv[7]);
        *(uint4*)((unsigned short*)C + (size_t)m * 64 + tf * 8) = pk;
      }
    }
  }
}

// ---------------- GCN prep: hgs = (h2 @ Wg) * dinv ----------------
__global__ void k_gcnprep(const float* __restrict__ h2, const float* __restrict__ Wg,
                          const int* __restrict__ rowptr,
                          float* __restrict__ hgs, float* __restrict__ dinv) {
  int t = blockIdx.x * 256 + threadIdx.x;   // NN*16 threads
  int node = t >> 4, f = t & 15;
  const float* hr = h2 + (size_t)node * 64;
  float a = 0.f;
#pragma unroll
  for (int j = 0; j < 64; j++) a = fmaf(hr[j], Wg[j * 16 + f], a);
  int dg = rowptr[node + 1] - rowptr[node] + 1;  // +1 self loop
  float dv = 1.0f / sqrtf((float)dg);
  hgs[(size_t)node * 16 + f] = a * dv;
  if (f == 0) dinv[node] = dv;
}

// ---------------- GCN aggregate + MLP head ----------------
__global__ __launch_bounds__(256) void k_head(const float* __restrict__ x,
                                              const float* __restrict__ hgs,
                                              const float* __restrict__ dinv,
                                              const int* __restrict__ rowptr,
                                              const int* __restrict__ col,
                                              const float* __restrict__ bg,
                                              const float* __restrict__ Wh1,
                                              const float* __restrict__ bh1,
                                              const float* __restrict__ Wh2,
                                              const float* __restrict__ bh2,
                                              float* __restrict__ out) {
  __shared__ float zb[4][32];
  __shared__ float o1b[4][10];
  const int w = threadIdx.x >> 6, lane = threadIdx.x & 63;
  const int g = lane >> 4, f = lane & 15;
  const int node = blockIdx.x * 4 + w;
  const int start = rowptr[node], end = rowptr[node + 1];
  float s = 0.f;
  for (int p = start + g; p < end; p += 4) {
    int si = col[p];
    s += hgs[(size_t)si * 16 + f];
  }
  s += __shfl_xor(s, 16); s += __shfl_xor(s, 32);
  if (g == 0) {
    float gout = (s + hgs[(size_t)node * 16 + f]) * dinv[node] + bg[f];
    zb[w][f] = gout;
    zb[w][16 + f] = x[(size_t)node * 16 + f];
  }
  __syncthreads();
  if (lane < 10) {
    float a = bh1[lane];
#pragma unroll
    for (int k = 0; k < 32; k++) a = fmaf(zb[w][k], Wh1[k * 10 + lane], a);
    o1b[w][lane] = fmaxf(a, 0.f);
  }
  __syncthreads();
  if (lane < 10) {
    float a = bh2[lane];
#pragma unroll
    for (int j = 0; j < 10; j++) a = fmaf(o1b[w][j], Wh2[j * 10 + lane], a);
    out[(size_t)node * 10 + lane] = a;
  }
}

// ---------------- launcher ----------------
extern "C" void kernel_launch(void* const* d_in, const int* in_sizes, int n_in,
                              void* d_out, int out_size, void* d_ws, size_t ws_size,
                              hipStream_t stream) {
  const float* x      = (const float*)d_in[0];
  const int*   ei     = (const int*)d_in[1];
  const float* eattr  = (const float*)d_in[2];
  const float* We0    = (const float*)d_in[3];
  const float* be0    = (const float*)d_in[4];
  const float* Wpre0  = (const float*)d_in[5];
  const float* bpre0  = (const float*)d_in[6];
  const float* Wpost0 = (const float*)d_in[7];
  const float* bpost0 = (const float*)d_in[8];
  const float* Wlin0  = (const float*)d_in[9];
  const float* blin0  = (const float*)d_in[10];
  const float* We1    = (const float*)d_in[11];
  const float* be1    = (const float*)d_in[12];
  const float* Wpre1  = (const float*)d_in[13];
  const float* bpre1  = (const float*)d_in[14];
  const float* Wpost1 = (const float*)d_in[15];
  const float* bpost1 = (const float*)d_in[16];
  const float* Wlin1  = (const float*)d_in[17];
  const float* blin1  = (const float*)d_in[18];
  const float* Wg     = (const float*)d_in[19];
  const float* bg     = (const float*)d_in[20];
  const float* Wh1    = (const float*)d_in[21];
  const float* bh1    = (const float*)d_in[22];
  const float* Wh2    = (const float*)d_in[23];
  const float* bh2    = (const float*)d_in[24];
  const int* srcI = ei;
  const int* dstI = ei + NE;
  float* out = (float*)d_out;

  char* base = (char*)d_ws;
  size_t off = 0;
  auto take = [&](size_t bytes) -> char* {
    char* p = base + off;
    off += (bytes + 255) & ~(size_t)255;
    return p;
  };
  int* cnt     = (int*)take((size_t)NN * 4);
  int* rowptr  = (int*)take((size_t)(NN + 1) * 4);
  int* fill    = (int*)take((size_t)NN * 4);
  int* partial = (int*)take((size_t)NN * 4);
  int* bsums   = (int*)take(512 * 4);
  int* boff    = (int*)take(512 * 4);
  int* gfill   = (int*)take(512 * 4);
  int* col     = (int*)take((size_t)NE * 4);
  float4* eap  = (float4*)take((size_t)NE * 16);     // 25.6MB; aliased by h2 later
  float* h2    = (float*)eap;                        // h2 [NN,64], alive after eap dies
  float* wbuf  = (float*)take((size_t)WBUF_TOT * 4);
  float* h     = (float*)take((size_t)NN * 64 * 4);
  int*   perm  = (int*)h;                            // perm [NE] = 6.4MB, dead before h written
  float* xA1   = (float*)take((size_t)NN * 64 * 4);
  int2*  rec   = (int2*)take((size_t)NE * 8);        // 12.8MB
  unsigned short* xB1b = (unsigned short*)rec;       // xB1 bf16 [NN,64] = 12.8MB, after rec dies
  // region Z (128MB): vec96/xA0/xB0 early -> agg320b (64MB) mid -> hgs/dinv late
  char* Z = take((size_t)NN * 320 * 4);
  unsigned short* agg320b = (unsigned short*)Z;
  float* vec96  = (float*)Z;
  float* xA0    = (float*)(Z + (size_t)NN * 96 * 4);
  float* xB0    = (float*)(Z + (size_t)NN * 96 * 4 + (size_t)NN * 16 * 4);
  float* hgs    = (float*)Z;
  float* dinv   = (float*)(Z + (size_t)NN * 16 * 4);

  hipMemsetAsync(cnt, 0, (size_t)NN * 4, stream);
  k_prep<<<(WBUF_TOT + 255) / 256, 256, 0, stream>>>(
      We0, be0, Wpre0, bpre0, Wpost0, bpost0, Wlin0, blin0,
      We1, be1, Wpre1, bpre1, Wpost1, bpost1, Wlin1, blin1, wbuf);
  k_hist<<<(NE + 255) / 256, 256, 0, stream>>>(dstI, cnt);
  k_scan1<<<391, 256, 0, stream>>>(cnt, partial, bsums);
  k_scan2<<<1, 512, 0, stream>>>(bsums, boff, 391);
  k_scan3<<<391, 256, 0, stream>>>(partial, boff, cnt, rowptr, fill);
  k_binit<<<1, 256, 0, stream>>>(rowptr, gfill);
  k_bin<<<256, 256, 0, stream>>>(dstI, gfill, rec);
  k_scatter2<<<NB, 256, 0, stream>>>(rec, rowptr, perm);
  k_permute<<<(NE + 255) / 256, 256, 0, stream>>>(perm, srcI, (const float4*)eattr,
                                                  col, eap);
  k_pre0<<<NN * 32 / 256, 256, 0, stream>>>(x, Wpre0, xA0, xB0);
  k_agg0<<<NN / 4, 256, 0, stream>>>(x, xA0, xB0, rowptr, col, eap, wbuf, vec96);
  k_gemm<96, 96, true, 0, 0><<<(NN + 127) / 128, 256, 0, stream>>>(
      vec96, vec96, wbuf + OFF_WPL0, wbuf + OFF_BPL0, h, NN);
  k_gemm<64, 64, false, 0, 0><<<(NN + 127) / 128, 256, 0, stream>>>(
      h, h, Wpre1, nullptr, xA1, NN);
  k_gemm<64, 64, false, 1, 0><<<(NN + 127) / 128, 256, 0, stream>>>(
      h, h, Wpre1 + 64 * 64, nullptr, xB1b, NN);       // bf16 out, overlays rec
  k_agg1<<<NN / 4, 256, 0, stream>>>(xA1, xB1b, rowptr, col, eap, wbuf, agg320b);
  k_gemm<384, 64, true, 0, 1><<<(NN + 127) / 128, 256, 0, stream>>>(
      h, agg320b, wbuf + OFF_WPL1, wbuf + OFF_BPL1, h2, NN);
  k_gcnprep<<<NN * 16 / 256, 256, 0, stream>>>(h2, Wg, rowptr, hgs, dinv);
  k_head<<<NN / 4, 256, 0, stream>>>(x, hgs, dinv, rowptr, col, bg, Wh1, bh1,
                                     Wh2, bh2, out);
}

// Round 6
// 692.873 us; speedup vs baseline: 1.0732x; 1.0371x over previous
//
#include <hip/hip_runtime.h>

#define NN 100000
#define NE 1600000

// bucketing for two-level CSR sort
#define BSH 9                      // 512 nodes per bucket
#define BSZ (1 << BSH)
#define NB  196                    // ceil(NN / 512)
#define CHUNK 6250                 // NE / 256

// folded-weight buffer layout (float offsets)
#define OFF_C0   0
#define OFF_D0   64
#define OFF_WPL0 80
#define OFF_BPL0 6224
#define OFF_C1   6288
#define OFF_D1   6544
#define OFF_WPL1 6608
#define OFF_BPL1 31184
#define WBUF_TOT 31248

// ---- bf16 helpers (RNE pack, cheap unpack) ----
__device__ inline unsigned pack_bf16x2(float a, float b) {
  unsigned ua = __float_as_uint(a), ub = __float_as_uint(b);
  ua += 0x7fffu + ((ua >> 16) & 1u);
  ub += 0x7fffu + ((ub >> 16) & 1u);
  return (ua >> 16) | (ub & 0xffff0000u);
}
__device__ inline unsigned short pack_bf16(float a) {
  unsigned ua = __float_as_uint(a);
  ua += 0x7fffu + ((ua >> 16) & 1u);
  return (unsigned short)(ua >> 16);
}
__device__ inline float bf_s(unsigned short u) { return __uint_as_float(((unsigned)u) << 16); }

// ---------------- weight folding ----------------
__global__ void k_prep(const float* __restrict__ We0, const float* __restrict__ be0,
                       const float* __restrict__ Wpre0, const float* __restrict__ bpre0,
                       const float* __restrict__ Wpost0, const float* __restrict__ bpost0,
                       const float* __restrict__ Wlin0, const float* __restrict__ blin0,
                       const float* __restrict__ We1, const float* __restrict__ be1,
                       const float* __restrict__ Wpre1, const float* __restrict__ bpre1,
                       const float* __restrict__ Wpost1, const float* __restrict__ bpost1,
                       const float* __restrict__ Wlin1, const float* __restrict__ blin1,
                       float* __restrict__ wbuf) {
  int id = blockIdx.x * 256 + threadIdx.x;
  if (id >= WBUF_TOT) return;
  float a = 0.f;
  if (id < OFF_D0) {
    int j = id >> 4, f = id & 15;
    for (int t = 0; t < 16; t++) a = fmaf(We0[j*16+t], Wpre0[(32+t)*16+f], a);
  } else if (id < OFF_WPL0) {
    int f = id - OFF_D0; a = bpre0[f];
    for (int t = 0; t < 16; t++) a = fmaf(be0[t], Wpre0[(32+t)*16+f], a);
  } else if (id < OFF_BPL0) {
    int r = id - OFF_WPL0; int k = r >> 6, o = r & 63;
    for (int j = 0; j < 64; j++) a = fmaf(Wpost0[k*64+j], Wlin0[j*64+o], a);
  } else if (id < OFF_C1) {
    int o = id - OFF_BPL0; a = blin0[o];
    for (int j = 0; j < 64; j++) a = fmaf(bpost0[j], Wlin0[j*64+o], a);
  } else if (id < OFF_D1) {
    int r = id - OFF_C1; int j = r >> 6, f = r & 63;
    for (int t = 0; t < 64; t++) a = fmaf(We1[j*64+t], Wpre1[(128+t)*64+f], a);
  } else if (id < OFF_WPL1) {
    int f = id - OFF_D1; a = bpre1[f];
    for (int t = 0; t < 64; t++) a = fmaf(be1[t], Wpre1[(128+t)*64+f], a);
  } else if (id < OFF_BPL1) {
    int r = id - OFF_WPL1; int k = r >> 6, o = r & 63;
    for (int j = 0; j < 64; j++) a = fmaf(Wpost1[k*64+j], Wlin1[j*64+o], a);
  } else {
    int o = id - OFF_BPL1; a = blin1[o];
    for (int j = 0; j < 64; j++) a = fmaf(bpost1[j], Wlin1[j*64+o], a);
  }
  wbuf[id] = a;
}

// transpose+bf16 the folded [384,64] WPL1 -> Btb [64][384]
__global__ void k_bt(const float* __restrict__ wbuf, unsigned short* __restrict__ Btb) {
  int nn = blockIdx.x;        // 64 blocks
  int k  = threadIdx.x;       // 384 threads
  Btb[nn * 384 + k] = pack_bf16(wbuf[OFF_WPL1 + k * 64 + nn]);
}

// ---------------- CSR build ----------------
__global__ void k_hist(const int* __restrict__ dst, int* __restrict__ cnt) {
  int i = blockIdx.x * 256 + threadIdx.x;
  if (i < NE) atomicAdd(&cnt[dst[i]], 1);
}

__global__ void k_scan1(const int* __restrict__ deg, int* __restrict__ partial,
                        int* __restrict__ bsums) {
  __shared__ int lds[256];
  int i = blockIdx.x * 256 + threadIdx.x;
  int v = (i < NN) ? deg[i] : 0;
  lds[threadIdx.x] = v;
  __syncthreads();
  for (int off = 1; off < 256; off <<= 1) {
    int t = (threadIdx.x >= off) ? lds[threadIdx.x - off] : 0;
    __syncthreads();
    lds[threadIdx.x] += t;
    __syncthreads();
  }
  if (i < NN) partial[i] = lds[threadIdx.x];
  if (threadIdx.x == 255) bsums[blockIdx.x] = lds[255];
}

__global__ void k_scan2(const int* __restrict__ bsums, int* __restrict__ boff, int nb) {
  __shared__ int lds[512];
  int v = ((int)threadIdx.x < nb) ? bsums[threadIdx.x] : 0;
  lds[threadIdx.x] = v;
  __syncthreads();
  for (int off = 1; off < 512; off <<= 1) {
    int t = (threadIdx.x >= off) ? lds[threadIdx.x - off] : 0;
    __syncthreads();
    lds[threadIdx.x] += t;
    __syncthreads();
  }
  if ((int)threadIdx.x < nb) boff[threadIdx.x] = lds[threadIdx.x] - v;  // exclusive
}

__global__ void k_scan3(const int* __restrict__ partial, const int* __restrict__ boff,
                        const int* __restrict__ deg, int* __restrict__ rowptr,
                        int* __restrict__ fill) {
  int i = blockIdx.x * 256 + threadIdx.x;
  if (i < NN) {
    int incl = partial[i] + boff[blockIdx.x];
    rowptr[i + 1] = incl;
    fill[i] = incl - deg[i];
  }
  if (i == 0) rowptr[0] = 0;
}

__global__ void k_binit(const int* __restrict__ rowptr, int* __restrict__ gfill) {
  int b = threadIdx.x;
  if (b < NB) {
    int n0 = b << BSH;
    gfill[b] = rowptr[n0 > NN ? NN : n0];
  }
}

// pass 1: LDS-binned coarse sort
__global__ __launch_bounds__(256) void k_bin(const int* __restrict__ dst,
                                             int* __restrict__ gfill,
                                             int2* __restrict__ rec) {
  __shared__ int hcnt[NB];
  __shared__ int hbase[NB];
  const int t = threadIdx.x;
  for (int b = t; b < NB; b += 256) hcnt[b] = 0;
  __syncthreads();
  const int lo = blockIdx.x * CHUNK, hi = lo + CHUNK;
  for (int i = lo + t; i < hi; i += 256)
    atomicAdd(&hcnt[dst[i] >> BSH], 1);
  __syncthreads();
  for (int b = t; b < NB; b += 256) {
    int c = hcnt[b];
    hbase[b] = c > 0 ? atomicAdd(&gfill[b], c) : 0;
    hcnt[b] = 0;
  }
  __syncthreads();
  for (int i = lo + t; i < hi; i += 256) {
    int d = dst[i];
    int b = d >> BSH;
    int lp = atomicAdd(&hcnt[b], 1);
    rec[hbase[b] + lp] = make_int2(d, i);
  }
}

// pass 2: in-bucket scatter (L2-resident window)
__global__ __launch_bounds__(256) void k_scatter2(const int2* __restrict__ rec,
                                                  const int* __restrict__ rowptr,
                                                  int* __restrict__ perm) {
  __shared__ int lfill[BSZ];
  const int b = blockIdx.x;
  const int n0 = b << BSH;
  const int n1 = (n0 + BSZ < NN) ? n0 + BSZ : NN;
  const int t = threadIdx.x;
  for (int n = n0 + t; n < n1; n += 256) lfill[n - n0] = rowptr[n];
  __syncthreads();
  const int lo = rowptr[n0], hi = rowptr[n1];
  for (int i = lo + t; i < hi; i += 256) {
    int2 r = rec[i];
    int pos = atomicAdd(&lfill[r.x - n0], 1);
    perm[pos] = r.y;
  }
}

// pass 3: gather-permute
__global__ void k_permute(const int* __restrict__ perm, const int* __restrict__ src,
                          const float4* __restrict__ ea, int* __restrict__ col,
                          float4* __restrict__ eap) {
  int i = blockIdx.x * 256 + threadIdx.x;
  if (i < NE) {
    int eid = perm[i];
    col[i] = src[eid];
    eap[i] = ea[eid];
  }
}

// ---------------- layer 0 node pre-projection ----------------
__global__ void k_pre0(const float* __restrict__ x, const float* __restrict__ Wpre0,
                       float* __restrict__ xA0, float* __restrict__ xB0) {
  int t = blockIdx.x * 256 + threadIdx.x;   // NN*32 threads
  int node = t >> 5, k = t & 31;
  int f = k & 15;
  const float* W = Wpre0 + (k < 16 ? 0 : 256);
  const float* xr = x + (size_t)node * 16;
  float a = 0.f;
#pragma unroll
  for (int j = 0; j < 16; j++) a = fmaf(xr[j], W[j*16+f], a);
  if (k < 16) xA0[(size_t)node*16+f] = a; else xB0[(size_t)node*16+f] = a;
}

// ---------------- layer 0 aggregation ----------------
__global__ __launch_bounds__(256) void k_agg0(const float* __restrict__ x,
                                              const float* __restrict__ xA0,
                                              const float* __restrict__ xB0,
                                              const int* __restrict__ rowptr,
                                              const int* __restrict__ col,
                                              const float4* __restrict__ eap,
                                              const float* __restrict__ wbuf,
                                              float* __restrict__ vec96) {
  const int w = threadIdx.x >> 6, lane = threadIdx.x & 63;
  const int g = lane >> 4, f = lane & 15;
  const int node = blockIdx.x * 4 + w;
  const int start = rowptr[node], end = rowptr[node + 1];
  const int cnt = end - start;
  const float c0 = wbuf[OFF_C0 + f],      c1v = wbuf[OFF_C0 + 16 + f];
  const float c2v = wbuf[OFF_C0 + 32 + f], c3v = wbuf[OFF_C0 + 48 + f];
  float s = 0.f, sq = 0.f, mx = -__builtin_inff(), mn = __builtin_inff();
  for (int p = start + g; p < end; p += 4) {
    int si = col[p];
    float4 e0 = eap[p];
    float v = xB0[(size_t)si * 16 + f];
    v = fmaf(e0.x, c0, v); v = fmaf(e0.y, c1v, v);
    v = fmaf(e0.z, c2v, v); v = fmaf(e0.w, c3v, v);
    s += v; sq = fmaf(v, v, sq); mx = fmaxf(mx, v); mn = fminf(mn, v);
  }
  s  += __shfl_xor(s, 16);  s  += __shfl_xor(s, 32);
  sq += __shfl_xor(sq, 16); sq += __shfl_xor(sq, 32);
  mx = fmaxf(mx, __shfl_xor(mx, 16)); mx = fmaxf(mx, __shfl_xor(mx, 32));
  mn = fminf(mn, __shfl_xor(mn, 16)); mn = fminf(mn, __shfl_xor(mn, 32));
  const float c = xA0[(size_t)node * 16 + f] + wbuf[OFF_D0 + f];
  float sum_m, mean_m, mx_m, mn_m, std_m;
  if (cnt > 0) {
    float inv = 1.f / (float)cnt;
    float meanv = s * inv;
    sum_m = fmaf((float)cnt, c, s);
    mean_m = meanv + c;
    mx_m = mx + c; mn_m = mn + c;
    float var = fmaf(-meanv, meanv, sq * inv);
    std_m = sqrtf(fmaxf(var, 0.f) + 1e-5f);
  } else {
    sum_m = 0.f; mean_m = 0.f; mx_m = 0.f; mn_m = 0.f; std_m = sqrtf(1e-5f);
  }
  if (g == 0) {
    float* vr = vec96 + (size_t)node * 96;
    vr[f]      = x[(size_t)node * 16 + f];
    vr[16 + f] = sum_m;
    vr[32 + f] = mean_m;
    vr[48 + f] = mx_m;
    vr[64 + f] = mn_m;
    vr[80 + f] = std_m;
  }
}

// ---------------- layer 1 aggregation: lane-per-feature, 8-edge unroll ----------------
__global__ __launch_bounds__(256) void k_agg1(const float* __restrict__ xA1,
                                              const unsigned short* __restrict__ xB1b,
                                              const int* __restrict__ rowptr,
                                              const int* __restrict__ col,
                                              const float4* __restrict__ eap,
                                              const float* __restrict__ wbuf,
                                              unsigned short* __restrict__ agg320b) {
  const int w = threadIdx.x >> 6, f = threadIdx.x & 63;
  const int node = blockIdx.x * 4 + w;
  const int start = rowptr[node], end = rowptr[node + 1];
  const int cnt = end - start;
  const float c0 = wbuf[OFF_C1 + f],       c1v = wbuf[OFF_C1 + 64 + f];
  const float c2v = wbuf[OFF_C1 + 128 + f], c3v = wbuf[OFF_C1 + 192 + f];
  float s = 0.f, sq = 0.f, mx = -__builtin_inff(), mn = __builtin_inff();
  int p = start;
  for (; p + 7 < end; p += 8) {
    int idx[8]; float4 ev[8]; float v[8];
#pragma unroll
    for (int u = 0; u < 8; u++) idx[u] = col[p + u];
#pragma unroll
    for (int u = 0; u < 8; u++) ev[u] = eap[p + u];
#pragma unroll
    for (int u = 0; u < 8; u++) v[u] = bf_s(xB1b[(size_t)idx[u] * 64 + f]);
#pragma unroll
    for (int u = 0; u < 8; u++) {
      float t = v[u];
      t = fmaf(ev[u].x, c0, t); t = fmaf(ev[u].y, c1v, t);
      t = fmaf(ev[u].z, c2v, t); t = fmaf(ev[u].w, c3v, t);
      s += t; sq = fmaf(t, t, sq); mx = fmaxf(mx, t); mn = fminf(mn, t);
    }
  }
  for (; p + 3 < end; p += 4) {
    int idx[4]; float4 ev[4]; float v[4];
#pragma unroll
    for (int u = 0; u < 4; u++) idx[u] = col[p + u];
#pragma unroll
    for (int u = 0; u < 4; u++) ev[u] = eap[p + u];
#pragma unroll
    for (int u = 0; u < 4; u++) v[u] = bf_s(xB1b[(size_t)idx[u] * 64 + f]);
#pragma unroll
    for (int u = 0; u < 4; u++) {
      float t = v[u];
      t = fmaf(ev[u].x, c0, t); t = fmaf(ev[u].y, c1v, t);
      t = fmaf(ev[u].z, c2v, t); t = fmaf(ev[u].w, c3v, t);
      s += t; sq = fmaf(t, t, sq); mx = fmaxf(mx, t); mn = fminf(mn, t);
    }
  }
  for (; p < end; p++) {
    int i0 = col[p];
    float4 e0 = eap[p];
    float v0 = bf_s(xB1b[(size_t)i0 * 64 + f]);
    v0 = fmaf(e0.x, c0, v0); v0 = fmaf(e0.y, c1v, v0);
    v0 = fmaf(e0.z, c2v, v0); v0 = fmaf(e0.w, c3v, v0);
    s += v0; sq = fmaf(v0, v0, sq); mx = fmaxf(mx, v0); mn = fminf(mn, v0);
  }
  const float c = xA1[(size_t)node * 64 + f] + wbuf[OFF_D1 + f];
  float sum_m, mean_m, mx_m, mn_m, std_m;
  if (cnt > 0) {
    float inv = 1.f / (float)cnt;
    float meanv = s * inv;
    sum_m = fmaf((float)cnt, c, s);
    mean_m = meanv + c;
    mx_m = mx + c; mn_m = mn + c;
    float var = fmaf(-meanv, meanv, sq * inv);
    std_m = sqrtf(fmaxf(var, 0.f) + 1e-5f);
  } else {
    sum_m = 0.f; mean_m = 0.f; mx_m = 0.f; mn_m = 0.f; std_m = sqrtf(1e-5f);
  }
  unsigned short* ar = agg320b + (size_t)node * 320;
  ar[f]       = pack_bf16(sum_m);
  ar[64 + f]  = pack_bf16(mean_m);
  ar[128 + f] = pack_bf16(mx_m);
  ar[192 + f] = pack_bf16(mn_m);
  ar[256 + f] = pack_bf16(std_m);
}

// ---------------- tiled fp32 GEMM: C[n,64] = [A1|A2][n,KT] @ B[KT,64] ----
// OMODE: 0 = fp32 C, 1 = bf16 C, 2 = fp32 C + bf16 C2.
template <int KT, int K1, bool RELU, int OMODE>
__global__ __launch_bounds__(256) void k_gemm(const float* __restrict__ A1,
                                              const float* __restrict__ A2,
                                              const float* __restrict__ B,
                                              const float* __restrict__ bias,
                                              void* __restrict__ C,
                                              void* __restrict__ C2, int n) {
  __shared__ float As[32][128];
  __shared__ float Bs[32][64];
  const int tid = threadIdx.x;
  const int tm = tid & 31, tf = tid >> 5;
  const int m0 = blockIdx.x * 128;
  float acc[4][8];
#pragma unroll
  for (int i = 0; i < 4; i++)
#pragma unroll
    for (int j = 0; j < 8; j++) acc[i][j] = 0.f;

  for (int k0 = 0; k0 < KT; k0 += 32) {
    {
      int ml = tid & 127;
      int m = m0 + ml;
      int qh = tid >> 7;
      if (m < n) {
#pragma unroll
        for (int q = 0; q < 4; q++) {
          int kk = qh * 16 + q * 4;
          int kg = k0 + kk;
          float4 v;
          if (kg < K1) v = *(const float4*)(A1 + (size_t)m * K1 + kg);
          else         v = *(const float4*)(A2 + (size_t)m * (KT - K1) + (kg - K1));
          As[kk + 0][ml] = v.x; As[kk + 1][ml] = v.y;
          As[kk + 2][ml] = v.z; As[kk + 3][ml] = v.w;
        }
      } else {
#pragma unroll
        for (int q = 0; q < 4; q++) {
          int kk = qh * 16 + q * 4;
          As[kk][ml] = 0.f; As[kk + 1][ml] = 0.f; As[kk + 2][ml] = 0.f; As[kk + 3][ml] = 0.f;
        }
      }
    }
    {
      int kb = tid >> 3;
      int fb = (tid & 7) * 8;
      const float4* br = (const float4*)(B + (size_t)(k0 + kb) * 64 + fb);
      float4 b0 = br[0], b1 = br[1];
      *(float4*)&Bs[kb][fb] = b0;
      *(float4*)&Bs[kb][fb + 4] = b1;
    }
    __syncthreads();
#pragma unroll 8
    for (int k = 0; k < 32; k++) {
      float av[4], bv[8];
      *(float4*)&av[0] = *(const float4*)&As[k][tm * 4];
      *(float4*)&bv[0] = *(const float4*)&Bs[k][tf * 8];
      *(float4*)&bv[4] = *(const float4*)&Bs[k][tf * 8 + 4];
#pragma unroll
      for (int i = 0; i < 4; i++)
#pragma unroll
        for (int j = 0; j < 8; j++) acc[i][j] = fmaf(av[i], bv[j], acc[i][j]);
    }
    __syncthreads();
  }
  float bb[8];
#pragma unroll
  for (int j = 0; j < 8; j++) bb[j] = bias ? bias[tf * 8 + j] : 0.f;
#pragma unroll
  for (int i = 0; i < 4; i++) {
    int m = m0 + tm * 4 + i;
    if (m < n) {
      float vv[8];
#pragma unroll
      for (int j = 0; j < 8; j++) {
        float v = acc[i][j] + bb[j];
        vv[j] = RELU ? fmaxf(v, 0.f) : v;
      }
      if (OMODE == 0 || OMODE == 2) {
        float4* cp = (float4*)((float*)C + (size_t)m * 64 + tf * 8);
        cp[0] = make_float4(vv[0], vv[1], vv[2], vv[3]);
        cp[1] = make_float4(vv[4], vv[5], vv[6], vv[7]);
      }
      if (OMODE == 1 || OMODE == 2) {
        uint4 pk;
        pk.x = pack_bf16x2(vv[0], vv[1]); pk.y = pack_bf16x2(vv[2], vv[3]);
        pk.z = pack_bf16x2(vv[4], vv[5]); pk.w = pack_bf16x2(vv[6], vv[7]);
        void* dst = (OMODE == 1) ? C : C2;
        *(uint4*)((unsigned short*)dst + (size_t)m * 64 + tf * 8) = pk;
      }
    }
  }
}

// ---------------- MFMA GEMM: h2[n,64] = relu([hb|aggb][n,384]_bf16 @ Btb^T + bias) ----
__global__ __launch_bounds__(256) void k_mm384(const unsigned short* __restrict__ hb,
                                               const unsigned short* __restrict__ aggb,
                                               const unsigned short* __restrict__ Btb,
                                               const float* __restrict__ wbuf,
                                               float* __restrict__ h2, int n) {
  using bf16x8 = __attribute__((ext_vector_type(8))) short;
  using f32x4  = __attribute__((ext_vector_type(4))) float;
  const int wave = threadIdx.x >> 6, lane = threadIdx.x & 63;
  const int qm = lane & 15, quad = lane >> 4;
  const int m0 = blockIdx.x * 64 + wave * 16;
  const int mrow = m0 + qm;                    // A-fragment row (padded buffers)
  f32x4 acc[4] = {};
  for (int k0 = 0; k0 < 384; k0 += 32) {
    bf16x8 a;
    if (k0 < 64) a = *(const bf16x8*)(hb + (size_t)mrow * 64 + k0 + quad * 8);
    else         a = *(const bf16x8*)(aggb + (size_t)mrow * 320 + (k0 - 64) + quad * 8);
#pragma unroll
    for (int nt = 0; nt < 4; nt++) {
      bf16x8 b = *(const bf16x8*)(Btb + (size_t)(nt * 16 + qm) * 384 + k0 + quad * 8);
      acc[nt] = __builtin_amdgcn_mfma_f32_16x16x32_bf16(a, b, acc[nt], 0, 0, 0);
    }
  }
#pragma unroll
  for (int nt = 0; nt < 4; nt++) {
    int colc = nt * 16 + qm;
    float bias = wbuf[OFF_BPL1 + colc];
#pragma unroll
    for (int r = 0; r < 4; r++) {
      int m = m0 + quad * 4 + r;
      if (m < n) h2[(size_t)m * 64 + colc] = fmaxf(acc[nt][r] + bias, 0.f);
    }
  }
}

// ---------------- GCN prep: hgs = (h2 @ Wg) * dinv ----------------
__global__ void k_gcnprep(const float* __restrict__ h2, const float* __restrict__ Wg,
                          const int* __restrict__ rowptr,
                          float* __restrict__ hgs, float* __restrict__ dinv) {
  int t = blockIdx.x * 256 + threadIdx.x;   // NN*16 threads
  int node = t >> 4, f = t & 15;
  const float* hr = h2 + (size_t)node * 64;
  float a = 0.f;
#pragma unroll
  for (int j = 0; j < 64; j++) a = fmaf(hr[j], Wg[j * 16 + f], a);
  int dg = rowptr[node + 1] - rowptr[node] + 1;  // +1 self loop
  float dv = 1.0f / sqrtf((float)dg);
  hgs[(size_t)node * 16 + f] = a * dv;
  if (f == 0) dinv[node] = dv;
}

// ---------------- GCN aggregate + MLP head ----------------
__global__ __launch_bounds__(256) void k_head(const float* __restrict__ x,
                                              const float* __restrict__ hgs,
                                              const float* __restrict__ dinv,
                                              const int* __restrict__ rowptr,
                                              const int* __restrict__ col,
                                              const float* __restrict__ bg,
                                              const float* __restrict__ Wh1,
                                              const float* __restrict__ bh1,
                                              const float* __restrict__ Wh2,
                                              const float* __restrict__ bh2,
                                              float* __restrict__ out) {
  __shared__ float zb[4][32];
  __shared__ float o1b[4][10];
  const int w = threadIdx.x >> 6, lane = threadIdx.x & 63;
  const int g = lane >> 4, f = lane & 15;
  const int node = blockIdx.x * 4 + w;
  const int start = rowptr[node], end = rowptr[node + 1];
  float s = 0.f;
  for (int p = start + g; p < end; p += 4) {
    int si = col[p];
    s += hgs[(size_t)si * 16 + f];
  }
  s += __shfl_xor(s, 16); s += __shfl_xor(s, 32);
  if (g == 0) {
    float gout = (s + hgs[(size_t)node * 16 + f]) * dinv[node] + bg[f];
    zb[w][f] = gout;
    zb[w][16 + f] = x[(size_t)node * 16 + f];
  }
  __syncthreads();
  if (lane < 10) {
    float a = bh1[lane];
#pragma unroll
    for (int k = 0; k < 32; k++) a = fmaf(zb[w][k], Wh1[k * 10 + lane], a);
    o1b[w][lane] = fmaxf(a, 0.f);
  }
  __syncthreads();
  if (lane < 10) {
    float a = bh2[lane];
#pragma unroll
    for (int j = 0; j < 10; j++) a = fmaf(o1b[w][j], Wh2[j * 10 + lane], a);
    out[(size_t)node * 10 + lane] = a;
  }
}

// ---------------- launcher ----------------
extern "C" void kernel_launch(void* const* d_in, const int* in_sizes, int n_in,
                              void* d_out, int out_size, void* d_ws, size_t ws_size,
                              hipStream_t stream) {
  const float* x      = (const float*)d_in[0];
  const int*   ei     = (const int*)d_in[1];
  const float* eattr  = (const float*)d_in[2];
  const float* We0    = (const float*)d_in[3];
  const float* be0    = (const float*)d_in[4];
  const float* Wpre0  = (const float*)d_in[5];
  const float* bpre0  = (const float*)d_in[6];
  const float* Wpost0 = (const float*)d_in[7];
  const float* bpost0 = (const float*)d_in[8];
  const float* Wlin0  = (const float*)d_in[9];
  const float* blin0  = (const float*)d_in[10];
  const float* We1    = (const float*)d_in[11];
  const float* be1    = (const float*)d_in[12];
  const float* Wpre1  = (const float*)d_in[13];
  const float* bpre1  = (const float*)d_in[14];
  const float* Wpost1 = (const float*)d_in[15];
  const float* bpost1 = (const float*)d_in[16];
  const float* Wlin1  = (const float*)d_in[17];
  const float* blin1  = (const float*)d_in[18];
  const float* Wg     = (const float*)d_in[19];
  const float* bg     = (const float*)d_in[20];
  const float* Wh1    = (const float*)d_in[21];
  const float* bh1    = (const float*)d_in[22];
  const float* Wh2    = (const float*)d_in[23];
  const float* bh2    = (const float*)d_in[24];
  const int* srcI = ei;
  const int* dstI = ei + NE;
  float* out = (float*)d_out;

  char* base = (char*)d_ws;
  size_t off = 0;
  auto take = [&](size_t bytes) -> char* {
    char* p = base + off;
    off += (bytes + 255) & ~(size_t)255;
    return p;
  };
  int* cnt     = (int*)take((size_t)NN * 4);
  int* rowptr  = (int*)take((size_t)(NN + 1) * 4);
  int* fill    = (int*)take((size_t)NN * 4);
  int* partial = (int*)take((size_t)NN * 4);
  int* bsums   = (int*)take(512 * 4);
  int* boff    = (int*)take(512 * 4);
  int* gfill   = (int*)take(512 * 4);
  unsigned short* Btb = (unsigned short*)take(64 * 384 * 2);
  int* col     = (int*)take((size_t)NE * 4);
  float4* eap  = (float4*)take((size_t)NE * 16);     // 25.6MB; aliased by h2 later
  float* h2    = (float*)eap;                        // h2 [NN,64], alive after eap dies
  float* wbuf  = (float*)take((size_t)WBUF_TOT * 4);
  float* h     = (float*)take((size_t)NN * 64 * 4);
  int*   perm  = (int*)h;                            // perm [NE] = 6.4MB, dead before h written
  float* xA1   = (float*)take((size_t)NN * 64 * 4);
  int2*  rec   = (int2*)take((size_t)NE * 8);        // 12.8MB
  unsigned short* xB1b = (unsigned short*)rec;       // xB1 bf16 [NN,64], after rec dies
  // region Z (128MB): vec96/xA0/xB0 early -> agg320b (64MB) + hb mid -> hgs/dinv late
  char* Z = take((size_t)NN * 320 * 4);
  unsigned short* agg320b = (unsigned short*)Z;                  // [0 .. 64MB)
  float* vec96  = (float*)Z;                                     // [0 .. 38.4MB)
  float* xA0    = (float*)(Z + (size_t)NN * 96 * 4);
  float* xB0    = (float*)(Z + (size_t)NN * 96 * 4 + (size_t)NN * 16 * 4);
  unsigned short* hb = (unsigned short*)(Z + (size_t)96 * 1024 * 1024);  // [96MB..108.8MB)
  float* hgs    = (float*)Z;
  float* dinv   = (float*)(Z + (size_t)NN * 16 * 4);

  hipMemsetAsync(cnt, 0, (size_t)NN * 4, stream);
  k_prep<<<(WBUF_TOT + 255) / 256, 256, 0, stream>>>(
      We0, be0, Wpre0, bpre0, Wpost0, bpost0, Wlin0, blin0,
      We1, be1, Wpre1, bpre1, Wpost1, bpost1, Wlin1, blin1, wbuf);
  k_bt<<<64, 384, 0, stream>>>(wbuf, Btb);
  k_hist<<<(NE + 255) / 256, 256, 0, stream>>>(dstI, cnt);
  k_scan1<<<391, 256, 0, stream>>>(cnt, partial, bsums);
  k_scan2<<<1, 512, 0, stream>>>(bsums, boff, 391);
  k_scan3<<<391, 256, 0, stream>>>(partial, boff, cnt, rowptr, fill);
  k_binit<<<1, 256, 0, stream>>>(rowptr, gfill);
  k_bin<<<256, 256, 0, stream>>>(dstI, gfill, rec);
  k_scatter2<<<NB, 256, 0, stream>>>(rec, rowptr, perm);
  k_permute<<<(NE + 255) / 256, 256, 0, stream>>>(perm, srcI, (const float4*)eattr,
                                                  col, eap);
  k_pre0<<<NN * 32 / 256, 256, 0, stream>>>(x, Wpre0, xA0, xB0);
  k_agg0<<<NN / 4, 256, 0, stream>>>(x, xA0, xB0, rowptr, col, eap, wbuf, vec96);
  k_gemm<96, 96, true, 2><<<(NN + 127) / 128, 256, 0, stream>>>(
      vec96, vec96, wbuf + OFF_WPL0, wbuf + OFF_BPL0, h, hb, NN);
  k_gemm<64, 64, false, 0><<<(NN + 127) / 128, 256, 0, stream>>>(
      h, h, Wpre1, nullptr, xA1, nullptr, NN);
  k_gemm<64, 64, false, 1><<<(NN + 127) / 128, 256, 0, stream>>>(
      h, h, Wpre1 + 64 * 64, nullptr, xB1b, nullptr, NN);
  k_agg1<<<NN / 4, 256, 0, stream>>>(xA1, xB1b, rowptr, col, eap, wbuf, agg320b);
  k_mm384<<<(NN + 63) / 64, 256, 0, stream>>>(hb, agg320b, Btb, wbuf, h2, NN);
  k_gcnprep<<<NN * 16 / 256, 256, 0, stream>>>(h2, Wg, rowptr, hgs, dinv);
  k_head<<<NN / 4, 256, 0, stream>>>(x, hgs, dinv, rowptr, col, bg, Wh1, bh1,
                                     Wh2, bh2, out);
}

// Round 7
// 664.946 us; speedup vs baseline: 1.1182x; 1.0420x over previous
//
#include <hip/hip_runtime.h>

#define NN 100000
#define NE 1600000

// bucketing for two-level CSR sort
#define BSH 9                      // 512 nodes per bucket
#define BSZ (1 << BSH)
#define NB  196                    // ceil(NN / 512)
#define CHUNK 6250                 // NE / 256

// folded-weight buffer layout (float offsets)
#define OFF_C0   0
#define OFF_D0   64
#define OFF_WPL0 80
#define OFF_BPL0 6224
#define OFF_C1   6288
#define OFF_D1   6544
#define OFF_WPL1 6608
#define OFF_BPL1 31184
#define WBUF_TOT 31248

// ---- bf16 helpers (RNE pack, cheap unpack) ----
__device__ inline unsigned pack_bf16x2(float a, float b) {
  unsigned ua = __float_as_uint(a), ub = __float_as_uint(b);
  ua += 0x7fffu + ((ua >> 16) & 1u);
  ub += 0x7fffu + ((ub >> 16) & 1u);
  return (ua >> 16) | (ub & 0xffff0000u);
}
__device__ inline unsigned short pack_bf16(float a) {
  unsigned ua = __float_as_uint(a);
  ua += 0x7fffu + ((ua >> 16) & 1u);
  return (unsigned short)(ua >> 16);
}
__device__ inline float bf_s(unsigned short u) { return __uint_as_float(((unsigned)u) << 16); }

// ---------------- weight folding ----------------
__global__ void k_prep(const float* __restrict__ We0, const float* __restrict__ be0,
                       const float* __restrict__ Wpre0, const float* __restrict__ bpre0,
                       const float* __restrict__ Wpost0, const float* __restrict__ bpost0,
                       const float* __restrict__ Wlin0, const float* __restrict__ blin0,
                       const float* __restrict__ We1, const float* __restrict__ be1,
                       const float* __restrict__ Wpre1, const float* __restrict__ bpre1,
                       const float* __restrict__ Wpost1, const float* __restrict__ bpost1,
                       const float* __restrict__ Wlin1, const float* __restrict__ blin1,
                       float* __restrict__ wbuf) {
  int id = blockIdx.x * 256 + threadIdx.x;
  if (id >= WBUF_TOT) return;
  float a = 0.f;
  if (id < OFF_D0) {
    int j = id >> 4, f = id & 15;
    for (int t = 0; t < 16; t++) a = fmaf(We0[j*16+t], Wpre0[(32+t)*16+f], a);
  } else if (id < OFF_WPL0) {
    int f = id - OFF_D0; a = bpre0[f];
    for (int t = 0; t < 16; t++) a = fmaf(be0[t], Wpre0[(32+t)*16+f], a);
  } else if (id < OFF_BPL0) {
    int r = id - OFF_WPL0; int k = r >> 6, o = r & 63;
    for (int j = 0; j < 64; j++) a = fmaf(Wpost0[k*64+j], Wlin0[j*64+o], a);
  } else if (id < OFF_C1) {
    int o = id - OFF_BPL0; a = blin0[o];
    for (int j = 0; j < 64; j++) a = fmaf(bpost0[j], Wlin0[j*64+o], a);
  } else if (id < OFF_D1) {
    int r = id - OFF_C1; int j = r >> 6, f = r & 63;
    for (int t = 0; t < 64; t++) a = fmaf(We1[j*64+t], Wpre1[(128+t)*64+f], a);
  } else if (id < OFF_WPL1) {
    int f = id - OFF_D1; a = bpre1[f];
    for (int t = 0; t < 64; t++) a = fmaf(be1[t], Wpre1[(128+t)*64+f], a);
  } else if (id < OFF_BPL1) {
    int r = id - OFF_WPL1; int k = r >> 6, o = r & 63;
    for (int j = 0; j < 64; j++) a = fmaf(Wpost1[k*64+j], Wlin1[j*64+o], a);
  } else {
    int o = id - OFF_BPL1; a = blin1[o];
    for (int j = 0; j < 64; j++) a = fmaf(bpost1[j], Wlin1[j*64+o], a);
  }
  wbuf[id] = a;
}

// transpose+bf16 the folded [384,64] WPL1 -> Btb [64][384]
__global__ void k_bt(const float* __restrict__ wbuf, unsigned short* __restrict__ Btb) {
  int nn = blockIdx.x;        // 64 blocks
  int k  = threadIdx.x;       // 384 threads
  Btb[nn * 384 + k] = pack_bf16(wbuf[OFF_WPL1 + k * 64 + nn]);
}

// ---------------- CSR build ----------------
__global__ void k_hist(const int* __restrict__ dst, int* __restrict__ cnt) {
  int i = blockIdx.x * 256 + threadIdx.x;
  if (i < NE) atomicAdd(&cnt[dst[i]], 1);
}

__global__ void k_scan1(const int* __restrict__ deg, int* __restrict__ partial,
                        int* __restrict__ bsums) {
  __shared__ int lds[256];
  int i = blockIdx.x * 256 + threadIdx.x;
  int v = (i < NN) ? deg[i] : 0;
  lds[threadIdx.x] = v;
  __syncthreads();
  for (int off = 1; off < 256; off <<= 1) {
    int t = (threadIdx.x >= off) ? lds[threadIdx.x - off] : 0;
    __syncthreads();
    lds[threadIdx.x] += t;
    __syncthreads();
  }
  if (i < NN) partial[i] = lds[threadIdx.x];
  if (threadIdx.x == 255) bsums[blockIdx.x] = lds[255];
}

__global__ void k_scan2(const int* __restrict__ bsums, int* __restrict__ boff, int nb) {
  __shared__ int lds[512];
  int v = ((int)threadIdx.x < nb) ? bsums[threadIdx.x] : 0;
  lds[threadIdx.x] = v;
  __syncthreads();
  for (int off = 1; off < 512; off <<= 1) {
    int t = (threadIdx.x >= off) ? lds[threadIdx.x - off] : 0;
    __syncthreads();
    lds[threadIdx.x] += t;
    __syncthreads();
  }
  if ((int)threadIdx.x < nb) boff[threadIdx.x] = lds[threadIdx.x] - v;  // exclusive
}

__global__ void k_scan3(const int* __restrict__ partial, const int* __restrict__ boff,
                        const int* __restrict__ deg, int* __restrict__ rowptr,
                        int* __restrict__ fill) {
  int i = blockIdx.x * 256 + threadIdx.x;
  if (i < NN) {
    int incl = partial[i] + boff[blockIdx.x];
    rowptr[i + 1] = incl;
    fill[i] = incl - deg[i];
  }
  if (i == 0) rowptr[0] = 0;
}

__global__ void k_binit(const int* __restrict__ rowptr, int* __restrict__ gfill) {
  int b = threadIdx.x;
  if (b < NB) {
    int n0 = b << BSH;
    gfill[b] = rowptr[n0 > NN ? NN : n0];
  }
}

// pass 1: LDS-binned coarse sort
__global__ __launch_bounds__(256) void k_bin(const int* __restrict__ dst,
                                             int* __restrict__ gfill,
                                             int2* __restrict__ rec) {
  __shared__ int hcnt[NB];
  __shared__ int hbase[NB];
  const int t = threadIdx.x;
  for (int b = t; b < NB; b += 256) hcnt[b] = 0;
  __syncthreads();
  const int lo = blockIdx.x * CHUNK, hi = lo + CHUNK;
  for (int i = lo + t; i < hi; i += 256)
    atomicAdd(&hcnt[dst[i] >> BSH], 1);
  __syncthreads();
  for (int b = t; b < NB; b += 256) {
    int c = hcnt[b];
    hbase[b] = c > 0 ? atomicAdd(&gfill[b], c) : 0;
    hcnt[b] = 0;
  }
  __syncthreads();
  for (int i = lo + t; i < hi; i += 256) {
    int d = dst[i];
    int b = d >> BSH;
    int lp = atomicAdd(&hcnt[b], 1);
    rec[hbase[b] + lp] = make_int2(d, i);
  }
}

// pass 2: in-bucket scatter (L2-resident window)
__global__ __launch_bounds__(256) void k_scatter2(const int2* __restrict__ rec,
                                                  const int* __restrict__ rowptr,
                                                  int* __restrict__ perm) {
  __shared__ int lfill[BSZ];
  const int b = blockIdx.x;
  const int n0 = b << BSH;
  const int n1 = (n0 + BSZ < NN) ? n0 + BSZ : NN;
  const int t = threadIdx.x;
  for (int n = n0 + t; n < n1; n += 256) lfill[n - n0] = rowptr[n];
  __syncthreads();
  const int lo = rowptr[n0], hi = rowptr[n1];
  for (int i = lo + t; i < hi; i += 256) {
    int2 r = rec[i];
    int pos = atomicAdd(&lfill[r.x - n0], 1);
    perm[pos] = r.y;
  }
}

// pass 3: gather-permute
__global__ void k_permute(const int* __restrict__ perm, const int* __restrict__ src,
                          const float4* __restrict__ ea, int* __restrict__ col,
                          float4* __restrict__ eap) {
  int i = blockIdx.x * 256 + threadIdx.x;
  if (i < NE) {
    int eid = perm[i];
    col[i] = src[eid];
    eap[i] = ea[eid];
  }
}

// ---------------- layer 0 node pre-projection ----------------
__global__ void k_pre0(const float* __restrict__ x, const float* __restrict__ Wpre0,
                       float* __restrict__ xA0, float* __restrict__ xB0) {
  int t = blockIdx.x * 256 + threadIdx.x;   // NN*32 threads
  int node = t >> 5, k = t & 31;
  int f = k & 15;
  const float* W = Wpre0 + (k < 16 ? 0 : 256);
  const float* xr = x + (size_t)node * 16;
  float a = 0.f;
#pragma unroll
  for (int j = 0; j < 16; j++) a = fmaf(xr[j], W[j*16+f], a);
  if (k < 16) xA0[(size_t)node*16+f] = a; else xB0[(size_t)node*16+f] = a;
}

// ---------------- layer 0 aggregation ----------------
__global__ __launch_bounds__(256) void k_agg0(const float* __restrict__ x,
                                              const float* __restrict__ xA0,
                                              const float* __restrict__ xB0,
                                              const int* __restrict__ rowptr,
                                              const int* __restrict__ col,
                                              const float4* __restrict__ eap,
                                              const float* __restrict__ wbuf,
                                              float* __restrict__ vec96) {
  const int w = threadIdx.x >> 6, lane = threadIdx.x & 63;
  const int g = lane >> 4, f = lane & 15;
  const int node = blockIdx.x * 4 + w;
  const int start = rowptr[node], end = rowptr[node + 1];
  const int cnt = end - start;
  const float c0 = wbuf[OFF_C0 + f],      c1v = wbuf[OFF_C0 + 16 + f];
  const float c2v = wbuf[OFF_C0 + 32 + f], c3v = wbuf[OFF_C0 + 48 + f];
  float s = 0.f, sq = 0.f, mx = -__builtin_inff(), mn = __builtin_inff();
  for (int p = start + g; p < end; p += 4) {
    int si = col[p];
    float4 e0 = eap[p];
    float v = xB0[(size_t)si * 16 + f];
    v = fmaf(e0.x, c0, v); v = fmaf(e0.y, c1v, v);
    v = fmaf(e0.z, c2v, v); v = fmaf(e0.w, c3v, v);
    s += v; sq = fmaf(v, v, sq); mx = fmaxf(mx, v); mn = fminf(mn, v);
  }
  s  += __shfl_xor(s, 16);  s  += __shfl_xor(s, 32);
  sq += __shfl_xor(sq, 16); sq += __shfl_xor(sq, 32);
  mx = fmaxf(mx, __shfl_xor(mx, 16)); mx = fmaxf(mx, __shfl_xor(mx, 32));
  mn = fminf(mn, __shfl_xor(mn, 16)); mn = fminf(mn, __shfl_xor(mn, 32));
  const float c = xA0[(size_t)node * 16 + f] + wbuf[OFF_D0 + f];
  float sum_m, mean_m, mx_m, mn_m, std_m;
  if (cnt > 0) {
    float inv = 1.f / (float)cnt;
    float meanv = s * inv;
    sum_m = fmaf((float)cnt, c, s);
    mean_m = meanv + c;
    mx_m = mx + c; mn_m = mn + c;
    float var = fmaf(-meanv, meanv, sq * inv);
    std_m = sqrtf(fmaxf(var, 0.f) + 1e-5f);
  } else {
    sum_m = 0.f; mean_m = 0.f; mx_m = 0.f; mn_m = 0.f; std_m = sqrtf(1e-5f);
  }
  if (g == 0) {
    float* vr = vec96 + (size_t)node * 96;
    vr[f]      = x[(size_t)node * 16 + f];
    vr[16 + f] = sum_m;
    vr[32 + f] = mean_m;
    vr[48 + f] = mx_m;
    vr[64 + f] = mn_m;
    vr[80 + f] = std_m;
  }
}

// ---------------- layer 1 aggregation: one node per 64-thread block ----------------
// node = blockIdx.x is provably uniform -> col[p]/eap[p] compile to s_load
// (SMEM pipe), edge coeffs become SGPR operands, gather base computed on SALU.
// Per-edge vector work: 1 global_load_ushort + ~9 VALU.
__global__ __launch_bounds__(64) void k_agg1(const float* __restrict__ xA1,
                                             const unsigned short* __restrict__ xB1b,
                                             const int* __restrict__ rowptr,
                                             const int* __restrict__ col,
                                             const float4* __restrict__ eap,
                                             const float* __restrict__ wbuf,
                                             unsigned short* __restrict__ agg320b) {
  const int f = threadIdx.x;            // 0..63
  const int node = blockIdx.x;
  const int start = rowptr[node], end = rowptr[node + 1];
  const int cnt = end - start;
  const float c0 = wbuf[OFF_C1 + f],       c1v = wbuf[OFF_C1 + 64 + f];
  const float c2v = wbuf[OFF_C1 + 128 + f], c3v = wbuf[OFF_C1 + 192 + f];
  float s = 0.f, sq = 0.f, mx = -__builtin_inff(), mn = __builtin_inff();
  int p = start;
  for (; p + 7 < end; p += 8) {
#pragma unroll
    for (int u = 0; u < 8; u++) {
      int si = col[p + u];                                   // scalar load
      float4 e = eap[p + u];                                 // scalar dwordx4
      const unsigned short* row = xB1b + (unsigned)si * 64;  // SALU base
      float v = bf_s(row[f]);                                // 128B coalesced gather
      v = fmaf(e.x, c0, v); v = fmaf(e.y, c1v, v);
      v = fmaf(e.z, c2v, v); v = fmaf(e.w, c3v, v);
      s += v; sq = fmaf(v, v, sq); mx = fmaxf(mx, v); mn = fminf(mn, v);
    }
  }
  for (; p < end; p++) {
    int si = col[p];
    float4 e = eap[p];
    const unsigned short* row = xB1b + (unsigned)si * 64;
    float v = bf_s(row[f]);
    v = fmaf(e.x, c0, v); v = fmaf(e.y, c1v, v);
    v = fmaf(e.z, c2v, v); v = fmaf(e.w, c3v, v);
    s += v; sq = fmaf(v, v, sq); mx = fmaxf(mx, v); mn = fminf(mn, v);
  }
  const float c = xA1[(size_t)node * 64 + f] + wbuf[OFF_D1 + f];
  float sum_m, mean_m, mx_m, mn_m, std_m;
  if (cnt > 0) {
    float inv = 1.f / (float)cnt;
    float meanv = s * inv;
    sum_m = fmaf((float)cnt, c, s);
    mean_m = meanv + c;
    mx_m = mx + c; mn_m = mn + c;
    float var = fmaf(-meanv, meanv, sq * inv);
    std_m = sqrtf(fmaxf(var, 0.f) + 1e-5f);
  } else {
    sum_m = 0.f; mean_m = 0.f; mx_m = 0.f; mn_m = 0.f; std_m = sqrtf(1e-5f);
  }
  unsigned short* ar = agg320b + (size_t)node * 320;
  ar[f]       = pack_bf16(sum_m);
  ar[64 + f]  = pack_bf16(mean_m);
  ar[128 + f] = pack_bf16(mx_m);
  ar[192 + f] = pack_bf16(mn_m);
  ar[256 + f] = pack_bf16(std_m);
}

// ---------------- tiled fp32 GEMM: C[n,64] = [A1|A2][n,KT] @ B[KT,64] ----
// OMODE: 0 = fp32 C, 1 = bf16 C, 2 = fp32 C + bf16 C2.
template <int KT, int K1, bool RELU, int OMODE>
__global__ __launch_bounds__(256) void k_gemm(const float* __restrict__ A1,
                                              const float* __restrict__ A2,
                                              const float* __restrict__ B,
                                              const float* __restrict__ bias,
                                              void* __restrict__ C,
                                              void* __restrict__ C2, int n) {
  __shared__ float As[32][128];
  __shared__ float Bs[32][64];
  const int tid = threadIdx.x;
  const int tm = tid & 31, tf = tid >> 5;
  const int m0 = blockIdx.x * 128;
  float acc[4][8];
#pragma unroll
  for (int i = 0; i < 4; i++)
#pragma unroll
    for (int j = 0; j < 8; j++) acc[i][j] = 0.f;

  for (int k0 = 0; k0 < KT; k0 += 32) {
    {
      int ml = tid & 127;
      int m = m0 + ml;
      int qh = tid >> 7;
      if (m < n) {
#pragma unroll
        for (int q = 0; q < 4; q++) {
          int kk = qh * 16 + q * 4;
          int kg = k0 + kk;
          float4 v;
          if (kg < K1) v = *(const float4*)(A1 + (size_t)m * K1 + kg);
          else         v = *(const float4*)(A2 + (size_t)m * (KT - K1) + (kg - K1));
          As[kk + 0][ml] = v.x; As[kk + 1][ml] = v.y;
          As[kk + 2][ml] = v.z; As[kk + 3][ml] = v.w;
        }
      } else {
#pragma unroll
        for (int q = 0; q < 4; q++) {
          int kk = qh * 16 + q * 4;
          As[kk][ml] = 0.f; As[kk + 1][ml] = 0.f; As[kk + 2][ml] = 0.f; As[kk + 3][ml] = 0.f;
        }
      }
    }
    {
      int kb = tid >> 3;
      int fb = (tid & 7) * 8;
      const float4* br = (const float4*)(B + (size_t)(k0 + kb) * 64 + fb);
      float4 b0 = br[0], b1 = br[1];
      *(float4*)&Bs[kb][fb] = b0;
      *(float4*)&Bs[kb][fb + 4] = b1;
    }
    __syncthreads();
#pragma unroll 8
    for (int k = 0; k < 32; k++) {
      float av[4], bv[8];
      *(float4*)&av[0] = *(const float4*)&As[k][tm * 4];
      *(float4*)&bv[0] = *(const float4*)&Bs[k][tf * 8];
      *(float4*)&bv[4] = *(const float4*)&Bs[k][tf * 8 + 4];
#pragma unroll
      for (int i = 0; i < 4; i++)
#pragma unroll
        for (int j = 0; j < 8; j++) acc[i][j] = fmaf(av[i], bv[j], acc[i][j]);
    }
    __syncthreads();
  }
  float bb[8];
#pragma unroll
  for (int j = 0; j < 8; j++) bb[j] = bias ? bias[tf * 8 + j] : 0.f;
#pragma unroll
  for (int i = 0; i < 4; i++) {
    int m = m0 + tm * 4 + i;
    if (m < n) {
      float vv[8];
#pragma unroll
      for (int j = 0; j < 8; j++) {
        float v = acc[i][j] + bb[j];
        vv[j] = RELU ? fmaxf(v, 0.f) : v;
      }
      if (OMODE == 0 || OMODE == 2) {
        float4* cp = (float4*)((float*)C + (size_t)m * 64 + tf * 8);
        cp[0] = make_float4(vv[0], vv[1], vv[2], vv[3]);
        cp[1] = make_float4(vv[4], vv[5], vv[6], vv[7]);
      }
      if (OMODE == 1 || OMODE == 2) {
        uint4 pk;
        pk.x = pack_bf16x2(vv[0], vv[1]); pk.y = pack_bf16x2(vv[2], vv[3]);
        pk.z = pack_bf16x2(vv[4], vv[5]); pk.w = pack_bf16x2(vv[6], vv[7]);
        void* dst = (OMODE == 1) ? C : C2;
        *(uint4*)((unsigned short*)dst + (size_t)m * 64 + tf * 8) = pk;
      }
    }
  }
}

// ---------------- MFMA GEMM: h2[n,64] = relu([hb|aggb][n,384]_bf16 @ Btb^T + bias) ----
__global__ __launch_bounds__(256) void k_mm384(const unsigned short* __restrict__ hb,
                                               const unsigned short* __restrict__ aggb,
                                               const unsigned short* __restrict__ Btb,
                                               const float* __restrict__ wbuf,
                                               float* __restrict__ h2, int n) {
  using bf16x8 = __attribute__((ext_vector_type(8))) short;
  using f32x4  = __attribute__((ext_vector_type(4))) float;
  const int wave = threadIdx.x >> 6, lane = threadIdx.x & 63;
  const int qm = lane & 15, quad = lane >> 4;
  const int m0 = blockIdx.x * 64 + wave * 16;
  const int mrow = m0 + qm;                    // A-fragment row (padded buffers)
  f32x4 acc[4] = {};
  for (int k0 = 0; k0 < 384; k0 += 32) {
    bf16x8 a;
    if (k0 < 64) a = *(const bf16x8*)(hb + (size_t)mrow * 64 + k0 + quad * 8);
    else         a = *(const bf16x8*)(aggb + (size_t)mrow * 320 + (k0 - 64) + quad * 8);
#pragma unroll
    for (int nt = 0; nt < 4; nt++) {
      bf16x8 b = *(const bf16x8*)(Btb + (size_t)(nt * 16 + qm) * 384 + k0 + quad * 8);
      acc[nt] = __builtin_amdgcn_mfma_f32_16x16x32_bf16(a, b, acc[nt], 0, 0, 0);
    }
  }
#pragma unroll
  for (int nt = 0; nt < 4; nt++) {
    int colc = nt * 16 + qm;
    float bias = wbuf[OFF_BPL1 + colc];
#pragma unroll
    for (int r = 0; r < 4; r++) {
      int m = m0 + quad * 4 + r;
      if (m < n) h2[(size_t)m * 64 + colc] = fmaxf(acc[nt][r] + bias, 0.f);
    }
  }
}

// ---------------- GCN prep: hgs = (h2 @ Wg) * dinv ----------------
__global__ void k_gcnprep(const float* __restrict__ h2, const float* __restrict__ Wg,
                          const int* __restrict__ rowptr,
                          float* __restrict__ hgs, float* __restrict__ dinv) {
  int t = blockIdx.x * 256 + threadIdx.x;   // NN*16 threads
  int node = t >> 4, f = t & 15;
  const float* hr = h2 + (size_t)node * 64;
  float a = 0.f;
#pragma unroll
  for (int j = 0; j < 64; j++) a = fmaf(hr[j], Wg[j * 16 + f], a);
  int dg = rowptr[node + 1] - rowptr[node] + 1;  // +1 self loop
  float dv = 1.0f / sqrtf((float)dg);
  hgs[(size_t)node * 16 + f] = a * dv;
  if (f == 0) dinv[node] = dv;
}

// ---------------- GCN aggregate + MLP head ----------------
__global__ __launch_bounds__(256) void k_head(const float* __restrict__ x,
                                              const float* __restrict__ hgs,
                                              const float* __restrict__ dinv,
                                              const int* __restrict__ rowptr,
                                              const int* __restrict__ col,
                                              const float* __restrict__ bg,
                                              const float* __restrict__ Wh1,
                                              const float* __restrict__ bh1,
                                              const float* __restrict__ Wh2,
                                              const float* __restrict__ bh2,
                                              float* __restrict__ out) {
  __shared__ float zb[4][32];
  __shared__ float o1b[4][10];
  const int w = threadIdx.x >> 6, lane = threadIdx.x & 63;
  const int g = lane >> 4, f = lane & 15;
  const int node = blockIdx.x * 4 + w;
  const int start = rowptr[node], end = rowptr[node + 1];
  float s = 0.f;
  for (int p = start + g; p < end; p += 4) {
    int si = col[p];
    s += hgs[(size_t)si * 16 + f];
  }
  s += __shfl_xor(s, 16); s += __shfl_xor(s, 32);
  if (g == 0) {
    float gout = (s + hgs[(size_t)node * 16 + f]) * dinv[node] + bg[f];
    zb[w][f] = gout;
    zb[w][16 + f] = x[(size_t)node * 16 + f];
  }
  __syncthreads();
  if (lane < 10) {
    float a = bh1[lane];
#pragma unroll
    for (int k = 0; k < 32; k++) a = fmaf(zb[w][k], Wh1[k * 10 + lane], a);
    o1b[w][lane] = fmaxf(a, 0.f);
  }
  __syncthreads();
  if (lane < 10) {
    float a = bh2[lane];
#pragma unroll
    for (int j = 0; j < 10; j++) a = fmaf(o1b[w][j], Wh2[j * 10 + lane], a);
    out[(size_t)node * 10 + lane] = a;
  }
}

// ---------------- launcher ----------------
extern "C" void kernel_launch(void* const* d_in, const int* in_sizes, int n_in,
                              void* d_out, int out_size, void* d_ws, size_t ws_size,
                              hipStream_t stream) {
  const float* x      = (const float*)d_in[0];
  const int*   ei     = (const int*)d_in[1];
  const float* eattr  = (const float*)d_in[2];
  const float* We0    = (const float*)d_in[3];
  const float* be0    = (const float*)d_in[4];
  const float* Wpre0  = (const float*)d_in[5];
  const float* bpre0  = (const float*)d_in[6];
  const float* Wpost0 = (const float*)d_in[7];
  const float* bpost0 = (const float*)d_in[8];
  const float* Wlin0  = (const float*)d_in[9];
  const float* blin0  = (const float*)d_in[10];
  const float* We1    = (const float*)d_in[11];
  const float* be1    = (const float*)d_in[12];
  const float* Wpre1  = (const float*)d_in[13];
  const float* bpre1  = (const float*)d_in[14];
  const float* Wpost1 = (const float*)d_in[15];
  const float* bpost1 = (const float*)d_in[16];
  const float* Wlin1  = (const float*)d_in[17];
  const float* blin1  = (const float*)d_in[18];
  const float* Wg     = (const float*)d_in[19];
  const float* bg     = (const float*)d_in[20];
  const float* Wh1    = (const float*)d_in[21];
  const float* bh1    = (const float*)d_in[22];
  const float* Wh2    = (const float*)d_in[23];
  const float* bh2    = (const float*)d_in[24];
  const int* srcI = ei;
  const int* dstI = ei + NE;
  float* out = (float*)d_out;

  char* base = (char*)d_ws;
  size_t off = 0;
  auto take = [&](size_t bytes) -> char* {
    char* p = base + off;
    off += (bytes + 255) & ~(size_t)255;
    return p;
  };
  int* cnt     = (int*)take((size_t)NN * 4);
  int* rowptr  = (int*)take((size_t)(NN + 1) * 4);
  int* fill    = (int*)take((size_t)NN * 4);
  int* partial = (int*)take((size_t)NN * 4);
  int* bsums   = (int*)take(512 * 4);
  int* boff    = (int*)take(512 * 4);
  int* gfill   = (int*)take(512 * 4);
  unsigned short* Btb = (unsigned short*)take(64 * 384 * 2);
  int* col     = (int*)take((size_t)NE * 4);
  float4* eap  = (float4*)take((size_t)NE * 16);     // 25.6MB; aliased by h2 later
  float* h2    = (float*)eap;                        // h2 [NN,64], alive after eap dies
  float* wbuf  = (float*)take((size_t)WBUF_TOT * 4);
  float* h     = (float*)take((size_t)NN * 64 * 4);
  int*   perm  = (int*)h;                            // perm [NE] = 6.4MB, dead before h written
  float* xA1   = (float*)take((size_t)NN * 64 * 4);
  int2*  rec   = (int2*)take((size_t)NE * 8);        // 12.8MB
  unsigned short* xB1b = (unsigned short*)rec;       // xB1 bf16 [NN,64], after rec dies
  // region Z (128MB): vec96/xA0/xB0 early -> agg320b (64MB) + hb mid -> hgs/dinv late
  char* Z = take((size_t)NN * 320 * 4);
  unsigned short* agg320b = (unsigned short*)Z;                  // [0 .. 64MB)
  float* vec96  = (float*)Z;                                     // [0 .. 38.4MB)
  float* xA0    = (float*)(Z + (size_t)NN * 96 * 4);
  float* xB0    = (float*)(Z + (size_t)NN * 96 * 4 + (size_t)NN * 16 * 4);
  unsigned short* hb = (unsigned short*)(Z + (size_t)96 * 1024 * 1024);  // [96MB..108.8MB)
  float* hgs    = (float*)Z;
  float* dinv   = (float*)(Z + (size_t)NN * 16 * 4);

  hipMemsetAsync(cnt, 0, (size_t)NN * 4, stream);
  k_prep<<<(WBUF_TOT + 255) / 256, 256, 0, stream>>>(
      We0, be0, Wpre0, bpre0, Wpost0, bpost0, Wlin0, blin0,
      We1, be1, Wpre1, bpre1, Wpost1, bpost1, Wlin1, blin1, wbuf);
  k_bt<<<64, 384, 0, stream>>>(wbuf, Btb);
  k_hist<<<(NE + 255) / 256, 256, 0, stream>>>(dstI, cnt);
  k_scan1<<<391, 256, 0, stream>>>(cnt, partial, bsums);
  k_scan2<<<1, 512, 0, stream>>>(bsums, boff, 391);
  k_scan3<<<391, 256, 0, stream>>>(partial, boff, cnt, rowptr, fill);
  k_binit<<<1, 256, 0, stream>>>(rowptr, gfill);
  k_bin<<<256, 256, 0, stream>>>(dstI, gfill, rec);
  k_scatter2<<<NB, 256, 0, stream>>>(rec, rowptr, perm);
  k_permute<<<(NE + 255) / 256, 256, 0, stream>>>(perm, srcI, (const float4*)eattr,
                                                  col, eap);
  k_pre0<<<NN * 32 / 256, 256, 0, stream>>>(x, Wpre0, xA0, xB0);
  k_agg0<<<NN / 4, 256, 0, stream>>>(x, xA0, xB0, rowptr, col, eap, wbuf, vec96);
  k_gemm<96, 96, true, 2><<<(NN + 127) / 128, 256, 0, stream>>>(
      vec96, vec96, wbuf + OFF_WPL0, wbuf + OFF_BPL0, h, hb, NN);
  k_gemm<64, 64, false, 0><<<(NN + 127) / 128, 256, 0, stream>>>(
      h, h, Wpre1, nullptr, xA1, nullptr, NN);
  k_gemm<64, 64, false, 1><<<(NN + 127) / 128, 256, 0, stream>>>(
      h, h, Wpre1 + 64 * 64, nullptr, xB1b, nullptr, NN);
  k_agg1<<<NN, 64, 0, stream>>>(xA1, xB1b, rowptr, col, eap, wbuf, agg320b);
  k_mm384<<<(NN + 63) / 64, 256, 0, stream>>>(hb, agg320b, Btb, wbuf, h2, NN);
  k_gcnprep<<<NN * 16 / 256, 256, 0, stream>>>(h2, Wg, rowptr, hgs, dinv);
  k_head<<<NN / 4, 256, 0, stream>>>(x, hgs, dinv, rowptr, col, bg, Wh1, bh1,
                                     Wh2, bh2, out);
}

// Round 8
// 652.361 us; speedup vs baseline: 1.1398x; 1.0193x over previous
//
#include <hip/hip_runtime.h>

#define NN 100000
#define NE 1600000

// bucketing for two-level CSR sort
#define BSH 9                      // 512 nodes per bucket
#define BSZ (1 << BSH)
#define NB  196                    // ceil(NN / 512)
#define CHUNK 6250                 // NE / 256

// folded-weight buffer layout (float offsets)
#define OFF_C0   0
#define OFF_D0   64
#define OFF_WPL0 80
#define OFF_BPL0 6224
#define OFF_C1   6288
#define OFF_D1   6544
#define OFF_WPL1 6608
#define OFF_BPL1 31184
#define WBUF_TOT 31248

// ---- bf16 helpers (RNE pack, cheap unpack) ----
__device__ inline unsigned pack_bf16x2(float a, float b) {
  unsigned ua = __float_as_uint(a), ub = __float_as_uint(b);
  ua += 0x7fffu + ((ua >> 16) & 1u);
  ub += 0x7fffu + ((ub >> 16) & 1u);
  return (ua >> 16) | (ub & 0xffff0000u);
}
__device__ inline unsigned short pack_bf16(float a) {
  unsigned ua = __float_as_uint(a);
  ua += 0x7fffu + ((ua >> 16) & 1u);
  return (unsigned short)(ua >> 16);
}
__device__ inline float bf_s(unsigned short u) { return __uint_as_float(((unsigned)u) << 16); }

// ---------------- weight folding ----------------
__global__ void k_prep(const float* __restrict__ We0, const float* __restrict__ be0,
                       const float* __restrict__ Wpre0, const float* __restrict__ bpre0,
                       const float* __restrict__ Wpost0, const float* __restrict__ bpost0,
                       const float* __restrict__ Wlin0, const float* __restrict__ blin0,
                       const float* __restrict__ We1, const float* __restrict__ be1,
                       const float* __restrict__ Wpre1, const float* __restrict__ bpre1,
                       const float* __restrict__ Wpost1, const float* __restrict__ bpost1,
                       const float* __restrict__ Wlin1, const float* __restrict__ blin1,
                       float* __restrict__ wbuf) {
  int id = blockIdx.x * 256 + threadIdx.x;
  if (id >= WBUF_TOT) return;
  float a = 0.f;
  if (id < OFF_D0) {
    int j = id >> 4, f = id & 15;
    for (int t = 0; t < 16; t++) a = fmaf(We0[j*16+t], Wpre0[(32+t)*16+f], a);
  } else if (id < OFF_WPL0) {
    int f = id - OFF_D0; a = bpre0[f];
    for (int t = 0; t < 16; t++) a = fmaf(be0[t], Wpre0[(32+t)*16+f], a);
  } else if (id < OFF_BPL0) {
    int r = id - OFF_WPL0; int k = r >> 6, o = r & 63;
    for (int j = 0; j < 64; j++) a = fmaf(Wpost0[k*64+j], Wlin0[j*64+o], a);
  } else if (id < OFF_C1) {
    int o = id - OFF_BPL0; a = blin0[o];
    for (int j = 0; j < 64; j++) a = fmaf(bpost0[j], Wlin0[j*64+o], a);
  } else if (id < OFF_D1) {
    int r = id - OFF_C1; int j = r >> 6, f = r & 63;
    for (int t = 0; t < 64; t++) a = fmaf(We1[j*64+t], Wpre1[(128+t)*64+f], a);
  } else if (id < OFF_WPL1) {
    int f = id - OFF_D1; a = bpre1[f];
    for (int t = 0; t < 64; t++) a = fmaf(be1[t], Wpre1[(128+t)*64+f], a);
  } else if (id < OFF_BPL1) {
    int r = id - OFF_WPL1; int k = r >> 6, o = r & 63;
    for (int j = 0; j < 64; j++) a = fmaf(Wpost1[k*64+j], Wlin1[j*64+o], a);
  } else {
    int o = id - OFF_BPL1; a = blin1[o];
    for (int j = 0; j < 64; j++) a = fmaf(bpost1[j], Wlin1[j*64+o], a);
  }
  wbuf[id] = a;
}

// transpose+bf16 the folded [384,64] WPL1 -> Btb [64][384]
__global__ void k_bt(const float* __restrict__ wbuf, unsigned short* __restrict__ Btb) {
  int nn = blockIdx.x;        // 64 blocks
  int k  = threadIdx.x;       // 384 threads
  Btb[nn * 384 + k] = pack_bf16(wbuf[OFF_WPL1 + k * 64 + nn]);
}

// ---------------- CSR build ----------------
__global__ void k_hist(const int* __restrict__ dst, int* __restrict__ cnt) {
  int i = blockIdx.x * 256 + threadIdx.x;
  if (i < NE) atomicAdd(&cnt[dst[i]], 1);
}

__global__ void k_scan1(const int* __restrict__ deg, int* __restrict__ partial,
                        int* __restrict__ bsums) {
  __shared__ int lds[256];
  int i = blockIdx.x * 256 + threadIdx.x;
  int v = (i < NN) ? deg[i] : 0;
  lds[threadIdx.x] = v;
  __syncthreads();
  for (int off = 1; off < 256; off <<= 1) {
    int t = (threadIdx.x >= off) ? lds[threadIdx.x - off] : 0;
    __syncthreads();
    lds[threadIdx.x] += t;
    __syncthreads();
  }
  if (i < NN) partial[i] = lds[threadIdx.x];
  if (threadIdx.x == 255) bsums[blockIdx.x] = lds[255];
}

__global__ void k_scan2(const int* __restrict__ bsums, int* __restrict__ boff, int nb) {
  __shared__ int lds[512];
  int v = ((int)threadIdx.x < nb) ? bsums[threadIdx.x] : 0;
  lds[threadIdx.x] = v;
  __syncthreads();
  for (int off = 1; off < 512; off <<= 1) {
    int t = (threadIdx.x >= off) ? lds[threadIdx.x - off] : 0;
    __syncthreads();
    lds[threadIdx.x] += t;
    __syncthreads();
  }
  if ((int)threadIdx.x < nb) boff[threadIdx.x] = lds[threadIdx.x] - v;  // exclusive
}

__global__ void k_scan3(const int* __restrict__ partial, const int* __restrict__ boff,
                        const int* __restrict__ deg, int* __restrict__ rowptr,
                        int* __restrict__ fill) {
  int i = blockIdx.x * 256 + threadIdx.x;
  if (i < NN) {
    int incl = partial[i] + boff[blockIdx.x];
    rowptr[i + 1] = incl;
    fill[i] = incl - deg[i];
  }
  if (i == 0) rowptr[0] = 0;
}

__global__ void k_binit(const int* __restrict__ rowptr, int* __restrict__ gfill) {
  int b = threadIdx.x;
  if (b < NB) {
    int n0 = b << BSH;
    gfill[b] = rowptr[n0 > NN ? NN : n0];
  }
}

// pass 1: LDS-binned coarse sort
__global__ __launch_bounds__(256) void k_bin(const int* __restrict__ dst,
                                             int* __restrict__ gfill,
                                             int2* __restrict__ rec) {
  __shared__ int hcnt[NB];
  __shared__ int hbase[NB];
  const int t = threadIdx.x;
  for (int b = t; b < NB; b += 256) hcnt[b] = 0;
  __syncthreads();
  const int lo = blockIdx.x * CHUNK, hi = lo + CHUNK;
  for (int i = lo + t; i < hi; i += 256)
    atomicAdd(&hcnt[dst[i] >> BSH], 1);
  __syncthreads();
  for (int b = t; b < NB; b += 256) {
    int c = hcnt[b];
    hbase[b] = c > 0 ? atomicAdd(&gfill[b], c) : 0;
    hcnt[b] = 0;
  }
  __syncthreads();
  for (int i = lo + t; i < hi; i += 256) {
    int d = dst[i];
    int b = d >> BSH;
    int lp = atomicAdd(&hcnt[b], 1);
    rec[hbase[b] + lp] = make_int2(d, i);
  }
}

// pass 2: in-bucket scatter (L2-resident window)
__global__ __launch_bounds__(256) void k_scatter2(const int2* __restrict__ rec,
                                                  const int* __restrict__ rowptr,
                                                  int* __restrict__ perm) {
  __shared__ int lfill[BSZ];
  const int b = blockIdx.x;
  const int n0 = b << BSH;
  const int n1 = (n0 + BSZ < NN) ? n0 + BSZ : NN;
  const int t = threadIdx.x;
  for (int n = n0 + t; n < n1; n += 256) lfill[n - n0] = rowptr[n];
  __syncthreads();
  const int lo = rowptr[n0], hi = rowptr[n1];
  for (int i = lo + t; i < hi; i += 256) {
    int2 r = rec[i];
    int pos = atomicAdd(&lfill[r.x - n0], 1);
    perm[pos] = r.y;
  }
}

// pass 3: gather-permute
__global__ void k_permute(const int* __restrict__ perm, const int* __restrict__ src,
                          const float4* __restrict__ ea, int* __restrict__ col,
                          float4* __restrict__ eap) {
  int i = blockIdx.x * 256 + threadIdx.x;
  if (i < NE) {
    int eid = perm[i];
    col[i] = src[eid];
    eap[i] = ea[eid];
  }
}

// ---------------- layer 0 node pre-projection ----------------
__global__ void k_pre0(const float* __restrict__ x, const float* __restrict__ Wpre0,
                       float* __restrict__ xA0, float* __restrict__ xB0) {
  int t = blockIdx.x * 256 + threadIdx.x;   // NN*32 threads
  int node = t >> 5, k = t & 31;
  int f = k & 15;
  const float* W = Wpre0 + (k < 16 ? 0 : 256);
  const float* xr = x + (size_t)node * 16;
  float a = 0.f;
#pragma unroll
  for (int j = 0; j < 16; j++) a = fmaf(xr[j], W[j*16+f], a);
  if (k < 16) xA0[(size_t)node*16+f] = a; else xB0[(size_t)node*16+f] = a;
}

// ---------------- layer 0 aggregation ----------------
__global__ __launch_bounds__(256) void k_agg0(const float* __restrict__ x,
                                              const float* __restrict__ xA0,
                                              const float* __restrict__ xB0,
                                              const int* __restrict__ rowptr,
                                              const int* __restrict__ col,
                                              const float4* __restrict__ eap,
                                              const float* __restrict__ wbuf,
                                              float* __restrict__ vec96) {
  const int w = threadIdx.x >> 6, lane = threadIdx.x & 63;
  const int g = lane >> 4, f = lane & 15;
  const int node = blockIdx.x * 4 + w;
  const int start = rowptr[node], end = rowptr[node + 1];
  const int cnt = end - start;
  const float c0 = wbuf[OFF_C0 + f],      c1v = wbuf[OFF_C0 + 16 + f];
  const float c2v = wbuf[OFF_C0 + 32 + f], c3v = wbuf[OFF_C0 + 48 + f];
  float s = 0.f, sq = 0.f, mx = -__builtin_inff(), mn = __builtin_inff();
  for (int p = start + g; p < end; p += 4) {
    int si = col[p];
    float4 e0 = eap[p];
    float v = xB0[(size_t)si * 16 + f];
    v = fmaf(e0.x, c0, v); v = fmaf(e0.y, c1v, v);
    v = fmaf(e0.z, c2v, v); v = fmaf(e0.w, c3v, v);
    s += v; sq = fmaf(v, v, sq); mx = fmaxf(mx, v); mn = fminf(mn, v);
  }
  s  += __shfl_xor(s, 16);  s  += __shfl_xor(s, 32);
  sq += __shfl_xor(sq, 16); sq += __shfl_xor(sq, 32);
  mx = fmaxf(mx, __shfl_xor(mx, 16)); mx = fmaxf(mx, __shfl_xor(mx, 32));
  mn = fminf(mn, __shfl_xor(mn, 16)); mn = fminf(mn, __shfl_xor(mn, 32));
  const float c = xA0[(size_t)node * 16 + f] + wbuf[OFF_D0 + f];
  float sum_m, mean_m, mx_m, mn_m, std_m;
  if (cnt > 0) {
    float inv = 1.f / (float)cnt;
    float meanv = s * inv;
    sum_m = fmaf((float)cnt, c, s);
    mean_m = meanv + c;
    mx_m = mx + c; mn_m = mn + c;
    float var = fmaf(-meanv, meanv, sq * inv);
    std_m = sqrtf(fmaxf(var, 0.f) + 1e-5f);
  } else {
    sum_m = 0.f; mean_m = 0.f; mx_m = 0.f; mn_m = 0.f; std_m = sqrtf(1e-5f);
  }
  if (g == 0) {
    float* vr = vec96 + (size_t)node * 96;
    vr[f]      = x[(size_t)node * 16 + f];
    vr[16 + f] = sum_m;
    vr[32 + f] = mean_m;
    vr[48 + f] = mx_m;
    vr[64 + f] = mn_m;
    vr[80 + f] = std_m;
  }
}

// ---------------- layer 1 aggregation: one node per 64-thread block ----------------
__global__ __launch_bounds__(64) void k_agg1(const float* __restrict__ xA1,
                                             const unsigned short* __restrict__ xB1b,
                                             const int* __restrict__ rowptr,
                                             const int* __restrict__ col,
                                             const float4* __restrict__ eap,
                                             const float* __restrict__ wbuf,
                                             unsigned short* __restrict__ agg320b) {
  const int f = threadIdx.x;            // 0..63
  const int node = blockIdx.x;
  const int start = rowptr[node], end = rowptr[node + 1];
  const int cnt = end - start;
  const float c0 = wbuf[OFF_C1 + f],       c1v = wbuf[OFF_C1 + 64 + f];
  const float c2v = wbuf[OFF_C1 + 128 + f], c3v = wbuf[OFF_C1 + 192 + f];
  float s = 0.f, sq = 0.f, mx = -__builtin_inff(), mn = __builtin_inff();
  int p = start;
  for (; p + 7 < end; p += 8) {
#pragma unroll
    for (int u = 0; u < 8; u++) {
      int si = col[p + u];                                   // scalar load
      float4 e = eap[p + u];                                 // scalar dwordx4
      const unsigned short* row = xB1b + (unsigned)si * 64;  // SALU base
      float v = bf_s(row[f]);                                // 128B coalesced gather
      v = fmaf(e.x, c0, v); v = fmaf(e.y, c1v, v);
      v = fmaf(e.z, c2v, v); v = fmaf(e.w, c3v, v);
      s += v; sq = fmaf(v, v, sq); mx = fmaxf(mx, v); mn = fminf(mn, v);
    }
  }
  for (; p < end; p++) {
    int si = col[p];
    float4 e = eap[p];
    const unsigned short* row = xB1b + (unsigned)si * 64;
    float v = bf_s(row[f]);
    v = fmaf(e.x, c0, v); v = fmaf(e.y, c1v, v);
    v = fmaf(e.z, c2v, v); v = fmaf(e.w, c3v, v);
    s += v; sq = fmaf(v, v, sq); mx = fmaxf(mx, v); mn = fminf(mn, v);
  }
  const float c = xA1[(size_t)node * 64 + f] + wbuf[OFF_D1 + f];
  float sum_m, mean_m, mx_m, mn_m, std_m;
  if (cnt > 0) {
    float inv = 1.f / (float)cnt;
    float meanv = s * inv;
    sum_m = fmaf((float)cnt, c, s);
    mean_m = meanv + c;
    mx_m = mx + c; mn_m = mn + c;
    float var = fmaf(-meanv, meanv, sq * inv);
    std_m = sqrtf(fmaxf(var, 0.f) + 1e-5f);
  } else {
    sum_m = 0.f; mean_m = 0.f; mx_m = 0.f; mn_m = 0.f; std_m = sqrtf(1e-5f);
  }
  unsigned short* ar = agg320b + (size_t)node * 320;
  ar[f]       = pack_bf16(sum_m);
  ar[64 + f]  = pack_bf16(mean_m);
  ar[128 + f] = pack_bf16(mx_m);
  ar[192 + f] = pack_bf16(mn_m);
  ar[256 + f] = pack_bf16(std_m);
}

// ---------------- tiled fp32 GEMM: C[n,64] = [A1|A2][n,KT] @ B[KT,64] ----
// OMODE: 0 = fp32 C, 1 = bf16 C, 2 = fp32 C + bf16 C2.
template <int KT, int K1, bool RELU, int OMODE>
__global__ __launch_bounds__(256) void k_gemm(const float* __restrict__ A1,
                                              const float* __restrict__ A2,
                                              const float* __restrict__ B,
                                              const float* __restrict__ bias,
                                              void* __restrict__ C,
                                              void* __restrict__ C2, int n) {
  __shared__ float As[32][128];
  __shared__ float Bs[32][64];
  const int tid = threadIdx.x;
  const int tm = tid & 31, tf = tid >> 5;
  const int m0 = blockIdx.x * 128;
  float acc[4][8];
#pragma unroll
  for (int i = 0; i < 4; i++)
#pragma unroll
    for (int j = 0; j < 8; j++) acc[i][j] = 0.f;

  for (int k0 = 0; k0 < KT; k0 += 32) {
    {
      int ml = tid & 127;
      int m = m0 + ml;
      int qh = tid >> 7;
      if (m < n) {
#pragma unroll
        for (int q = 0; q < 4; q++) {
          int kk = qh * 16 + q * 4;
          int kg = k0 + kk;
          float4 v;
          if (kg < K1) v = *(const float4*)(A1 + (size_t)m * K1 + kg);
          else         v = *(const float4*)(A2 + (size_t)m * (KT - K1) + (kg - K1));
          As[kk + 0][ml] = v.x; As[kk + 1][ml] = v.y;
          As[kk + 2][ml] = v.z; As[kk + 3][ml] = v.w;
        }
      } else {
#pragma unroll
        for (int q = 0; q < 4; q++) {
          int kk = qh * 16 + q * 4;
          As[kk][ml] = 0.f; As[kk + 1][ml] = 0.f; As[kk + 2][ml] = 0.f; As[kk + 3][ml] = 0.f;
        }
      }
    }
    {
      int kb = tid >> 3;
      int fb = (tid & 7) * 8;
      const float4* br = (const float4*)(B + (size_t)(k0 + kb) * 64 + fb);
      float4 b0 = br[0], b1 = br[1];
      *(float4*)&Bs[kb][fb] = b0;
      *(float4*)&Bs[kb][fb + 4] = b1;
    }
    __syncthreads();
#pragma unroll 8
    for (int k = 0; k < 32; k++) {
      float av[4], bv[8];
      *(float4*)&av[0] = *(const float4*)&As[k][tm * 4];
      *(float4*)&bv[0] = *(const float4*)&Bs[k][tf * 8];
      *(float4*)&bv[4] = *(const float4*)&Bs[k][tf * 8 + 4];
#pragma unroll
      for (int i = 0; i < 4; i++)
#pragma unroll
        for (int j = 0; j < 8; j++) acc[i][j] = fmaf(av[i], bv[j], acc[i][j]);
    }
    __syncthreads();
  }
  float bb[8];
#pragma unroll
  for (int j = 0; j < 8; j++) bb[j] = bias ? bias[tf * 8 + j] : 0.f;
#pragma unroll
  for (int i = 0; i < 4; i++) {
    int m = m0 + tm * 4 + i;
    if (m < n) {
      float vv[8];
#pragma unroll
      for (int j = 0; j < 8; j++) {
        float v = acc[i][j] + bb[j];
        vv[j] = RELU ? fmaxf(v, 0.f) : v;
      }
      if (OMODE == 0 || OMODE == 2) {
        float4* cp = (float4*)((float*)C + (size_t)m * 64 + tf * 8);
        cp[0] = make_float4(vv[0], vv[1], vv[2], vv[3]);
        cp[1] = make_float4(vv[4], vv[5], vv[6], vv[7]);
      }
      if (OMODE == 1 || OMODE == 2) {
        uint4 pk;
        pk.x = pack_bf16x2(vv[0], vv[1]); pk.y = pack_bf16x2(vv[2], vv[3]);
        pk.z = pack_bf16x2(vv[4], vv[5]); pk.w = pack_bf16x2(vv[6], vv[7]);
        void* dst = (OMODE == 1) ? C : C2;
        *(uint4*)((unsigned short*)dst + (size_t)m * 64 + tf * 8) = pk;
      }
    }
  }
}

// ---------------- MFMA GEMM: h2[n,64] = relu([hb|aggb][n,384]_bf16 @ Btb^T + bias) ----
__global__ __launch_bounds__(256) void k_mm384(const unsigned short* __restrict__ hb,
                                               const unsigned short* __restrict__ aggb,
                                               const unsigned short* __restrict__ Btb,
                                               const float* __restrict__ wbuf,
                                               float* __restrict__ h2, int n) {
  using bf16x8 = __attribute__((ext_vector_type(8))) short;
  using f32x4  = __attribute__((ext_vector_type(4))) float;
  const int wave = threadIdx.x >> 6, lane = threadIdx.x & 63;
  const int qm = lane & 15, quad = lane >> 4;
  const int m0 = blockIdx.x * 64 + wave * 16;
  const int mrow = m0 + qm;                    // A-fragment row (padded buffers)
  f32x4 acc[4] = {};
  for (int k0 = 0; k0 < 384; k0 += 32) {
    bf16x8 a;
    if (k0 < 64) a = *(const bf16x8*)(hb + (size_t)mrow * 64 + k0 + quad * 8);
    else         a = *(const bf16x8*)(aggb + (size_t)mrow * 320 + (k0 - 64) + quad * 8);
#pragma unroll
    for (int nt = 0; nt < 4; nt++) {
      bf16x8 b = *(const bf16x8*)(Btb + (size_t)(nt * 16 + qm) * 384 + k0 + quad * 8);
      acc[nt] = __builtin_amdgcn_mfma_f32_16x16x32_bf16(a, b, acc[nt], 0, 0, 0);
    }
  }
#pragma unroll
  for (int nt = 0; nt < 4; nt++) {
    int colc = nt * 16 + qm;
    float bias = wbuf[OFF_BPL1 + colc];
#pragma unroll
    for (int r = 0; r < 4; r++) {
      int m = m0 + quad * 4 + r;
      if (m < n) h2[(size_t)m * 64 + colc] = fmaxf(acc[nt][r] + bias, 0.f);
    }
  }
}

// ---------------- GCN prep: hgsb = bf16((h2 @ Wg) * dinv) ----------------
__global__ void k_gcnprep(const float* __restrict__ h2, const float* __restrict__ Wg,
                          const int* __restrict__ rowptr,
                          unsigned short* __restrict__ hgsb, float* __restrict__ dinv) {
  int t = blockIdx.x * 256 + threadIdx.x;   // NN*16 threads
  int node = t >> 4, f = t & 15;
  const float* hr = h2 + (size_t)node * 64;
  float a = 0.f;
#pragma unroll
  for (int j = 0; j < 64; j++) a = fmaf(hr[j], Wg[j * 16 + f], a);
  int dg = rowptr[node + 1] - rowptr[node] + 1;  // +1 self loop
  float dv = 1.0f / sqrtf((float)dg);
  hgsb[(size_t)node * 16 + f] = pack_bf16(a * dv);
  if (f == 0) dinv[node] = dv;
}

// ---------------- GCN aggregate + MLP head ----------------
// hgsb is 3.2MB -> fits one XCD's 4MB L2; 4x-unrolled gather loop keeps
// 4 independent col-load->gather chains in flight.
__global__ __launch_bounds__(256) void k_head(const float* __restrict__ x,
                                              const unsigned short* __restrict__ hgsb,
                                              const float* __restrict__ dinv,
                                              const int* __restrict__ rowptr,
                                              const int* __restrict__ col,
                                              const float* __restrict__ bg,
                                              const float* __restrict__ Wh1,
                                              const float* __restrict__ bh1,
                                              const float* __restrict__ Wh2,
                                              const float* __restrict__ bh2,
                                              float* __restrict__ out) {
  __shared__ float zb[4][32];
  __shared__ float o1b[4][10];
  const int w = threadIdx.x >> 6, lane = threadIdx.x & 63;
  const int g = lane >> 4, f = lane & 15;
  const int node = blockIdx.x * 4 + w;
  const int start = rowptr[node], end = rowptr[node + 1];
  float s = 0.f;
  int p = start + g;
  for (; p + 12 < end; p += 16) {
    int s0 = col[p], s1 = col[p + 4], s2 = col[p + 8], s3 = col[p + 12];
    float v0 = bf_s(hgsb[(size_t)s0 * 16 + f]);
    float v1 = bf_s(hgsb[(size_t)s1 * 16 + f]);
    float v2 = bf_s(hgsb[(size_t)s2 * 16 + f]);
    float v3 = bf_s(hgsb[(size_t)s3 * 16 + f]);
    s += (v0 + v1) + (v2 + v3);
  }
  for (; p < end; p += 4) {
    int si = col[p];
    s += bf_s(hgsb[(size_t)si * 16 + f]);
  }
  s += __shfl_xor(s, 16); s += __shfl_xor(s, 32);
  if (g == 0) {
    float gout = (s + bf_s(hgsb[(size_t)node * 16 + f])) * dinv[node] + bg[f];
    zb[w][f] = gout;
    zb[w][16 + f] = x[(size_t)node * 16 + f];
  }
  __syncthreads();
  if (lane < 10) {
    float a = bh1[lane];
#pragma unroll
    for (int k = 0; k < 32; k++) a = fmaf(zb[w][k], Wh1[k * 10 + lane], a);
    o1b[w][lane] = fmaxf(a, 0.f);
  }
  __syncthreads();
  if (lane < 10) {
    float a = bh2[lane];
#pragma unroll
    for (int j = 0; j < 10; j++) a = fmaf(o1b[w][j], Wh2[j * 10 + lane], a);
    out[(size_t)node * 10 + lane] = a;
  }
}

// ---------------- launcher ----------------
extern "C" void kernel_launch(void* const* d_in, const int* in_sizes, int n_in,
                              void* d_out, int out_size, void* d_ws, size_t ws_size,
                              hipStream_t stream) {
  const float* x      = (const float*)d_in[0];
  const int*   ei     = (const int*)d_in[1];
  const float* eattr  = (const float*)d_in[2];
  const float* We0    = (const float*)d_in[3];
  const float* be0    = (const float*)d_in[4];
  const float* Wpre0  = (const float*)d_in[5];
  const float* bpre0  = (const float*)d_in[6];
  const float* Wpost0 = (const float*)d_in[7];
  const float* bpost0 = (const float*)d_in[8];
  const float* Wlin0  = (const float*)d_in[9];
  const float* blin0  = (const float*)d_in[10];
  const float* We1    = (const float*)d_in[11];
  const float* be1    = (const float*)d_in[12];
  const float* Wpre1  = (const float*)d_in[13];
  const float* bpre1  = (const float*)d_in[14];
  const float* Wpost1 = (const float*)d_in[15];
  const float* bpost1 = (const float*)d_in[16];
  const float* Wlin1  = (const float*)d_in[17];
  const float* blin1  = (const float*)d_in[18];
  const float* Wg     = (const float*)d_in[19];
  const float* bg     = (const float*)d_in[20];
  const float* Wh1    = (const float*)d_in[21];
  const float* bh1    = (const float*)d_in[22];
  const float* Wh2    = (const float*)d_in[23];
  const float* bh2    = (const float*)d_in[24];
  const int* srcI = ei;
  const int* dstI = ei + NE;
  float* out = (float*)d_out;

  char* base = (char*)d_ws;
  size_t off = 0;
  auto take = [&](size_t bytes) -> char* {
    char* p = base + off;
    off += (bytes + 255) & ~(size_t)255;
    return p;
  };
  int* cnt     = (int*)take((size_t)NN * 4);
  int* rowptr  = (int*)take((size_t)(NN + 1) * 4);
  int* fill    = (int*)take((size_t)NN * 4);
  int* partial = (int*)take((size_t)NN * 4);
  int* bsums   = (int*)take(512 * 4);
  int* boff    = (int*)take(512 * 4);
  int* gfill   = (int*)take(512 * 4);
  unsigned short* Btb = (unsigned short*)take(64 * 384 * 2);
  int* col     = (int*)take((size_t)NE * 4);
  float4* eap  = (float4*)take((size_t)NE * 16);     // 25.6MB; aliased by h2 later
  float* h2    = (float*)eap;                        // h2 [NN,64], alive after eap dies
  float* wbuf  = (float*)take((size_t)WBUF_TOT * 4);
  float* h     = (float*)take((size_t)NN * 64 * 4);
  int*   perm  = (int*)h;                            // perm [NE] = 6.4MB, dead before h written
  float* xA1   = (float*)take((size_t)NN * 64 * 4);
  int2*  rec   = (int2*)take((size_t)NE * 8);        // 12.8MB
  unsigned short* xB1b = (unsigned short*)rec;       // xB1 bf16 [NN,64], after rec dies
  // region Z (128MB): vec96/xA0/xB0 early -> agg320b (64MB) + hb mid -> hgsb/dinv late
  char* Z = take((size_t)NN * 320 * 4);
  unsigned short* agg320b = (unsigned short*)Z;                  // [0 .. 64MB)
  float* vec96  = (float*)Z;                                     // [0 .. 38.4MB)
  float* xA0    = (float*)(Z + (size_t)NN * 96 * 4);
  float* xB0    = (float*)(Z + (size_t)NN * 96 * 4 + (size_t)NN * 16 * 4);
  unsigned short* hb = (unsigned short*)(Z + (size_t)96 * 1024 * 1024);  // [96MB..108.8MB)
  unsigned short* hgsb = (unsigned short*)Z;                     // 3.2MB
  float* dinv   = (float*)(Z + (size_t)NN * 16 * 4);

  hipMemsetAsync(cnt, 0, (size_t)NN * 4, stream);
  k_prep<<<(WBUF_TOT + 255) / 256, 256, 0, stream>>>(
      We0, be0, Wpre0, bpre0, Wpost0, bpost0, Wlin0, blin0,
      We1, be1, Wpre1, bpre1, Wpost1, bpost1, Wlin1, blin1, wbuf);
  k_bt<<<64, 384, 0, stream>>>(wbuf, Btb);
  k_hist<<<(NE + 255) / 256, 256, 0, stream>>>(dstI, cnt);
  k_scan1<<<391, 256, 0, stream>>>(cnt, partial, bsums);
  k_scan2<<<1, 512, 0, stream>>>(bsums, boff, 391);
  k_scan3<<<391, 256, 0, stream>>>(partial, boff, cnt, rowptr, fill);
  k_binit<<<1, 256, 0, stream>>>(rowptr, gfill);
  k_bin<<<256, 256, 0, stream>>>(dstI, gfill, rec);
  k_scatter2<<<NB, 256, 0, stream>>>(rec, rowptr, perm);
  k_permute<<<(NE + 255) / 256, 256, 0, stream>>>(perm, srcI, (const float4*)eattr,
                                                  col, eap);
  k_pre0<<<NN * 32 / 256, 256, 0, stream>>>(x, Wpre0, xA0, xB0);
  k_agg0<<<NN / 4, 256, 0, stream>>>(x, xA0, xB0, rowptr, col, eap, wbuf, vec96);
  k_gemm<96, 96, true, 2><<<(NN + 127) / 128, 256, 0, stream>>>(
      vec96, vec96, wbuf + OFF_WPL0, wbuf + OFF_BPL0, h, hb, NN);
  k_gemm<64, 64, false, 0><<<(NN + 127) / 128, 256, 0, stream>>>(
      h, h, Wpre1, nullptr, xA1, nullptr, NN);
  k_gemm<64, 64, false, 1><<<(NN + 127) / 128, 256, 0, stream>>>(
      h, h, Wpre1 + 64 * 64, nullptr, xB1b, nullptr, NN);
  k_agg1<<<NN, 64, 0, stream>>>(xA1, xB1b, rowptr, col, eap, wbuf, agg320b);
  k_mm384<<<(NN + 63) / 64, 256, 0, stream>>>(hb, agg320b, Btb, wbuf, h2, NN);
  k_gcnprep<<<NN * 16 / 256, 256, 0, stream>>>(h2, Wg, rowptr, hgsb, dinv);
  k_head<<<NN / 4, 256, 0, stream>>>(x, hgsb, dinv, rowptr, col, bg, Wh1, bh1,
                                     Wh2, bh2, out);
}

// Round 9
// 593.946 us; speedup vs baseline: 1.2519x; 1.0984x over previous
//
#include <hip/hip_runtime.h>

#define NN 100000
#define NE 1600000

// bucketing for two-level CSR sort
#define BSH 9                      // 512 nodes per bucket
#define BSZ (1 << BSH)
#define NB  196                    // ceil(NN / 512)
#define CHUNK 6250                 // NE / 256

// folded-weight buffer layout (float offsets)
#define OFF_C0   0
#define OFF_D0   64
#define OFF_WPL0 80
#define OFF_BPL0 6224
#define OFF_C1   6288
#define OFF_D1   6544
#define OFF_WPL1 6608
#define OFF_BPL1 31184
#define WBUF_TOT 31248

// transposed bf16 B-matrix buffer layout (ushort offsets)
#define BT1_OFF 0          // WPL1^T  [64][384]
#define BT0_OFF 24576      // WPL0^T  [64][96]
#define BTA_OFF 30720      // Wpre1A^T [64][64]
#define BTB_OFF 34816      // Wpre1B^T [64][64]
#define BT_TOT  38912

// ---- bf16 helpers (RNE pack, cheap unpack) ----
__device__ inline unsigned short pack_bf16(float a) {
  unsigned ua = __float_as_uint(a);
  ua += 0x7fffu + ((ua >> 16) & 1u);
  return (unsigned short)(ua >> 16);
}
__device__ inline float bf_s(unsigned short u) { return __uint_as_float(((unsigned)u) << 16); }

// ---------------- weight folding ----------------
__global__ void k_prep(const float* __restrict__ We0, const float* __restrict__ be0,
                       const float* __restrict__ Wpre0, const float* __restrict__ bpre0,
                       const float* __restrict__ Wpost0, const float* __restrict__ bpost0,
                       const float* __restrict__ Wlin0, const float* __restrict__ blin0,
                       const float* __restrict__ We1, const float* __restrict__ be1,
                       const float* __restrict__ Wpre1, const float* __restrict__ bpre1,
                       const float* __restrict__ Wpost1, const float* __restrict__ bpost1,
                       const float* __restrict__ Wlin1, const float* __restrict__ blin1,
                       float* __restrict__ wbuf) {
  int id = blockIdx.x * 256 + threadIdx.x;
  if (id >= WBUF_TOT) return;
  float a = 0.f;
  if (id < OFF_D0) {
    int j = id >> 4, f = id & 15;
    for (int t = 0; t < 16; t++) a = fmaf(We0[j*16+t], Wpre0[(32+t)*16+f], a);
  } else if (id < OFF_WPL0) {
    int f = id - OFF_D0; a = bpre0[f];
    for (int t = 0; t < 16; t++) a = fmaf(be0[t], Wpre0[(32+t)*16+f], a);
  } else if (id < OFF_BPL0) {
    int r = id - OFF_WPL0; int k = r >> 6, o = r & 63;
    for (int j = 0; j < 64; j++) a = fmaf(Wpost0[k*64+j], Wlin0[j*64+o], a);
  } else if (id < OFF_C1) {
    int o = id - OFF_BPL0; a = blin0[o];
    for (int j = 0; j < 64; j++) a = fmaf(bpost0[j], Wlin0[j*64+o], a);
  } else if (id < OFF_D1) {
    int r = id - OFF_C1; int j = r >> 6, f = r & 63;
    for (int t = 0; t < 64; t++) a = fmaf(We1[j*64+t], Wpre1[(128+t)*64+f], a);
  } else if (id < OFF_WPL1) {
    int f = id - OFF_D1; a = bpre1[f];
    for (int t = 0; t < 64; t++) a = fmaf(be1[t], Wpre1[(128+t)*64+f], a);
  } else if (id < OFF_BPL1) {
    int r = id - OFF_WPL1; int k = r >> 6, o = r & 63;
    for (int j = 0; j < 64; j++) a = fmaf(Wpost1[k*64+j], Wlin1[j*64+o], a);
  } else {
    int o = id - OFF_BPL1; a = blin1[o];
    for (int j = 0; j < 64; j++) a = fmaf(bpost1[j], Wlin1[j*64+o], a);
  }
  wbuf[id] = a;
}

// transpose+bf16 all dense B matrices.  block = output row nn (0..63),
// thread k indexes the concatenated K dims (384 | 96 | 64 | 64).
__global__ void k_bt(const float* __restrict__ wbuf, const float* __restrict__ Wpre1,
                     unsigned short* __restrict__ Bt) {
  int nn = blockIdx.x;
  int k  = threadIdx.x;
  if (k < 384) {
    Bt[BT1_OFF + nn * 384 + k] = pack_bf16(wbuf[OFF_WPL1 + k * 64 + nn]);
  } else if (k < 480) {
    int kk = k - 384;
    Bt[BT0_OFF + nn * 96 + kk] = pack_bf16(wbuf[OFF_WPL0 + kk * 64 + nn]);
  } else if (k < 544) {
    int kk = k - 480;
    Bt[BTA_OFF + nn * 64 + kk] = pack_bf16(Wpre1[kk * 64 + nn]);
  } else if (k < 608) {
    int kk = k - 544;
    Bt[BTB_OFF + nn * 64 + kk] = pack_bf16(Wpre1[(64 + kk) * 64 + nn]);
  }
}

// ---------------- CSR build ----------------
__global__ void k_hist(const int* __restrict__ dst, int* __restrict__ cnt) {
  int i = blockIdx.x * 256 + threadIdx.x;
  if (i < NE) atomicAdd(&cnt[dst[i]], 1);
}

__global__ void k_scan1(const int* __restrict__ deg, int* __restrict__ partial,
                        int* __restrict__ bsums) {
  __shared__ int lds[256];
  int i = blockIdx.x * 256 + threadIdx.x;
  int v = (i < NN) ? deg[i] : 0;
  lds[threadIdx.x] = v;
  __syncthreads();
  for (int off = 1; off < 256; off <<= 1) {
    int t = (threadIdx.x >= off) ? lds[threadIdx.x - off] : 0;
    __syncthreads();
    lds[threadIdx.x] += t;
    __syncthreads();
  }
  if (i < NN) partial[i] = lds[threadIdx.x];
  if (threadIdx.x == 255) bsums[blockIdx.x] = lds[255];
}

__global__ void k_scan2(const int* __restrict__ bsums, int* __restrict__ boff, int nb) {
  __shared__ int lds[512];
  int v = ((int)threadIdx.x < nb) ? bsums[threadIdx.x] : 0;
  lds[threadIdx.x] = v;
  __syncthreads();
  for (int off = 1; off < 512; off <<= 1) {
    int t = (threadIdx.x >= off) ? lds[threadIdx.x - off] : 0;
    __syncthreads();
    lds[threadIdx.x] += t;
    __syncthreads();
  }
  if ((int)threadIdx.x < nb) boff[threadIdx.x] = lds[threadIdx.x] - v;  // exclusive
}

__global__ void k_scan3(const int* __restrict__ partial, const int* __restrict__ boff,
                        const int* __restrict__ deg, int* __restrict__ rowptr,
                        int* __restrict__ fill) {
  int i = blockIdx.x * 256 + threadIdx.x;
  if (i < NN) {
    int incl = partial[i] + boff[blockIdx.x];
    rowptr[i + 1] = incl;
    fill[i] = incl - deg[i];
  }
  if (i == 0) rowptr[0] = 0;
}

__global__ void k_binit(const int* __restrict__ rowptr, int* __restrict__ gfill) {
  int b = threadIdx.x;
  if (b < NB) {
    int n0 = b << BSH;
    gfill[b] = rowptr[n0 > NN ? NN : n0];
  }
}

// pass 1: LDS-binned coarse sort
__global__ __launch_bounds__(256) void k_bin(const int* __restrict__ dst,
                                             int* __restrict__ gfill,
                                             int2* __restrict__ rec) {
  __shared__ int hcnt[NB];
  __shared__ int hbase[NB];
  const int t = threadIdx.x;
  for (int b = t; b < NB; b += 256) hcnt[b] = 0;
  __syncthreads();
  const int lo = blockIdx.x * CHUNK, hi = lo + CHUNK;
  for (int i = lo + t; i < hi; i += 256)
    atomicAdd(&hcnt[dst[i] >> BSH], 1);
  __syncthreads();
  for (int b = t; b < NB; b += 256) {
    int c = hcnt[b];
    hbase[b] = c > 0 ? atomicAdd(&gfill[b], c) : 0;
    hcnt[b] = 0;
  }
  __syncthreads();
  for (int i = lo + t; i < hi; i += 256) {
    int d = dst[i];
    int b = d >> BSH;
    int lp = atomicAdd(&hcnt[b], 1);
    rec[hbase[b] + lp] = make_int2(d, i);
  }
}

// pass 2: in-bucket scatter (L2-resident window)
__global__ __launch_bounds__(256) void k_scatter2(const int2* __restrict__ rec,
                                                  const int* __restrict__ rowptr,
                                                  int* __restrict__ perm) {
  __shared__ int lfill[BSZ];
  const int b = blockIdx.x;
  const int n0 = b << BSH;
  const int n1 = (n0 + BSZ < NN) ? n0 + BSZ : NN;
  const int t = threadIdx.x;
  for (int n = n0 + t; n < n1; n += 256) lfill[n - n0] = rowptr[n];
  __syncthreads();
  const int lo = rowptr[n0], hi = rowptr[n1];
  for (int i = lo + t; i < hi; i += 256) {
    int2 r = rec[i];
    int pos = atomicAdd(&lfill[r.x - n0], 1);
    perm[pos] = r.y;
  }
}

// pass 3: gather-permute
__global__ void k_permute(const int* __restrict__ perm, const int* __restrict__ src,
                          const float4* __restrict__ ea, int* __restrict__ col,
                          float4* __restrict__ eap) {
  int i = blockIdx.x * 256 + threadIdx.x;
  if (i < NE) {
    int eid = perm[i];
    col[i] = src[eid];
    eap[i] = ea[eid];
  }
}

// ---------------- layer 0 node pre-projection ----------------
__global__ void k_pre0(const float* __restrict__ x, const float* __restrict__ Wpre0,
                       float* __restrict__ xA0, unsigned short* __restrict__ xB0b) {
  int t = blockIdx.x * 256 + threadIdx.x;   // NN*32 threads
  int node = t >> 5, k = t & 31;
  int f = k & 15;
  const float* W = Wpre0 + (k < 16 ? 0 : 256);
  const float* xr = x + (size_t)node * 16;
  float a = 0.f;
#pragma unroll
  for (int j = 0; j < 16; j++) a = fmaf(xr[j], W[j*16+f], a);
  if (k < 16) xA0[(size_t)node*16+f] = a;
  else        xB0b[(size_t)node*16+f] = pack_bf16(a);
}

// ---------------- layer 0 aggregation (bf16 xB0, 2-edge unroll/group) ----------------
__global__ __launch_bounds__(256) void k_agg0(const float* __restrict__ x,
                                              const float* __restrict__ xA0,
                                              const unsigned short* __restrict__ xB0b,
                                              const int* __restrict__ rowptr,
                                              const int* __restrict__ col,
                                              const float4* __restrict__ eap,
                                              const float* __restrict__ wbuf,
                                              unsigned short* __restrict__ vec96b) {
  const int w = threadIdx.x >> 6, lane = threadIdx.x & 63;
  const int g = lane >> 4, f = lane & 15;
  const int node = blockIdx.x * 4 + w;
  const int start = rowptr[node], end = rowptr[node + 1];
  const int cnt = end - start;
  const float c0 = wbuf[OFF_C0 + f],      c1v = wbuf[OFF_C0 + 16 + f];
  const float c2v = wbuf[OFF_C0 + 32 + f], c3v = wbuf[OFF_C0 + 48 + f];
  float s = 0.f, sq = 0.f, mx = -__builtin_inff(), mn = __builtin_inff();
  int p = start + g;
  for (; p + 4 < end; p += 8) {
    int s0 = col[p], s1 = col[p + 4];
    float4 e0 = eap[p], e1 = eap[p + 4];
    float v0 = bf_s(xB0b[(size_t)s0 * 16 + f]);
    float v1 = bf_s(xB0b[(size_t)s1 * 16 + f]);
    v0 = fmaf(e0.x, c0, v0); v0 = fmaf(e0.y, c1v, v0);
    v0 = fmaf(e0.z, c2v, v0); v0 = fmaf(e0.w, c3v, v0);
    v1 = fmaf(e1.x, c0, v1); v1 = fmaf(e1.y, c1v, v1);
    v1 = fmaf(e1.z, c2v, v1); v1 = fmaf(e1.w, c3v, v1);
    s += v0 + v1;
    sq = fmaf(v0, v0, sq); sq = fmaf(v1, v1, sq);
    mx = fmaxf(mx, fmaxf(v0, v1)); mn = fminf(mn, fminf(v0, v1));
  }
  for (; p < end; p += 4) {
    int si = col[p];
    float4 e0 = eap[p];
    float v = bf_s(xB0b[(size_t)si * 16 + f]);
    v = fmaf(e0.x, c0, v); v = fmaf(e0.y, c1v, v);
    v = fmaf(e0.z, c2v, v); v = fmaf(e0.w, c3v, v);
    s += v; sq = fmaf(v, v, sq); mx = fmaxf(mx, v); mn = fminf(mn, v);
  }
  s  += __shfl_xor(s, 16);  s  += __shfl_xor(s, 32);
  sq += __shfl_xor(sq, 16); sq += __shfl_xor(sq, 32);
  mx = fmaxf(mx, __shfl_xor(mx, 16)); mx = fmaxf(mx, __shfl_xor(mx, 32));
  mn = fminf(mn, __shfl_xor(mn, 16)); mn = fminf(mn, __shfl_xor(mn, 32));
  const float c = xA0[(size_t)node * 16 + f] + wbuf[OFF_D0 + f];
  float sum_m, mean_m, mx_m, mn_m, std_m;
  if (cnt > 0) {
    float inv = 1.f / (float)cnt;
    float meanv = s * inv;
    sum_m = fmaf((float)cnt, c, s);
    mean_m = meanv + c;
    mx_m = mx + c; mn_m = mn + c;
    float var = fmaf(-meanv, meanv, sq * inv);
    std_m = sqrtf(fmaxf(var, 0.f) + 1e-5f);
  } else {
    sum_m = 0.f; mean_m = 0.f; mx_m = 0.f; mn_m = 0.f; std_m = sqrtf(1e-5f);
  }
  if (g == 0) {
    unsigned short* vr = vec96b + (size_t)node * 96;
    vr[f]      = pack_bf16(x[(size_t)node * 16 + f]);
    vr[16 + f] = pack_bf16(sum_m);
    vr[32 + f] = pack_bf16(mean_m);
    vr[48 + f] = pack_bf16(mx_m);
    vr[64 + f] = pack_bf16(mn_m);
    vr[80 + f] = pack_bf16(std_m);
  }
}

// ---------------- layer 1 aggregation: one node per 64-thread block ----------------
__global__ __launch_bounds__(64) void k_agg1(const float* __restrict__ xA1,
                                             const unsigned short* __restrict__ xB1b,
                                             const int* __restrict__ rowptr,
                                             const int* __restrict__ col,
                                             const float4* __restrict__ eap,
                                             const float* __restrict__ wbuf,
                                             unsigned short* __restrict__ agg320b) {
  const int f = threadIdx.x;            // 0..63
  const int node = blockIdx.x;
  const int start = rowptr[node], end = rowptr[node + 1];
  const int cnt = end - start;
  const float c0 = wbuf[OFF_C1 + f],       c1v = wbuf[OFF_C1 + 64 + f];
  const float c2v = wbuf[OFF_C1 + 128 + f], c3v = wbuf[OFF_C1 + 192 + f];
  float s = 0.f, sq = 0.f, mx = -__builtin_inff(), mn = __builtin_inff();
  int p = start;
  for (; p + 7 < end; p += 8) {
#pragma unroll
    for (int u = 0; u < 8; u++) {
      int si = col[p + u];                                   // scalar load
      float4 e = eap[p + u];                                 // scalar dwordx4
      const unsigned short* row = xB1b + (unsigned)si * 64;  // SALU base
      float v = bf_s(row[f]);                                // 128B coalesced gather
      v = fmaf(e.x, c0, v); v = fmaf(e.y, c1v, v);
      v = fmaf(e.z, c2v, v); v = fmaf(e.w, c3v, v);
      s += v; sq = fmaf(v, v, sq); mx = fmaxf(mx, v); mn = fminf(mn, v);
    }
  }
  for (; p < end; p++) {
    int si = col[p];
    float4 e = eap[p];
    const unsigned short* row = xB1b + (unsigned)si * 64;
    float v = bf_s(row[f]);
    v = fmaf(e.x, c0, v); v = fmaf(e.y, c1v, v);
    v = fmaf(e.z, c2v, v); v = fmaf(e.w, c3v, v);
    s += v; sq = fmaf(v, v, sq); mx = fmaxf(mx, v); mn = fminf(mn, v);
  }
  const float c = xA1[(size_t)node * 64 + f] + wbuf[OFF_D1 + f];
  float sum_m, mean_m, mx_m, mn_m, std_m;
  if (cnt > 0) {
    float inv = 1.f / (float)cnt;
    float meanv = s * inv;
    sum_m = fmaf((float)cnt, c, s);
    mean_m = meanv + c;
    mx_m = mx + c; mn_m = mn + c;
    float var = fmaf(-meanv, meanv, sq * inv);
    std_m = sqrtf(fmaxf(var, 0.f) + 1e-5f);
  } else {
    sum_m = 0.f; mean_m = 0.f; mx_m = 0.f; mn_m = 0.f; std_m = sqrtf(1e-5f);
  }
  unsigned short* ar = agg320b + (size_t)node * 320;
  ar[f]       = pack_bf16(sum_m);
  ar[64 + f]  = pack_bf16(mean_m);
  ar[128 + f] = pack_bf16(mx_m);
  ar[192 + f] = pack_bf16(mn_m);
  ar[256 + f] = pack_bf16(std_m);
}

// ---------------- MFMA GEMM: C[n,64] = (relu)(A[n,K]_bf16 @ Bt^T + bias) ----------------
// OMODE: 0 = fp32 out, 1 = bf16 out.
template <int K, bool RELU, int OMODE>
__global__ __launch_bounds__(256) void k_mmf(const unsigned short* __restrict__ A,
                                             const unsigned short* __restrict__ Bt,
                                             const float* __restrict__ bias,
                                             void* __restrict__ C, int n) {
  using bf16x8 = __attribute__((ext_vector_type(8))) short;
  using f32x4  = __attribute__((ext_vector_type(4))) float;
  const int wave = threadIdx.x >> 6, lane = threadIdx.x & 63;
  const int qm = lane & 15, quad = lane >> 4;
  const int m0 = blockIdx.x * 64 + wave * 16;
  const int mrow = m0 + qm;
  f32x4 acc[4] = {};
#pragma unroll
  for (int k0 = 0; k0 < K; k0 += 32) {
    bf16x8 a = *(const bf16x8*)(A + (size_t)mrow * K + k0 + quad * 8);
#pragma unroll
    for (int nt = 0; nt < 4; nt++) {
      bf16x8 b = *(const bf16x8*)(Bt + (size_t)(nt * 16 + qm) * K + k0 + quad * 8);
      acc[nt] = __builtin_amdgcn_mfma_f32_16x16x32_bf16(a, b, acc[nt], 0, 0, 0);
    }
  }
#pragma unroll
  for (int nt = 0; nt < 4; nt++) {
    int colc = nt * 16 + qm;
    float bb = bias ? bias[colc] : 0.f;
#pragma unroll
    for (int r = 0; r < 4; r++) {
      int m = m0 + quad * 4 + r;
      if (m < n) {
        float v = acc[nt][r] + bb;
        if (RELU) v = fmaxf(v, 0.f);
        if (OMODE == 0) ((float*)C)[(size_t)m * 64 + colc] = v;
        else ((unsigned short*)C)[(size_t)m * 64 + colc] = pack_bf16(v);
      }
    }
  }
}

// ---------------- MFMA GEMM: h2[n,64] = relu([hb|aggb][n,384]_bf16 @ Bt1^T + bias) ----
__global__ __launch_bounds__(256) void k_mm384(const unsigned short* __restrict__ hb,
                                               const unsigned short* __restrict__ aggb,
                                               const unsigned short* __restrict__ Btb,
                                               const float* __restrict__ wbuf,
                                               float* __restrict__ h2, int n) {
  using bf16x8 = __attribute__((ext_vector_type(8))) short;
  using f32x4  = __attribute__((ext_vector_type(4))) float;
  const int wave = threadIdx.x >> 6, lane = threadIdx.x & 63;
  const int qm = lane & 15, quad = lane >> 4;
  const int m0 = blockIdx.x * 64 + wave * 16;
  const int mrow = m0 + qm;
  f32x4 acc[4] = {};
  for (int k0 = 0; k0 < 384; k0 += 32) {
    bf16x8 a;
    if (k0 < 64) a = *(const bf16x8*)(hb + (size_t)mrow * 64 + k0 + quad * 8);
    else         a = *(const bf16x8*)(aggb + (size_t)mrow * 320 + (k0 - 64) + quad * 8);
#pragma unroll
    for (int nt = 0; nt < 4; nt++) {
      bf16x8 b = *(const bf16x8*)(Btb + (size_t)(nt * 16 + qm) * 384 + k0 + quad * 8);
      acc[nt] = __builtin_amdgcn_mfma_f32_16x16x32_bf16(a, b, acc[nt], 0, 0, 0);
    }
  }
#pragma unroll
  for (int nt = 0; nt < 4; nt++) {
    int colc = nt * 16 + qm;
    float bias = wbuf[OFF_BPL1 + colc];
#pragma unroll
    for (int r = 0; r < 4; r++) {
      int m = m0 + quad * 4 + r;
      if (m < n) h2[(size_t)m * 64 + colc] = fmaxf(acc[nt][r] + bias, 0.f);
    }
  }
}

// ---------------- GCN prep: hgsb = bf16((h2 @ Wg) * dinv) ----------------
__global__ void k_gcnprep(const float* __restrict__ h2, const float* __restrict__ Wg,
                          const int* __restrict__ rowptr,
                          unsigned short* __restrict__ hgsb, float* __restrict__ dinv) {
  int t = blockIdx.x * 256 + threadIdx.x;   // NN*16 threads
  int node = t >> 4, f = t & 15;
  const float* hr = h2 + (size_t)node * 64;
  float a = 0.f;
#pragma unroll
  for (int j = 0; j < 64; j++) a = fmaf(hr[j], Wg[j * 16 + f], a);
  int dg = rowptr[node + 1] - rowptr[node] + 1;  // +1 self loop
  float dv = 1.0f / sqrtf((float)dg);
  hgsb[(size_t)node * 16 + f] = pack_bf16(a * dv);
  if (f == 0) dinv[node] = dv;
}

// ---------------- GCN aggregate + MLP head ----------------
__global__ __launch_bounds__(256) void k_head(const float* __restrict__ x,
                                              const unsigned short* __restrict__ hgsb,
                                              const float* __restrict__ dinv,
                                              const int* __restrict__ rowptr,
                                              const int* __restrict__ col,
                                              const float* __restrict__ bg,
                                              const float* __restrict__ Wh1,
                                              const float* __restrict__ bh1,
                                              const float* __restrict__ Wh2,
                                              const float* __restrict__ bh2,
                                              float* __restrict__ out) {
  __shared__ float zb[4][32];
  __shared__ float o1b[4][10];
  const int w = threadIdx.x >> 6, lane = threadIdx.x & 63;
  const int g = lane >> 4, f = lane & 15;
  const int node = blockIdx.x * 4 + w;
  const int start = rowptr[node], end = rowptr[node + 1];
  float s = 0.f;
  int p = start + g;
  for (; p + 12 < end; p += 16) {
    int s0 = col[p], s1 = col[p + 4], s2 = col[p + 8], s3 = col[p + 12];
    float v0 = bf_s(hgsb[(size_t)s0 * 16 + f]);
    float v1 = bf_s(hgsb[(size_t)s1 * 16 + f]);
    float v2 = bf_s(hgsb[(size_t)s2 * 16 + f]);
    float v3 = bf_s(hgsb[(size_t)s3 * 16 + f]);
    s += (v0 + v1) + (v2 + v3);
  }
  for (; p < end; p += 4) {
    int si = col[p];
    s += bf_s(hgsb[(size_t)si * 16 + f]);
  }
  s += __shfl_xor(s, 16); s += __shfl_xor(s, 32);
  if (g == 0) {
    float gout = (s + bf_s(hgsb[(size_t)node * 16 + f])) * dinv[node] + bg[f];
    zb[w][f] = gout;
    zb[w][16 + f] = x[(size_t)node * 16 + f];
  }
  __syncthreads();
  if (lane < 10) {
    float a = bh1[lane];
#pragma unroll
    for (int k = 0; k < 32; k++) a = fmaf(zb[w][k], Wh1[k * 10 + lane], a);
    o1b[w][lane] = fmaxf(a, 0.f);
  }
  __syncthreads();
  if (lane < 10) {
    float a = bh2[lane];
#pragma unroll
    for (int j = 0; j < 10; j++) a = fmaf(o1b[w][j], Wh2[j * 10 + lane], a);
    out[(size_t)node * 10 + lane] = a;
  }
}

// ---------------- launcher ----------------
extern "C" void kernel_launch(void* const* d_in, const int* in_sizes, int n_in,
                              void* d_out, int out_size, void* d_ws, size_t ws_size,
                              hipStream_t stream) {
  const float* x      = (const float*)d_in[0];
  const int*   ei     = (const int*)d_in[1];
  const float* eattr  = (const float*)d_in[2];
  const float* We0    = (const float*)d_in[3];
  const float* be0    = (const float*)d_in[4];
  const float* Wpre0  = (const float*)d_in[5];
  const float* bpre0  = (const float*)d_in[6];
  const float* Wpost0 = (const float*)d_in[7];
  const float* bpost0 = (const float*)d_in[8];
  const float* Wlin0  = (const float*)d_in[9];
  const float* blin0  = (const float*)d_in[10];
  const float* We1    = (const float*)d_in[11];
  const float* be1    = (const float*)d_in[12];
  const float* Wpre1  = (const float*)d_in[13];
  const float* bpre1  = (const float*)d_in[14];
  const float* Wpost1 = (const float*)d_in[15];
  const float* bpost1 = (const float*)d_in[16];
  const float* Wlin1  = (const float*)d_in[17];
  const float* blin1  = (const float*)d_in[18];
  const float* Wg     = (const float*)d_in[19];
  const float* bg     = (const float*)d_in[20];
  const float* Wh1    = (const float*)d_in[21];
  const float* bh1    = (const float*)d_in[22];
  const float* Wh2    = (const float*)d_in[23];
  const float* bh2    = (const float*)d_in[24];
  const int* srcI = ei;
  const int* dstI = ei + NE;
  float* out = (float*)d_out;

  char* base = (char*)d_ws;
  size_t off = 0;
  auto take = [&](size_t bytes) -> char* {
    char* p = base + off;
    off += (bytes + 255) & ~(size_t)255;
    return p;
  };
  int* cnt     = (int*)take((size_t)NN * 4);
  int* rowptr  = (int*)take((size_t)(NN + 1) * 4);
  int* fill    = (int*)take((size_t)NN * 4);
  int* partial = (int*)take((size_t)NN * 4);
  int* bsums   = (int*)take(512 * 4);
  int* boff    = (int*)take(512 * 4);
  int* gfill   = (int*)take(512 * 4);
  unsigned short* Bt = (unsigned short*)take((size_t)BT_TOT * 2);
  int* col     = (int*)take((size_t)NE * 4);
  float4* eap  = (float4*)take((size_t)NE * 16);     // 25.6MB; aliased by h2 later
  float* h2    = (float*)eap;                        // h2 [NN,64], alive after eap dies
  float* wbuf  = (float*)take((size_t)WBUF_TOT * 4);
  int*   perm  = (int*)take((size_t)NE * 4);         // 6.4MB
  float* xA1   = (float*)take((size_t)NN * 64 * 4);  // 25.6MB
  int2*  rec   = (int2*)take((size_t)NE * 8);        // 12.8MB
  unsigned short* xB1b = (unsigned short*)rec;       // xB1 bf16 [NN,64], after rec dies
  // region Z (128MB): vec96b/xA0/xB0b early -> agg320b (64MB) mid -> hgsb/dinv late;
  // hb lives at +96MB throughout the middle phase.
  char* Z = take((size_t)NN * 320 * 4);
  unsigned short* vec96b  = (unsigned short*)Z;                        // 19.2MB
  float* xA0    = (float*)(Z + (size_t)NN * 96 * 2);                   // 6.4MB
  unsigned short* xB0b = (unsigned short*)(Z + (size_t)NN * 96 * 2 + (size_t)NN * 16 * 4);
  unsigned short* agg320b = (unsigned short*)Z;                        // 64MB
  unsigned short* hb = (unsigned short*)(Z + (size_t)96 * 1024 * 1024); // 12.8MB
  unsigned short* hgsb = (unsigned short*)Z;                           // 3.2MB
  float* dinv   = (float*)(Z + (size_t)NN * 16 * 2);

  hipMemsetAsync(cnt, 0, (size_t)NN * 4, stream);
  k_prep<<<(WBUF_TOT + 255) / 256, 256, 0, stream>>>(
      We0, be0, Wpre0, bpre0, Wpost0, bpost0, Wlin0, blin0,
      We1, be1, Wpre1, bpre1, Wpost1, bpost1, Wlin1, blin1, wbuf);
  k_bt<<<64, 640, 0, stream>>>(wbuf, Wpre1, Bt);
  k_hist<<<(NE + 255) / 256, 256, 0, stream>>>(dstI, cnt);
  k_scan1<<<391, 256, 0, stream>>>(cnt, partial, bsums);
  k_scan2<<<1, 512, 0, stream>>>(bsums, boff, 391);
  k_scan3<<<391, 256, 0, stream>>>(partial, boff, cnt, rowptr, fill);
  k_binit<<<1, 256, 0, stream>>>(rowptr, gfill);
  k_bin<<<256, 256, 0, stream>>>(dstI, gfill, rec);
  k_scatter2<<<NB, 256, 0, stream>>>(rec, rowptr, perm);
  k_permute<<<(NE + 255) / 256, 256, 0, stream>>>(perm, srcI, (const float4*)eattr,
                                                  col, eap);
  k_pre0<<<NN * 32 / 256, 256, 0, stream>>>(x, Wpre0, xA0, xB0b);
  k_agg0<<<NN / 4, 256, 0, stream>>>(x, xA0, xB0b, rowptr, col, eap, wbuf, vec96b);
  k_mmf<96, true, 1><<<(NN + 63) / 64, 256, 0, stream>>>(
      vec96b, Bt + BT0_OFF, wbuf + OFF_BPL0, hb, NN);
  k_mmf<64, false, 0><<<(NN + 63) / 64, 256, 0, stream>>>(
      hb, Bt + BTA_OFF, nullptr, xA1, NN);
  k_mmf<64, false, 1><<<(NN + 63) / 64, 256, 0, stream>>>(
      hb, Bt + BTB_OFF, nullptr, xB1b, NN);
  k_agg1<<<NN, 64, 0, stream>>>(xA1, xB1b, rowptr, col, eap, wbuf, agg320b);
  k_mm384<<<(NN + 63) / 64, 256, 0, stream>>>(hb, agg320b, Bt + BT1_OFF, wbuf, h2, NN);
  k_gcnprep<<<NN * 16 / 256, 256, 0, stream>>>(h2, Wg, rowptr, hgsb, dinv);
  k_head<<<NN / 4, 256, 0, stream>>>(x, hgsb, dinv, rowptr, col, bg, Wh1, bh1,
                                     Wh2, bh2, out);
}

// Round 10
// 560.456 us; speedup vs baseline: 1.3267x; 1.0598x over previous
//
#include <hip/hip_runtime.h>

#define NN 100000
#define NE 1600000

// bucketing for two-level CSR sort
#define BSH 9                      // 512 nodes per bucket
#define BSZ (1 << BSH)
#define NB  196                    // ceil(NN / 512)
#define CHUNK 6250                 // NE / 256

// folded-weight buffer layout (float offsets)
#define OFF_C0   0
#define OFF_D0   64
#define OFF_WPL0 80
#define OFF_BPL0 6224
#define OFF_C1   6288
#define OFF_D1   6544
#define OFF_WPL1 6608
#define OFF_BPL1 31184
#define WBUF_TOT 31248

// transposed bf16 B-matrix buffer layout (ushort offsets)
#define BT1_OFF 0          // WPL1^T  [64][384]
#define BT0_OFF 24576      // WPL0^T  [64][96]
#define BTA_OFF 30720      // Wpre1A^T [64][64]
#define BTB_OFF 34816      // Wpre1B^T [64][64]
#define BT_TOT  38912
#define PREP_TOT (WBUF_TOT + BT_TOT)   // 70160

// ---- bf16 helpers (RNE pack, cheap unpack) ----
__device__ inline unsigned short pack_bf16(float a) {
  unsigned ua = __float_as_uint(a);
  ua += 0x7fffu + ((ua >> 16) & 1u);
  return (unsigned short)(ua >> 16);
}
__device__ inline float bf_s(unsigned short u) { return __uint_as_float(((unsigned)u) << 16); }

// ---------------- weight folding + direct Bt transposes ----------------
__global__ void k_prep(const float* __restrict__ We0, const float* __restrict__ be0,
                       const float* __restrict__ Wpre0, const float* __restrict__ bpre0,
                       const float* __restrict__ Wpost0, const float* __restrict__ bpost0,
                       const float* __restrict__ Wlin0, const float* __restrict__ blin0,
                       const float* __restrict__ We1, const float* __restrict__ be1,
                       const float* __restrict__ Wpre1, const float* __restrict__ bpre1,
                       const float* __restrict__ Wpost1, const float* __restrict__ bpost1,
                       const float* __restrict__ Wlin1, const float* __restrict__ blin1,
                       float* __restrict__ wbuf, unsigned short* __restrict__ Bt) {
  int id = blockIdx.x * 256 + threadIdx.x;
  if (id >= PREP_TOT) return;
  if (id < WBUF_TOT) {
    float a = 0.f;
    if (id < OFF_D0) {
      int j = id >> 4, f = id & 15;
      for (int t = 0; t < 16; t++) a = fmaf(We0[j*16+t], Wpre0[(32+t)*16+f], a);
    } else if (id < OFF_WPL0) {
      int f = id - OFF_D0; a = bpre0[f];
      for (int t = 0; t < 16; t++) a = fmaf(be0[t], Wpre0[(32+t)*16+f], a);
    } else if (id < OFF_BPL0) {
      int r = id - OFF_WPL0; int k = r >> 6, o = r & 63;
      for (int j = 0; j < 64; j++) a = fmaf(Wpost0[k*64+j], Wlin0[j*64+o], a);
    } else if (id < OFF_C1) {
      int o = id - OFF_BPL0; a = blin0[o];
      for (int j = 0; j < 64; j++) a = fmaf(bpost0[j], Wlin0[j*64+o], a);
    } else if (id < OFF_D1) {
      int r = id - OFF_C1; int j = r >> 6, f = r & 63;
      for (int t = 0; t < 64; t++) a = fmaf(We1[j*64+t], Wpre1[(128+t)*64+f], a);
    } else if (id < OFF_WPL1) {
      int f = id - OFF_D1; a = bpre1[f];
      for (int t = 0; t < 64; t++) a = fmaf(be1[t], Wpre1[(128+t)*64+f], a);
    } else if (id < OFF_BPL1) {
      int r = id - OFF_WPL1; int k = r >> 6, o = r & 63;
      for (int j = 0; j < 64; j++) a = fmaf(Wpost1[k*64+j], Wlin1[j*64+o], a);
    } else {
      int o = id - OFF_BPL1; a = blin1[o];
      for (int j = 0; j < 64; j++) a = fmaf(bpost1[j], Wlin1[j*64+o], a);
    }
    wbuf[id] = a;
    return;
  }
  int rid = id - WBUF_TOT;
  if (rid < 24576) {                       // Bt1[nn][k] = (Wpost1@Wlin1)^T
    int nn = rid / 384, k = rid - nn * 384;
    float a = 0.f;
    for (int j = 0; j < 64; j++) a = fmaf(Wpost1[k*64+j], Wlin1[j*64+nn], a);
    Bt[BT1_OFF + rid] = pack_bf16(a);
  } else if (rid < 30720) {                // Bt0[nn][k] = (Wpost0@Wlin0)^T
    int r2 = rid - 24576;
    int nn = r2 / 96, k = r2 - nn * 96;
    float a = 0.f;
    for (int j = 0; j < 64; j++) a = fmaf(Wpost0[k*64+j], Wlin0[j*64+nn], a);
    Bt[BT0_OFF + r2] = pack_bf16(a);
  } else if (rid < 34816) {                // BtA[nn][k] = Wpre1[0:64]^T
    int r3 = rid - 30720;
    int nn = r3 >> 6, k = r3 & 63;
    Bt[BTA_OFF + r3] = pack_bf16(Wpre1[k*64+nn]);
  } else {                                 // BtB[nn][k] = Wpre1[64:128]^T
    int r4 = rid - 34816;
    int nn = r4 >> 6, k = r4 & 63;
    Bt[BTB_OFF + r4] = pack_bf16(Wpre1[(64+k)*64+nn]);
  }
}

// ---------------- CSR build ----------------
__global__ void k_hist(const int* __restrict__ dst, int* __restrict__ cnt) {
  int i = blockIdx.x * 256 + threadIdx.x;
  if (i < NE) atomicAdd(&cnt[dst[i]], 1);
}

__global__ void k_scan1(const int* __restrict__ deg, int* __restrict__ partial,
                        int* __restrict__ bsums) {
  __shared__ int lds[256];
  int i = blockIdx.x * 256 + threadIdx.x;
  int v = (i < NN) ? deg[i] : 0;
  lds[threadIdx.x] = v;
  __syncthreads();
  for (int off = 1; off < 256; off <<= 1) {
    int t = (threadIdx.x >= off) ? lds[threadIdx.x - off] : 0;
    __syncthreads();
    lds[threadIdx.x] += t;
    __syncthreads();
  }
  if (i < NN) partial[i] = lds[threadIdx.x];
  if (threadIdx.x == 255) bsums[blockIdx.x] = lds[255];
}

__global__ void k_scan2(const int* __restrict__ bsums, int* __restrict__ boff, int nb) {
  __shared__ int lds[512];
  int v = ((int)threadIdx.x < nb) ? bsums[threadIdx.x] : 0;
  lds[threadIdx.x] = v;
  __syncthreads();
  for (int off = 1; off < 512; off <<= 1) {
    int t = (threadIdx.x >= off) ? lds[threadIdx.x - off] : 0;
    __syncthreads();
    lds[threadIdx.x] += t;
    __syncthreads();
  }
  if ((int)threadIdx.x < nb) boff[threadIdx.x] = lds[threadIdx.x] - v;  // exclusive
}

__global__ void k_scan3(const int* __restrict__ partial, const int* __restrict__ boff,
                        int* __restrict__ rowptr) {
  int i = blockIdx.x * 256 + threadIdx.x;
  if (i < NN) rowptr[i + 1] = partial[i] + boff[blockIdx.x];
  if (i == 0) rowptr[0] = 0;
}

__global__ void k_binit(const int* __restrict__ rowptr, int* __restrict__ gfill) {
  int b = threadIdx.x;
  if (b < NB) {
    int n0 = b << BSH;
    gfill[b] = rowptr[n0 > NN ? NN : n0];
  }
}

// pass 1: LDS-binned coarse sort
__global__ __launch_bounds__(256) void k_bin(const int* __restrict__ dst,
                                             int* __restrict__ gfill,
                                             int2* __restrict__ rec) {
  __shared__ int hcnt[NB];
  __shared__ int hbase[NB];
  const int t = threadIdx.x;
  for (int b = t; b < NB; b += 256) hcnt[b] = 0;
  __syncthreads();
  const int lo = blockIdx.x * CHUNK, hi = lo + CHUNK;
  for (int i = lo + t; i < hi; i += 256)
    atomicAdd(&hcnt[dst[i] >> BSH], 1);
  __syncthreads();
  for (int b = t; b < NB; b += 256) {
    int c = hcnt[b];
    hbase[b] = c > 0 ? atomicAdd(&gfill[b], c) : 0;
    hcnt[b] = 0;
  }
  __syncthreads();
  for (int i = lo + t; i < hi; i += 256) {
    int d = dst[i];
    int b = d >> BSH;
    int lp = atomicAdd(&hcnt[b], 1);
    rec[hbase[b] + lp] = make_int2(d, i);
  }
}

// pass 2: in-bucket scatter (L2-resident window)
__global__ __launch_bounds__(256) void k_scatter2(const int2* __restrict__ rec,
                                                  const int* __restrict__ rowptr,
                                                  int* __restrict__ perm) {
  __shared__ int lfill[BSZ];
  const int b = blockIdx.x;
  const int n0 = b << BSH;
  const int n1 = (n0 + BSZ < NN) ? n0 + BSZ : NN;
  const int t = threadIdx.x;
  for (int n = n0 + t; n < n1; n += 256) lfill[n - n0] = rowptr[n];
  __syncthreads();
  const int lo = rowptr[n0], hi = rowptr[n1];
  for (int i = lo + t; i < hi; i += 256) {
    int2 r = rec[i];
    int pos = atomicAdd(&lfill[r.x - n0], 1);
    perm[pos] = r.y;
  }
}

// pass 3: gather-permute; edge attrs packed to bf16x4 (8B/edge)
__global__ void k_permute(const int* __restrict__ perm, const int* __restrict__ src,
                          const float4* __restrict__ ea, int* __restrict__ col,
                          ushort4* __restrict__ eapb) {
  int i = blockIdx.x * 256 + threadIdx.x;
  if (i < NE) {
    int eid = perm[i];
    col[i] = src[eid];
    float4 e = ea[eid];
    ushort4 pk;
    pk.x = pack_bf16(e.x); pk.y = pack_bf16(e.y);
    pk.z = pack_bf16(e.z); pk.w = pack_bf16(e.w);
    eapb[i] = pk;
  }
}

// ---------------- layer 0 node pre-projection ----------------
__global__ void k_pre0(const float* __restrict__ x, const float* __restrict__ Wpre0,
                       float* __restrict__ xA0, unsigned short* __restrict__ xB0b) {
  int t = blockIdx.x * 256 + threadIdx.x;   // NN*32 threads
  int node = t >> 5, k = t & 31;
  int f = k & 15;
  const float* W = Wpre0 + (k < 16 ? 0 : 256);
  const float* xr = x + (size_t)node * 16;
  float a = 0.f;
#pragma unroll
  for (int j = 0; j < 16; j++) a = fmaf(xr[j], W[j*16+f], a);
  if (k < 16) xA0[(size_t)node*16+f] = a;
  else        xB0b[(size_t)node*16+f] = pack_bf16(a);
}

// ---------------- layer 0 aggregation (bf16 xB0 + bf16 eap) ----------------
__global__ __launch_bounds__(256) void k_agg0(const float* __restrict__ x,
                                              const float* __restrict__ xA0,
                                              const unsigned short* __restrict__ xB0b,
                                              const int* __restrict__ rowptr,
                                              const int* __restrict__ col,
                                              const ushort4* __restrict__ eapb,
                                              const float* __restrict__ wbuf,
                                              unsigned short* __restrict__ vec96b) {
  const int w = threadIdx.x >> 6, lane = threadIdx.x & 63;
  const int g = lane >> 4, f = lane & 15;
  const int node = blockIdx.x * 4 + w;
  const int start = rowptr[node], end = rowptr[node + 1];
  const int cnt = end - start;
  const float c0 = wbuf[OFF_C0 + f],      c1v = wbuf[OFF_C0 + 16 + f];
  const float c2v = wbuf[OFF_C0 + 32 + f], c3v = wbuf[OFF_C0 + 48 + f];
  float s = 0.f, sq = 0.f, mx = -__builtin_inff(), mn = __builtin_inff();
  int p = start + g;
  for (; p + 4 < end; p += 8) {
    int s0 = col[p], s1 = col[p + 4];
    ushort4 e0 = eapb[p], e1 = eapb[p + 4];
    float v0 = bf_s(xB0b[(size_t)s0 * 16 + f]);
    float v1 = bf_s(xB0b[(size_t)s1 * 16 + f]);
    v0 = fmaf(bf_s(e0.x), c0, v0); v0 = fmaf(bf_s(e0.y), c1v, v0);
    v0 = fmaf(bf_s(e0.z), c2v, v0); v0 = fmaf(bf_s(e0.w), c3v, v0);
    v1 = fmaf(bf_s(e1.x), c0, v1); v1 = fmaf(bf_s(e1.y), c1v, v1);
    v1 = fmaf(bf_s(e1.z), c2v, v1); v1 = fmaf(bf_s(e1.w), c3v, v1);
    s += v0 + v1;
    sq = fmaf(v0, v0, sq); sq = fmaf(v1, v1, sq);
    mx = fmaxf(mx, fmaxf(v0, v1)); mn = fminf(mn, fminf(v0, v1));
  }
  for (; p < end; p += 4) {
    int si = col[p];
    ushort4 e0 = eapb[p];
    float v = bf_s(xB0b[(size_t)si * 16 + f]);
    v = fmaf(bf_s(e0.x), c0, v); v = fmaf(bf_s(e0.y), c1v, v);
    v = fmaf(bf_s(e0.z), c2v, v); v = fmaf(bf_s(e0.w), c3v, v);
    s += v; sq = fmaf(v, v, sq); mx = fmaxf(mx, v); mn = fminf(mn, v);
  }
  s  += __shfl_xor(s, 16);  s  += __shfl_xor(s, 32);
  sq += __shfl_xor(sq, 16); sq += __shfl_xor(sq, 32);
  mx = fmaxf(mx, __shfl_xor(mx, 16)); mx = fmaxf(mx, __shfl_xor(mx, 32));
  mn = fminf(mn, __shfl_xor(mn, 16)); mn = fminf(mn, __shfl_xor(mn, 32));
  const float c = xA0[(size_t)node * 16 + f] + wbuf[OFF_D0 + f];
  float sum_m, mean_m, mx_m, mn_m, std_m;
  if (cnt > 0) {
    float inv = 1.f / (float)cnt;
    float meanv = s * inv;
    sum_m = fmaf((float)cnt, c, s);
    mean_m = meanv + c;
    mx_m = mx + c; mn_m = mn + c;
    float var = fmaf(-meanv, meanv, sq * inv);
    std_m = sqrtf(fmaxf(var, 0.f) + 1e-5f);
  } else {
    sum_m = 0.f; mean_m = 0.f; mx_m = 0.f; mn_m = 0.f; std_m = sqrtf(1e-5f);
  }
  if (g == 0) {
    unsigned short* vr = vec96b + (size_t)node * 96;
    vr[f]      = pack_bf16(x[(size_t)node * 16 + f]);
    vr[16 + f] = pack_bf16(sum_m);
    vr[32 + f] = pack_bf16(mean_m);
    vr[48 + f] = pack_bf16(mx_m);
    vr[64 + f] = pack_bf16(mn_m);
    vr[80 + f] = pack_bf16(std_m);
  }
}

// ---------------- layer 1 aggregation: one node per 64-thread block ----------------
__global__ __launch_bounds__(64) void k_agg1(const float* __restrict__ xA1,
                                             const unsigned short* __restrict__ xB1b,
                                             const int* __restrict__ rowptr,
                                             const int* __restrict__ col,
                                             const ushort4* __restrict__ eapb,
                                             const float* __restrict__ wbuf,
                                             unsigned short* __restrict__ agg320b) {
  const int f = threadIdx.x;            // 0..63
  const int node = blockIdx.x;
  const int start = rowptr[node], end = rowptr[node + 1];
  const int cnt = end - start;
  const float c0 = wbuf[OFF_C1 + f],       c1v = wbuf[OFF_C1 + 64 + f];
  const float c2v = wbuf[OFF_C1 + 128 + f], c3v = wbuf[OFF_C1 + 192 + f];
  float s = 0.f, sq = 0.f, mx = -__builtin_inff(), mn = __builtin_inff();
  int p = start;
  for (; p + 7 < end; p += 8) {
#pragma unroll
    for (int u = 0; u < 8; u++) {
      int si = col[p + u];                                   // scalar load
      ushort4 e = eapb[p + u];                               // scalar dwordx2
      const unsigned short* row = xB1b + (unsigned)si * 64;  // SALU base
      float v = bf_s(row[f]);                                // 128B coalesced gather
      v = fmaf(bf_s(e.x), c0, v); v = fmaf(bf_s(e.y), c1v, v);
      v = fmaf(bf_s(e.z), c2v, v); v = fmaf(bf_s(e.w), c3v, v);
      s += v; sq = fmaf(v, v, sq); mx = fmaxf(mx, v); mn = fminf(mn, v);
    }
  }
  for (; p < end; p++) {
    int si = col[p];
    ushort4 e = eapb[p];
    const unsigned short* row = xB1b + (unsigned)si * 64;
    float v = bf_s(row[f]);
    v = fmaf(bf_s(e.x), c0, v); v = fmaf(bf_s(e.y), c1v, v);
    v = fmaf(bf_s(e.z), c2v, v); v = fmaf(bf_s(e.w), c3v, v);
    s += v; sq = fmaf(v, v, sq); mx = fmaxf(mx, v); mn = fminf(mn, v);
  }
  const float c = xA1[(size_t)node * 64 + f] + wbuf[OFF_D1 + f];
  float sum_m, mean_m, mx_m, mn_m, std_m;
  if (cnt > 0) {
    float inv = 1.f / (float)cnt;
    float meanv = s * inv;
    sum_m = fmaf((float)cnt, c, s);
    mean_m = meanv + c;
    mx_m = mx + c; mn_m = mn + c;
    float var = fmaf(-meanv, meanv, sq * inv);
    std_m = sqrtf(fmaxf(var, 0.f) + 1e-5f);
  } else {
    sum_m = 0.f; mean_m = 0.f; mx_m = 0.f; mn_m = 0.f; std_m = sqrtf(1e-5f);
  }
  unsigned short* ar = agg320b + (size_t)node * 320;
  ar[f]       = pack_bf16(sum_m);
  ar[64 + f]  = pack_bf16(mean_m);
  ar[128 + f] = pack_bf16(mx_m);
  ar[192 + f] = pack_bf16(mn_m);
  ar[256 + f] = pack_bf16(std_m);
}

// ---------------- MFMA GEMM: C[n,64] = (relu)(A[n,K]_bf16 @ Bt^T + bias) ----------------
template <int K, bool RELU, int OMODE>
__global__ __launch_bounds__(256) void k_mmf(const unsigned short* __restrict__ A,
                                             const unsigned short* __restrict__ Bt,
                                             const float* __restrict__ bias,
                                             void* __restrict__ C, int n) {
  using bf16x8 = __attribute__((ext_vector_type(8))) short;
  using f32x4  = __attribute__((ext_vector_type(4))) float;
  const int wave = threadIdx.x >> 6, lane = threadIdx.x & 63;
  const int qm = lane & 15, quad = lane >> 4;
  const int m0 = blockIdx.x * 64 + wave * 16;
  const int mrow = m0 + qm;
  f32x4 acc[4] = {};
#pragma unroll
  for (int k0 = 0; k0 < K; k0 += 32) {
    bf16x8 a = *(const bf16x8*)(A + (size_t)mrow * K + k0 + quad * 8);
#pragma unroll
    for (int nt = 0; nt < 4; nt++) {
      bf16x8 b = *(const bf16x8*)(Bt + (size_t)(nt * 16 + qm) * K + k0 + quad * 8);
      acc[nt] = __builtin_amdgcn_mfma_f32_16x16x32_bf16(a, b, acc[nt], 0, 0, 0);
    }
  }
#pragma unroll
  for (int nt = 0; nt < 4; nt++) {
    int colc = nt * 16 + qm;
    float bb = bias ? bias[colc] : 0.f;
#pragma unroll
    for (int r = 0; r < 4; r++) {
      int m = m0 + quad * 4 + r;
      if (m < n) {
        float v = acc[nt][r] + bb;
        if (RELU) v = fmaxf(v, 0.f);
        if (OMODE == 0) ((float*)C)[(size_t)m * 64 + colc] = v;
        else ((unsigned short*)C)[(size_t)m * 64 + colc] = pack_bf16(v);
      }
    }
  }
}

// ---------------- dual-B MFMA: xA1 (fp32) + xB1b (bf16) from one pass over hb ----------------
__global__ __launch_bounds__(256) void k_mmf64d(const unsigned short* __restrict__ A,
                                                const unsigned short* __restrict__ BtA,
                                                const unsigned short* __restrict__ BtB,
                                                float* __restrict__ xA1,
                                                unsigned short* __restrict__ xB1b, int n) {
  using bf16x8 = __attribute__((ext_vector_type(8))) short;
  using f32x4  = __attribute__((ext_vector_type(4))) float;
  const int wave = threadIdx.x >> 6, lane = threadIdx.x & 63;
  const int qm = lane & 15, quad = lane >> 4;
  const int m0 = blockIdx.x * 64 + wave * 16;
  const int mrow = m0 + qm;
  f32x4 accA[4] = {}, accB[4] = {};
#pragma unroll
  for (int k0 = 0; k0 < 64; k0 += 32) {
    bf16x8 a = *(const bf16x8*)(A + (size_t)mrow * 64 + k0 + quad * 8);
#pragma unroll
    for (int nt = 0; nt < 4; nt++) {
      bf16x8 bA = *(const bf16x8*)(BtA + (size_t)(nt * 16 + qm) * 64 + k0 + quad * 8);
      bf16x8 bB = *(const bf16x8*)(BtB + (size_t)(nt * 16 + qm) * 64 + k0 + quad * 8);
      accA[nt] = __builtin_amdgcn_mfma_f32_16x16x32_bf16(a, bA, accA[nt], 0, 0, 0);
      accB[nt] = __builtin_amdgcn_mfma_f32_16x16x32_bf16(a, bB, accB[nt], 0, 0, 0);
    }
  }
#pragma unroll
  for (int nt = 0; nt < 4; nt++) {
    int colc = nt * 16 + qm;
#pragma unroll
    for (int r = 0; r < 4; r++) {
      int m = m0 + quad * 4 + r;
      if (m < n) {
        xA1[(size_t)m * 64 + colc] = accA[nt][r];
        xB1b[(size_t)m * 64 + colc] = pack_bf16(accB[nt][r]);
      }
    }
  }
}

// ---------------- fused: h2 = relu([hb|aggb]@Bt1^T + bias); hgsb = bf16((h2@Wg)*dinv) ----
__global__ __launch_bounds__(256) void k_mm384g(const unsigned short* __restrict__ hb,
                                                const unsigned short* __restrict__ aggb,
                                                const unsigned short* __restrict__ Bt1,
                                                const float* __restrict__ wbuf,
                                                const float* __restrict__ Wg,
                                                const int* __restrict__ rowptr,
                                                unsigned short* __restrict__ hgsb,
                                                float* __restrict__ dinv, int n) {
  using bf16x8 = __attribute__((ext_vector_type(8))) short;
  using f32x4  = __attribute__((ext_vector_type(4))) float;
  __shared__ float h2t[4][16][65];     // padded: stride 65 breaks bank conflicts
  __shared__ float wg[64][16];
  const int tid = threadIdx.x;
  for (int i = tid; i < 1024; i += 256) wg[i >> 4][i & 15] = Wg[i];
  const int wave = tid >> 6, lane = tid & 63;
  const int qm = lane & 15, quad = lane >> 4;
  const int m0 = blockIdx.x * 64 + wave * 16;
  const int mrow = m0 + qm;
  f32x4 acc[4] = {};
  for (int k0 = 0; k0 < 384; k0 += 32) {
    bf16x8 a;
    if (k0 < 64) a = *(const bf16x8*)(hb + (size_t)mrow * 64 + k0 + quad * 8);
    else         a = *(const bf16x8*)(aggb + (size_t)mrow * 320 + (k0 - 64) + quad * 8);
#pragma unroll
    for (int nt = 0; nt < 4; nt++) {
      bf16x8 b = *(const bf16x8*)(Bt1 + (size_t)(nt * 16 + qm) * 384 + k0 + quad * 8);
      acc[nt] = __builtin_amdgcn_mfma_f32_16x16x32_bf16(a, b, acc[nt], 0, 0, 0);
    }
  }
#pragma unroll
  for (int nt = 0; nt < 4; nt++) {
    int colc = nt * 16 + qm;
    float bias = wbuf[OFF_BPL1 + colc];
#pragma unroll
    for (int r = 0; r < 4; r++)
      h2t[wave][quad * 4 + r][colc] = fmaxf(acc[nt][r] + bias, 0.f);
  }
  __syncthreads();
  // project: hgs[row][4g..4g+3] = sum_j h2[row][j] * Wg[j][4g..4g+3]
  const int row = lane & 15, g = lane >> 4;
  float hg0 = 0.f, hg1 = 0.f, hg2 = 0.f, hg3 = 0.f;
#pragma unroll 16
  for (int j = 0; j < 64; j++) {
    float hv = h2t[wave][row][j];
    float4 w4 = *(const float4*)&wg[j][g * 4];
    hg0 = fmaf(hv, w4.x, hg0); hg1 = fmaf(hv, w4.y, hg1);
    hg2 = fmaf(hv, w4.z, hg2); hg3 = fmaf(hv, w4.w, hg3);
  }
  int m = m0 + row;
  if (m < n) {
    int deg = rowptr[m + 1] - rowptr[m] + 1;   // +1 self loop
    float dv = 1.0f / sqrtf((float)deg);
    if (g == 0) dinv[m] = dv;
    ushort4 pk;
    pk.x = pack_bf16(hg0 * dv); pk.y = pack_bf16(hg1 * dv);
    pk.z = pack_bf16(hg2 * dv); pk.w = pack_bf16(hg3 * dv);
    *(ushort4*)(hgsb + (size_t)m * 16 + g * 4) = pk;
  }
}

// ---------------- GCN aggregate + MLP head ----------------
__global__ __launch_bounds__(256) void k_head(const float* __restrict__ x,
                                              const unsigned short* __restrict__ hgsb,
                                              const float* __restrict__ dinv,
                                              const int* __restrict__ rowptr,
                                              const int* __restrict__ col,
                                              const float* __restrict__ bg,
                                              const float* __restrict__ Wh1,
                                              const float* __restrict__ bh1,
                                              const float* __restrict__ Wh2,
                                              const float* __restrict__ bh2,
                                              float* __restrict__ out) {
  __shared__ float zb[4][32];
  __shared__ float o1b[4][10];
  const int w = threadIdx.x >> 6, lane = threadIdx.x & 63;
  const int g = lane >> 4, f = lane & 15;
  const int node = blockIdx.x * 4 + w;
  const int start = rowptr[node], end = rowptr[node + 1];
  float s = 0.f;
  int p = start + g;
  for (; p + 12 < end; p += 16) {
    int s0 = col[p], s1 = col[p + 4], s2 = col[p + 8], s3 = col[p + 12];
    float v0 = bf_s(hgsb[(size_t)s0 * 16 + f]);
    float v1 = bf_s(hgsb[(size_t)s1 * 16 + f]);
    float v2 = bf_s(hgsb[(size_t)s2 * 16 + f]);
    float v3 = bf_s(hgsb[(size_t)s3 * 16 + f]);
    s += (v0 + v1) + (v2 + v3);
  }
  for (; p < end; p += 4) {
    int si = col[p];
    s += bf_s(hgsb[(size_t)si * 16 + f]);
  }
  s += __shfl_xor(s, 16); s += __shfl_xor(s, 32);
  if (g == 0) {
    float gout = (s + bf_s(hgsb[(size_t)node * 16 + f])) * dinv[node] + bg[f];
    zb[w][f] = gout;
    zb[w][16 + f] = x[(size_t)node * 16 + f];
  }
  __syncthreads();
  if (lane < 10) {
    float a = bh1[lane];
#pragma unroll
    for (int k = 0; k < 32; k++) a = fmaf(zb[w][k], Wh1[k * 10 + lane], a);
    o1b[w][lane] = fmaxf(a, 0.f);
  }
  __syncthreads();
  if (lane < 10) {
    float a = bh2[lane];
#pragma unroll
    for (int j = 0; j < 10; j++) a = fmaf(o1b[w][j], Wh2[j * 10 + lane], a);
    out[(size_t)node * 10 + lane] = a;
  }
}

// ---------------- launcher ----------------
extern "C" void kernel_launch(void* const* d_in, const int* in_sizes, int n_in,
                              void* d_out, int out_size, void* d_ws, size_t ws_size,
                              hipStream_t stream) {
  const float* x      = (const float*)d_in[0];
  const int*   ei     = (const int*)d_in[1];
  const float* eattr  = (const float*)d_in[2];
  const float* We0    = (const float*)d_in[3];
  const float* be0    = (const float*)d_in[4];
  const float* Wpre0  = (const float*)d_in[5];
  const float* bpre0  = (const float*)d_in[6];
  const float* Wpost0 = (const float*)d_in[7];
  const float* bpost0 = (const float*)d_in[8];
  const float* Wlin0  = (const float*)d_in[9];
  const float* blin0  = (const float*)d_in[10];
  const float* We1    = (const float*)d_in[11];
  const float* be1    = (const float*)d_in[12];
  const float* Wpre1  = (const float*)d_in[13];
  const float* bpre1  = (const float*)d_in[14];
  const float* Wpost1 = (const float*)d_in[15];
  const float* bpost1 = (const float*)d_in[16];
  const float* Wlin1  = (const float*)d_in[17];
  const float* blin1  = (const float*)d_in[18];
  const float* Wg     = (const float*)d_in[19];
  const float* bg     = (const float*)d_in[20];
  const float* Wh1    = (const float*)d_in[21];
  const float* bh1    = (const float*)d_in[22];
  const float* Wh2    = (const float*)d_in[23];
  const float* bh2    = (const float*)d_in[24];
  const int* srcI = ei;
  const int* dstI = ei + NE;
  float* out = (float*)d_out;

  char* base = (char*)d_ws;
  size_t off = 0;
  auto take = [&](size_t bytes) -> char* {
    char* p = base + off;
    off += (bytes + 255) & ~(size_t)255;
    return p;
  };
  int* cnt     = (int*)take((size_t)NN * 4);
  int* rowptr  = (int*)take((size_t)(NN + 1) * 4);
  int* partial = (int*)take((size_t)NN * 4);
  int* bsums   = (int*)take(512 * 4);
  int* boff    = (int*)take(512 * 4);
  int* gfill   = (int*)take(512 * 4);
  unsigned short* Bt = (unsigned short*)take((size_t)BT_TOT * 2);
  int* col     = (int*)take((size_t)NE * 4);          // 6.4MB
  ushort4* eapb = (ushort4*)take((size_t)NE * 8);     // 12.8MB
  float* wbuf  = (float*)take((size_t)WBUF_TOT * 4);
  int*   perm  = (int*)take((size_t)NE * 4);          // 6.4MB; hgsb/dinv alias late
  unsigned short* hgsb = (unsigned short*)perm;       // 3.2MB (perm dead after permute)
  float* dinv  = (float*)((char*)perm + (size_t)NN * 16 * 2);  // +0.4MB
  float* xA1   = (float*)take((size_t)NN * 64 * 4);   // 25.6MB
  int2*  rec   = (int2*)take((size_t)NE * 8);         // 12.8MB
  unsigned short* xB1b = (unsigned short*)rec;        // bf16 [NN,64], after rec dies
  // region Z (128MB): vec96b/xA0/xB0b early -> agg320b (64MB) mid; hb at +96MB
  char* Z = take((size_t)NN * 320 * 4);
  unsigned short* vec96b  = (unsigned short*)Z;                         // 19.2MB
  float* xA0    = (float*)(Z + (size_t)NN * 96 * 2);                    // 6.4MB
  unsigned short* xB0b = (unsigned short*)(Z + (size_t)NN * 96 * 2 + (size_t)NN * 16 * 4);
  unsigned short* agg320b = (unsigned short*)Z;                         // 64MB
  unsigned short* hb = (unsigned short*)(Z + (size_t)96 * 1024 * 1024); // 12.8MB

  hipMemsetAsync(cnt, 0, (size_t)NN * 4, stream);
  k_prep<<<(PREP_TOT + 255) / 256, 256, 0, stream>>>(
      We0, be0, Wpre0, bpre0, Wpost0, bpost0, Wlin0, blin0,
      We1, be1, Wpre1, bpre1, Wpost1, bpost1, Wlin1, blin1, wbuf, Bt);
  k_hist<<<(NE + 255) / 256, 256, 0, stream>>>(dstI, cnt);
  k_scan1<<<391, 256, 0, stream>>>(cnt, partial, bsums);
  k_scan2<<<1, 512, 0, stream>>>(bsums, boff, 391);
  k_scan3<<<391, 256, 0, stream>>>(partial, boff, rowptr);
  k_binit<<<1, 256, 0, stream>>>(rowptr, gfill);
  k_bin<<<256, 256, 0, stream>>>(dstI, gfill, rec);
  k_scatter2<<<NB, 256, 0, stream>>>(rec, rowptr, perm);
  k_permute<<<(NE + 255) / 256, 256, 0, stream>>>(perm, srcI, (const float4*)eattr,
                                                  col, eapb);
  k_pre0<<<NN * 32 / 256, 256, 0, stream>>>(x, Wpre0, xA0, xB0b);
  k_agg0<<<NN / 4, 256, 0, stream>>>(x, xA0, xB0b, rowptr, col, eapb, wbuf, vec96b);
  k_mmf<96, true, 1><<<(NN + 63) / 64, 256, 0, stream>>>(
      vec96b, Bt + BT0_OFF, wbuf + OFF_BPL0, hb, NN);
  k_mmf64d<<<(NN + 63) / 64, 256, 0, stream>>>(
      hb, Bt + BTA_OFF, Bt + BTB_OFF, xA1, xB1b, NN);
  k_agg1<<<NN, 64, 0, stream>>>(xA1, xB1b, rowptr, col, eapb, wbuf, agg320b);
  k_mm384g<<<(NN + 63) / 64, 256, 0, stream>>>(
      hb, agg320b, Bt + BT1_OFF, wbuf, Wg, rowptr, hgsb, dinv, NN);
  k_head<<<NN / 4, 256, 0, stream>>>(x, hgsb, dinv, rowptr, col, bg, Wh1, bh1,
                                     Wh2, bh2, out);
}

// Round 11
// 485.842 us; speedup vs baseline: 1.5305x; 1.1536x over previous
//
#include <hip/hip_runtime.h>

#define NN 100000
#define NE 1600000

// bucketing for single-pass CSR sort
#define BSH 9                      // 512 nodes per bucket
#define BSZ (1 << BSH)
#define NB  196                    // ceil(NN / 512)
#define CHUNK 6250                 // NE / 256

// folded-weight buffer layout (float offsets)
#define OFF_C0   0
#define OFF_D0   64
#define OFF_WPL0 80
#define OFF_BPL0 6224
#define OFF_C1   6288
#define OFF_D1   6544
#define OFF_WPL1 6608
#define OFF_BPL1 31184
#define WBUF_TOT 31248

// transposed bf16 B-matrix buffer layout (ushort offsets)
#define BT1_OFF 0          // WPL1^T  [64][384]
#define BT0_OFF 24576      // WPL0^T  [64][96]
#define BTA_OFF 30720      // Wpre1A^T [64][64]
#define BTB_OFF 34816      // Wpre1B^T [64][64]
#define BT_TOT  38912
#define PREP_TOT (WBUF_TOT + BT_TOT)   // 70160

// ---- bf16 helpers (RNE pack, cheap unpack) ----
__device__ inline unsigned short pack_bf16(float a) {
  unsigned ua = __float_as_uint(a);
  ua += 0x7fffu + ((ua >> 16) & 1u);
  return (unsigned short)(ua >> 16);
}
__device__ inline float bf_s(unsigned short u) { return __uint_as_float(((unsigned)u) << 16); }

// ---------------- weight folding + direct Bt transposes ----------------
__global__ void k_prep(const float* __restrict__ We0, const float* __restrict__ be0,
                       const float* __restrict__ Wpre0, const float* __restrict__ bpre0,
                       const float* __restrict__ Wpost0, const float* __restrict__ bpost0,
                       const float* __restrict__ Wlin0, const float* __restrict__ blin0,
                       const float* __restrict__ We1, const float* __restrict__ be1,
                       const float* __restrict__ Wpre1, const float* __restrict__ bpre1,
                       const float* __restrict__ Wpost1, const float* __restrict__ bpost1,
                       const float* __restrict__ Wlin1, const float* __restrict__ blin1,
                       float* __restrict__ wbuf, unsigned short* __restrict__ Bt) {
  int id = blockIdx.x * 256 + threadIdx.x;
  if (id >= PREP_TOT) return;
  if (id < WBUF_TOT) {
    float a = 0.f;
    if (id < OFF_D0) {
      int j = id >> 4, f = id & 15;
      for (int t = 0; t < 16; t++) a = fmaf(We0[j*16+t], Wpre0[(32+t)*16+f], a);
    } else if (id < OFF_WPL0) {
      int f = id - OFF_D0; a = bpre0[f];
      for (int t = 0; t < 16; t++) a = fmaf(be0[t], Wpre0[(32+t)*16+f], a);
    } else if (id < OFF_BPL0) {
      int r = id - OFF_WPL0; int k = r >> 6, o = r & 63;
      for (int j = 0; j < 64; j++) a = fmaf(Wpost0[k*64+j], Wlin0[j*64+o], a);
    } else if (id < OFF_C1) {
      int o = id - OFF_BPL0; a = blin0[o];
      for (int j = 0; j < 64; j++) a = fmaf(bpost0[j], Wlin0[j*64+o], a);
    } else if (id < OFF_D1) {
      int r = id - OFF_C1; int j = r >> 6, f = r & 63;
      for (int t = 0; t < 64; t++) a = fmaf(We1[j*64+t], Wpre1[(128+t)*64+f], a);
    } else if (id < OFF_WPL1) {
      int f = id - OFF_D1; a = bpre1[f];
      for (int t = 0; t < 64; t++) a = fmaf(be1[t], Wpre1[(128+t)*64+f], a);
    } else if (id < OFF_BPL1) {
      int r = id - OFF_WPL1; int k = r >> 6, o = r & 63;
      for (int j = 0; j < 64; j++) a = fmaf(Wpost1[k*64+j], Wlin1[j*64+o], a);
    } else {
      int o = id - OFF_BPL1; a = blin1[o];
      for (int j = 0; j < 64; j++) a = fmaf(bpost1[j], Wlin1[j*64+o], a);
    }
    wbuf[id] = a;
    return;
  }
  int rid = id - WBUF_TOT;
  if (rid < 24576) {                       // Bt1[nn][k] = (Wpost1@Wlin1)^T
    int nn = rid / 384, k = rid - nn * 384;
    float a = 0.f;
    for (int j = 0; j < 64; j++) a = fmaf(Wpost1[k*64+j], Wlin1[j*64+nn], a);
    Bt[BT1_OFF + rid] = pack_bf16(a);
  } else if (rid < 30720) {                // Bt0[nn][k] = (Wpost0@Wlin0)^T
    int r2 = rid - 24576;
    int nn = r2 / 96, k = r2 - nn * 96;
    float a = 0.f;
    for (int j = 0; j < 64; j++) a = fmaf(Wpost0[k*64+j], Wlin0[j*64+nn], a);
    Bt[BT0_OFF + r2] = pack_bf16(a);
  } else if (rid < 34816) {                // BtA[nn][k] = Wpre1[0:64]^T
    int r3 = rid - 30720;
    int nn = r3 >> 6, k = r3 & 63;
    Bt[BTA_OFF + r3] = pack_bf16(Wpre1[k*64+nn]);
  } else {                                 // BtB[nn][k] = Wpre1[64:128]^T
    int r4 = rid - 34816;
    int nn = r4 >> 6, k = r4 & 63;
    Bt[BTB_OFF + r4] = pack_bf16(Wpre1[(64+k)*64+nn]);
  }
}

// ---------------- bucket histogram (196 counters, LDS-aggregated) ----------------
__global__ __launch_bounds__(256) void k_bcnt(const int* __restrict__ dst,
                                              int* __restrict__ bcnt) {
  __shared__ int h[NB];
  for (int b = threadIdx.x; b < NB; b += 256) h[b] = 0;
  __syncthreads();
  const int lo = blockIdx.x * CHUNK, hi = lo + CHUNK;
  for (int i = lo + threadIdx.x; i < hi; i += 256)
    atomicAdd(&h[dst[i] >> BSH], 1);
  __syncthreads();
  for (int b = threadIdx.x; b < NB; b += 256)
    if (h[b]) atomicAdd(&bcnt[b], h[b]);
}

// scan 196 bucket counts -> gbase[0..NB] (exclusive, gbase[NB]=NE) + gfill copy
__global__ void k_bscan(const int* __restrict__ bcnt, int* __restrict__ gbase,
                        int* __restrict__ gfill) {
  __shared__ int lds[256];
  int t = threadIdx.x;
  int v = (t < NB) ? bcnt[t] : 0;
  lds[t] = v;
  __syncthreads();
  for (int off = 1; off < 256; off <<= 1) {
    int u = (t >= off) ? lds[t - off] : 0;
    __syncthreads();
    lds[t] += u;
    __syncthreads();
  }
  if (t <= NB) {
    int excl = (t == 0) ? 0 : lds[t - 1];
    gbase[t] = excl;
    if (t < NB) gfill[t] = excl;
  }
}

// coarse sort: sequential edge read (dst,src,ea) -> 16B records in bucket runs
__global__ __launch_bounds__(256) void k_bin16(const int* __restrict__ dst,
                                               const int* __restrict__ src,
                                               const float4* __restrict__ ea,
                                               int* __restrict__ gfill,
                                               int4* __restrict__ rec) {
  __shared__ int hcnt[NB];
  __shared__ int hbase[NB];
  const int t = threadIdx.x;
  for (int b = t; b < NB; b += 256) hcnt[b] = 0;
  __syncthreads();
  const int lo = blockIdx.x * CHUNK, hi = lo + CHUNK;
  for (int i = lo + t; i < hi; i += 256)
    atomicAdd(&hcnt[dst[i] >> BSH], 1);
  __syncthreads();
  for (int b = t; b < NB; b += 256) {
    int c = hcnt[b];
    hbase[b] = c > 0 ? atomicAdd(&gfill[b], c) : 0;
    hcnt[b] = 0;
  }
  __syncthreads();
  for (int i = lo + t; i < hi; i += 256) {
    int d = dst[i];
    int b = d >> BSH;
    int lp = atomicAdd(&hcnt[b], 1);
    float4 e = ea[i];                       // sequential 16B read
    int4 r;
    r.x = d; r.y = src[i];
    r.z = (int)(((unsigned)pack_bf16(e.y) << 16) | (unsigned)pack_bf16(e.x));
    r.w = (int)(((unsigned)pack_bf16(e.w) << 16) | (unsigned)pack_bf16(e.z));
    rec[hbase[b] + lp] = r;
  }
}

// per-bucket: LDS degree histogram -> scan -> rowptr; scatter col+eapb into
// the bucket's L2-resident windows.  Replaces hist/scans/binit/scatter/permute.
__global__ __launch_bounds__(256) void k_scatter2b(const int4* __restrict__ rec,
                                                   const int* __restrict__ gbase,
                                                   int* __restrict__ rowptr,
                                                   int* __restrict__ col,
                                                   ushort4* __restrict__ eapb) {
  __shared__ int cnt[BSZ];
  __shared__ int scn[BSZ];
  __shared__ int fill[BSZ];
  const int b = blockIdx.x;
  const int n0 = b << BSH;
  const int n1 = (n0 + BSZ < NN) ? n0 + BSZ : NN;
  const int t = threadIdx.x;
  cnt[t] = 0; cnt[t + 256] = 0;
  __syncthreads();
  const int base = gbase[b];
  const int total = gbase[b + 1] - base;
  for (int i = t; i < total; i += 256)
    atomicAdd(&cnt[rec[base + i].x - n0], 1);
  __syncthreads();
  scn[t] = cnt[t]; scn[t + 256] = cnt[t + 256];
  __syncthreads();
  for (int off = 1; off < BSZ; off <<= 1) {
    int v0 = (t >= off) ? scn[t - off] : 0;
    int i1 = t + 256;
    int v1 = (i1 >= off) ? scn[i1 - off] : 0;
    __syncthreads();
    scn[t] += v0; scn[i1] += v1;
    __syncthreads();
  }
  {
    int e0 = scn[t] - cnt[t];
    int e1 = scn[t + 256] - cnt[t + 256];
    fill[t] = base + e0; fill[t + 256] = base + e1;
    if (n0 + t < n1) rowptr[n0 + t] = base + e0;
    if (n0 + t + 256 < n1) rowptr[n0 + t + 256] = base + e1;
  }
  if (b == NB - 1 && t == 0) rowptr[NN] = base + total;
  __syncthreads();
  for (int i = t; i < total; i += 256) {
    int4 r = rec[base + i];
    int pos = atomicAdd(&fill[r.x - n0], 1);
    col[pos] = r.y;
    ushort4 e;
    e.x = (unsigned short)(r.z & 0xffff);
    e.y = (unsigned short)((unsigned)r.z >> 16);
    e.z = (unsigned short)(r.w & 0xffff);
    e.w = (unsigned short)((unsigned)r.w >> 16);
    eapb[pos] = e;
  }
}

// ---------------- layer 0 node pre-projection ----------------
__global__ void k_pre0(const float* __restrict__ x, const float* __restrict__ Wpre0,
                       float* __restrict__ xA0, unsigned short* __restrict__ xB0b) {
  int t = blockIdx.x * 256 + threadIdx.x;   // NN*32 threads
  int node = t >> 5, k = t & 31;
  int f = k & 15;
  const float* W = Wpre0 + (k < 16 ? 0 : 256);
  const float* xr = x + (size_t)node * 16;
  float a = 0.f;
#pragma unroll
  for (int j = 0; j < 16; j++) a = fmaf(xr[j], W[j*16+f], a);
  if (k < 16) xA0[(size_t)node*16+f] = a;
  else        xB0b[(size_t)node*16+f] = pack_bf16(a);
}

// ---------------- layer 0 aggregation (bf16 xB0 + bf16 eap) ----------------
__global__ __launch_bounds__(256) void k_agg0(const float* __restrict__ x,
                                              const float* __restrict__ xA0,
                                              const unsigned short* __restrict__ xB0b,
                                              const int* __restrict__ rowptr,
                                              const int* __restrict__ col,
                                              const ushort4* __restrict__ eapb,
                                              const float* __restrict__ wbuf,
                                              unsigned short* __restrict__ vec96b) {
  const int w = threadIdx.x >> 6, lane = threadIdx.x & 63;
  const int g = lane >> 4, f = lane & 15;
  const int node = blockIdx.x * 4 + w;
  const int start = rowptr[node], end = rowptr[node + 1];
  const int cnt = end - start;
  const float c0 = wbuf[OFF_C0 + f],      c1v = wbuf[OFF_C0 + 16 + f];
  const float c2v = wbuf[OFF_C0 + 32 + f], c3v = wbuf[OFF_C0 + 48 + f];
  float s = 0.f, sq = 0.f, mx = -__builtin_inff(), mn = __builtin_inff();
  int p = start + g;
  for (; p + 4 < end; p += 8) {
    int s0 = col[p], s1 = col[p + 4];
    ushort4 e0 = eapb[p], e1 = eapb[p + 4];
    float v0 = bf_s(xB0b[(size_t)s0 * 16 + f]);
    float v1 = bf_s(xB0b[(size_t)s1 * 16 + f]);
    v0 = fmaf(bf_s(e0.x), c0, v0); v0 = fmaf(bf_s(e0.y), c1v, v0);
    v0 = fmaf(bf_s(e0.z), c2v, v0); v0 = fmaf(bf_s(e0.w), c3v, v0);
    v1 = fmaf(bf_s(e1.x), c0, v1); v1 = fmaf(bf_s(e1.y), c1v, v1);
    v1 = fmaf(bf_s(e1.z), c2v, v1); v1 = fmaf(bf_s(e1.w), c3v, v1);
    s += v0 + v1;
    sq = fmaf(v0, v0, sq); sq = fmaf(v1, v1, sq);
    mx = fmaxf(mx, fmaxf(v0, v1)); mn = fminf(mn, fminf(v0, v1));
  }
  for (; p < end; p += 4) {
    int si = col[p];
    ushort4 e0 = eapb[p];
    float v = bf_s(xB0b[(size_t)si * 16 + f]);
    v = fmaf(bf_s(e0.x), c0, v); v = fmaf(bf_s(e0.y), c1v, v);
    v = fmaf(bf_s(e0.z), c2v, v); v = fmaf(bf_s(e0.w), c3v, v);
    s += v; sq = fmaf(v, v, sq); mx = fmaxf(mx, v); mn = fminf(mn, v);
  }
  s  += __shfl_xor(s, 16);  s  += __shfl_xor(s, 32);
  sq += __shfl_xor(sq, 16); sq += __shfl_xor(sq, 32);
  mx = fmaxf(mx, __shfl_xor(mx, 16)); mx = fmaxf(mx, __shfl_xor(mx, 32));
  mn = fminf(mn, __shfl_xor(mn, 16)); mn = fminf(mn, __shfl_xor(mn, 32));
  const float c = xA0[(size_t)node * 16 + f] + wbuf[OFF_D0 + f];
  float sum_m, mean_m, mx_m, mn_m, std_m;
  if (cnt > 0) {
    float inv = 1.f / (float)cnt;
    float meanv = s * inv;
    sum_m = fmaf((float)cnt, c, s);
    mean_m = meanv + c;
    mx_m = mx + c; mn_m = mn + c;
    float var = fmaf(-meanv, meanv, sq * inv);
    std_m = sqrtf(fmaxf(var, 0.f) + 1e-5f);
  } else {
    sum_m = 0.f; mean_m = 0.f; mx_m = 0.f; mn_m = 0.f; std_m = sqrtf(1e-5f);
  }
  if (g == 0) {
    unsigned short* vr = vec96b + (size_t)node * 96;
    vr[f]      = pack_bf16(x[(size_t)node * 16 + f]);
    vr[16 + f] = pack_bf16(sum_m);
    vr[32 + f] = pack_bf16(mean_m);
    vr[48 + f] = pack_bf16(mx_m);
    vr[64 + f] = pack_bf16(mn_m);
    vr[80 + f] = pack_bf16(std_m);
  }
}

// ---------------- layer 1 aggregation: one node per 64-thread block ----------------
__global__ __launch_bounds__(64) void k_agg1(const unsigned short* __restrict__ xA1b,
                                             const unsigned short* __restrict__ xB1b,
                                             const int* __restrict__ rowptr,
                                             const int* __restrict__ col,
                                             const ushort4* __restrict__ eapb,
                                             const float* __restrict__ wbuf,
                                             unsigned short* __restrict__ agg320b) {
  const int f = threadIdx.x;            // 0..63
  const int node = blockIdx.x;
  const int start = rowptr[node], end = rowptr[node + 1];
  const int cnt = end - start;
  const float c0 = wbuf[OFF_C1 + f],       c1v = wbuf[OFF_C1 + 64 + f];
  const float c2v = wbuf[OFF_C1 + 128 + f], c3v = wbuf[OFF_C1 + 192 + f];
  float s = 0.f, sq = 0.f, mx = -__builtin_inff(), mn = __builtin_inff();
  int p = start;
  for (; p + 7 < end; p += 8) {
#pragma unroll
    for (int u = 0; u < 8; u++) {
      int si = col[p + u];                                   // scalar load
      ushort4 e = eapb[p + u];                               // scalar dwordx2
      const unsigned short* row = xB1b + (unsigned)si * 64;  // SALU base
      float v = bf_s(row[f]);                                // 128B coalesced gather
      v = fmaf(bf_s(e.x), c0, v); v = fmaf(bf_s(e.y), c1v, v);
      v = fmaf(bf_s(e.z), c2v, v); v = fmaf(bf_s(e.w), c3v, v);
      s += v; sq = fmaf(v, v, sq); mx = fmaxf(mx, v); mn = fminf(mn, v);
    }
  }
  for (; p < end; p++) {
    int si = col[p];
    ushort4 e = eapb[p];
    const unsigned short* row = xB1b + (unsigned)si * 64;
    float v = bf_s(row[f]);
    v = fmaf(bf_s(e.x), c0, v); v = fmaf(bf_s(e.y), c1v, v);
    v = fmaf(bf_s(e.z), c2v, v); v = fmaf(bf_s(e.w), c3v, v);
    s += v; sq = fmaf(v, v, sq); mx = fmaxf(mx, v); mn = fminf(mn, v);
  }
  const float c = bf_s(xA1b[(size_t)node * 64 + f]) + wbuf[OFF_D1 + f];
  float sum_m, mean_m, mx_m, mn_m, std_m;
  if (cnt > 0) {
    float inv = 1.f / (float)cnt;
    float meanv = s * inv;
    sum_m = fmaf((float)cnt, c, s);
    mean_m = meanv + c;
    mx_m = mx + c; mn_m = mn + c;
    float var = fmaf(-meanv, meanv, sq * inv);
    std_m = sqrtf(fmaxf(var, 0.f) + 1e-5f);
  } else {
    sum_m = 0.f; mean_m = 0.f; mx_m = 0.f; mn_m = 0.f; std_m = sqrtf(1e-5f);
  }
  unsigned short* ar = agg320b + (size_t)node * 320;
  ar[f]       = pack_bf16(sum_m);
  ar[64 + f]  = pack_bf16(mean_m);
  ar[128 + f] = pack_bf16(mx_m);
  ar[192 + f] = pack_bf16(mn_m);
  ar[256 + f] = pack_bf16(std_m);
}

// ---------------- MFMA GEMM: C[n,64] = (relu)(A[n,K]_bf16 @ Bt^T + bias) ----------------
template <int K, bool RELU, int OMODE>
__global__ __launch_bounds__(256) void k_mmf(const unsigned short* __restrict__ A,
                                             const unsigned short* __restrict__ Bt,
                                             const float* __restrict__ bias,
                                             void* __restrict__ C, int n) {
  using bf16x8 = __attribute__((ext_vector_type(8))) short;
  using f32x4  = __attribute__((ext_vector_type(4))) float;
  const int wave = threadIdx.x >> 6, lane = threadIdx.x & 63;
  const int qm = lane & 15, quad = lane >> 4;
  const int m0 = blockIdx.x * 64 + wave * 16;
  const int mrow = m0 + qm;
  f32x4 acc[4] = {};
#pragma unroll
  for (int k0 = 0; k0 < K; k0 += 32) {
    bf16x8 a = *(const bf16x8*)(A + (size_t)mrow * K + k0 + quad * 8);
#pragma unroll
    for (int nt = 0; nt < 4; nt++) {
      bf16x8 b = *(const bf16x8*)(Bt + (size_t)(nt * 16 + qm) * K + k0 + quad * 8);
      acc[nt] = __builtin_amdgcn_mfma_f32_16x16x32_bf16(a, b, acc[nt], 0, 0, 0);
    }
  }
#pragma unroll
  for (int nt = 0; nt < 4; nt++) {
    int colc = nt * 16 + qm;
    float bb = bias ? bias[colc] : 0.f;
#pragma unroll
    for (int r = 0; r < 4; r++) {
      int m = m0 + quad * 4 + r;
      if (m < n) {
        float v = acc[nt][r] + bb;
        if (RELU) v = fmaxf(v, 0.f);
        if (OMODE == 0) ((float*)C)[(size_t)m * 64 + colc] = v;
        else ((unsigned short*)C)[(size_t)m * 64 + colc] = pack_bf16(v);
      }
    }
  }
}

// ---------------- dual-B MFMA: xA1b + xB1b (both bf16) from one pass over hb ----------------
__global__ __launch_bounds__(256) void k_mmf64d(const unsigned short* __restrict__ A,
                                                const unsigned short* __restrict__ BtA,
                                                const unsigned short* __restrict__ BtB,
                                                unsigned short* __restrict__ xA1b,
                                                unsigned short* __restrict__ xB1b, int n) {
  using bf16x8 = __attribute__((ext_vector_type(8))) short;
  using f32x4  = __attribute__((ext_vector_type(4))) float;
  const int wave = threadIdx.x >> 6, lane = threadIdx.x & 63;
  const int qm = lane & 15, quad = lane >> 4;
  const int m0 = blockIdx.x * 64 + wave * 16;
  const int mrow = m0 + qm;
  f32x4 accA[4] = {}, accB[4] = {};
#pragma unroll
  for (int k0 = 0; k0 < 64; k0 += 32) {
    bf16x8 a = *(const bf16x8*)(A + (size_t)mrow * 64 + k0 + quad * 8);
#pragma unroll
    for (int nt = 0; nt < 4; nt++) {
      bf16x8 bA = *(const bf16x8*)(BtA + (size_t)(nt * 16 + qm) * 64 + k0 + quad * 8);
      bf16x8 bB = *(const bf16x8*)(BtB + (size_t)(nt * 16 + qm) * 64 + k0 + quad * 8);
      accA[nt] = __builtin_amdgcn_mfma_f32_16x16x32_bf16(a, bA, accA[nt], 0, 0, 0);
      accB[nt] = __builtin_amdgcn_mfma_f32_16x16x32_bf16(a, bB, accB[nt], 0, 0, 0);
    }
  }
#pragma unroll
  for (int nt = 0; nt < 4; nt++) {
    int colc = nt * 16 + qm;
#pragma unroll
    for (int r = 0; r < 4; r++) {
      int m = m0 + quad * 4 + r;
      if (m < n) {
        xA1b[(size_t)m * 64 + colc] = pack_bf16(accA[nt][r]);
        xB1b[(size_t)m * 64 + colc] = pack_bf16(accB[nt][r]);
      }
    }
  }
}

// ---------------- fused: h2 = relu([hb|aggb]@Bt1^T + bias); hgsb = bf16((h2@Wg)*dinv) ----
__global__ __launch_bounds__(256) void k_mm384g(const unsigned short* __restrict__ hb,
                                                const unsigned short* __restrict__ aggb,
                                                const unsigned short* __restrict__ Bt1,
                                                const float* __restrict__ wbuf,
                                                const float* __restrict__ Wg,
                                                const int* __restrict__ rowptr,
                                                unsigned short* __restrict__ hgsb,
                                                float* __restrict__ dinv, int n) {
  using bf16x8 = __attribute__((ext_vector_type(8))) short;
  using f32x4  = __attribute__((ext_vector_type(4))) float;
  __shared__ float h2t[4][16][65];     // padded: stride 65 breaks bank conflicts
  __shared__ float wg[64][16];
  const int tid = threadIdx.x;
  for (int i = tid; i < 1024; i += 256) wg[i >> 4][i & 15] = Wg[i];
  const int wave = tid >> 6, lane = tid & 63;
  const int qm = lane & 15, quad = lane >> 4;
  const int m0 = blockIdx.x * 64 + wave * 16;
  const int mrow = m0 + qm;
  f32x4 acc[4] = {};
  for (int k0 = 0; k0 < 384; k0 += 32) {
    bf16x8 a;
    if (k0 < 64) a = *(const bf16x8*)(hb + (size_t)mrow * 64 + k0 + quad * 8);
    else         a = *(const bf16x8*)(aggb + (size_t)mrow * 320 + (k0 - 64) + quad * 8);
#pragma unroll
    for (int nt = 0; nt < 4; nt++) {
      bf16x8 b = *(const bf16x8*)(Bt1 + (size_t)(nt * 16 + qm) * 384 + k0 + quad * 8);
      acc[nt] = __builtin_amdgcn_mfma_f32_16x16x32_bf16(a, b, acc[nt], 0, 0, 0);
    }
  }
#pragma unroll
  for (int nt = 0; nt < 4; nt++) {
    int colc = nt * 16 + qm;
    float bias = wbuf[OFF_BPL1 + colc];
#pragma unroll
    for (int r = 0; r < 4; r++)
      h2t[wave][quad * 4 + r][colc] = fmaxf(acc[nt][r] + bias, 0.f);
  }
  __syncthreads();
  const int row = lane & 15, g = lane >> 4;
  float hg0 = 0.f, hg1 = 0.f, hg2 = 0.f, hg3 = 0.f;
#pragma unroll 16
  for (int j = 0; j < 64; j++) {
    float hv = h2t[wave][row][j];
    float4 w4 = *(const float4*)&wg[j][g * 4];
    hg0 = fmaf(hv, w4.x, hg0); hg1 = fmaf(hv, w4.y, hg1);
    hg2 = fmaf(hv, w4.z, hg2); hg3 = fmaf(hv, w4.w, hg3);
  }
  int m = m0 + row;
  if (m < n) {
    int deg = rowptr[m + 1] - rowptr[m] + 1;   // +1 self loop
    float dv = 1.0f / sqrtf((float)deg);
    if (g == 0) dinv[m] = dv;
    ushort4 pk;
    pk.x = pack_bf16(hg0 * dv); pk.y = pack_bf16(hg1 * dv);
    pk.z = pack_bf16(hg2 * dv); pk.w = pack_bf16(hg3 * dv);
    *(ushort4*)(hgsb + (size_t)m * 16 + g * 4) = pk;
  }
}

// ---------------- GCN aggregate + MLP head ----------------
__global__ __launch_bounds__(256) void k_head(const float* __restrict__ x,
                                              const unsigned short* __restrict__ hgsb,
                                              const float* __restrict__ dinv,
                                              const int* __restrict__ rowptr,
                                              const int* __restrict__ col,
                                              const float* __restrict__ bg,
                                              const float* __restrict__ Wh1,
                                              const float* __restrict__ bh1,
                                              const float* __restrict__ Wh2,
                                              const float* __restrict__ bh2,
                                              float* __restrict__ out) {
  __shared__ float zb[4][32];
  __shared__ float o1b[4][10];
  const int w = threadIdx.x >> 6, lane = threadIdx.x & 63;
  const int g = lane >> 4, f = lane & 15;
  const int node = blockIdx.x * 4 + w;
  const int start = rowptr[node], end = rowptr[node + 1];
  float s = 0.f;
  int p = start + g;
  for (; p + 12 < end; p += 16) {
    int s0 = col[p], s1 = col[p + 4], s2 = col[p + 8], s3 = col[p + 12];
    float v0 = bf_s(hgsb[(size_t)s0 * 16 + f]);
    float v1 = bf_s(hgsb[(size_t)s1 * 16 + f]);
    float v2 = bf_s(hgsb[(size_t)s2 * 16 + f]);
    float v3 = bf_s(hgsb[(size_t)s3 * 16 + f]);
    s += (v0 + v1) + (v2 + v3);
  }
  for (; p < end; p += 4) {
    int si = col[p];
    s += bf_s(hgsb[(size_t)si * 16 + f]);
  }
  s += __shfl_xor(s, 16); s += __shfl_xor(s, 32);
  if (g == 0) {
    float gout = (s + bf_s(hgsb[(size_t)node * 16 + f])) * dinv[node] + bg[f];
    zb[w][f] = gout;
    zb[w][16 + f] = x[(size_t)node * 16 + f];
  }
  __syncthreads();
  if (lane < 10) {
    float a = bh1[lane];
#pragma unroll
    for (int k = 0; k < 32; k++) a = fmaf(zb[w][k], Wh1[k * 10 + lane], a);
    o1b[w][lane] = fmaxf(a, 0.f);
  }
  __syncthreads();
  if (lane < 10) {
    float a = bh2[lane];
#pragma unroll
    for (int j = 0; j < 10; j++) a = fmaf(o1b[w][j], Wh2[j * 10 + lane], a);
    out[(size_t)node * 10 + lane] = a;
  }
}

// ---------------- launcher ----------------
extern "C" void kernel_launch(void* const* d_in, const int* in_sizes, int n_in,
                              void* d_out, int out_size, void* d_ws, size_t ws_size,
                              hipStream_t stream) {
  const float* x      = (const float*)d_in[0];
  const int*   ei     = (const int*)d_in[1];
  const float* eattr  = (const float*)d_in[2];
  const float* We0    = (const float*)d_in[3];
  const float* be0    = (const float*)d_in[4];
  const float* Wpre0  = (const float*)d_in[5];
  const float* bpre0  = (const float*)d_in[6];
  const float* Wpost0 = (const float*)d_in[7];
  const float* bpost0 = (const float*)d_in[8];
  const float* Wlin0  = (const float*)d_in[9];
  const float* blin0  = (const float*)d_in[10];
  const float* We1    = (const float*)d_in[11];
  const float* be1    = (const float*)d_in[12];
  const float* Wpre1  = (const float*)d_in[13];
  const float* bpre1  = (const float*)d_in[14];
  const float* Wpost1 = (const float*)d_in[15];
  const float* bpost1 = (const float*)d_in[16];
  const float* Wlin1  = (const float*)d_in[17];
  const float* blin1  = (const float*)d_in[18];
  const float* Wg     = (const float*)d_in[19];
  const float* bg     = (const float*)d_in[20];
  const float* Wh1    = (const float*)d_in[21];
  const float* bh1    = (const float*)d_in[22];
  const float* Wh2    = (const float*)d_in[23];
  const float* bh2    = (const float*)d_in[24];
  const int* srcI = ei;
  const int* dstI = ei + NE;
  float* out = (float*)d_out;

  char* base = (char*)d_ws;
  size_t off = 0;
  auto take = [&](size_t bytes) -> char* {
    char* p = base + off;
    off += (bytes + 255) & ~(size_t)255;
    return p;
  };
  int* rowptr  = (int*)take((size_t)(NN + 1) * 4);
  int* bcnt    = (int*)take(256 * 4);
  int* gbase   = (int*)take(256 * 4);
  int* gfill   = (int*)take(256 * 4);
  unsigned short* Bt = (unsigned short*)take((size_t)BT_TOT * 2);
  int* col     = (int*)take((size_t)NE * 4);          // 6.4MB
  ushort4* eapb = (ushort4*)take((size_t)NE * 8);     // 12.8MB
  float* wbuf  = (float*)take((size_t)WBUF_TOT * 4);
  // rec16 (25.6MB) dies after scatter2b; xA1b/xB1b overlay it afterwards
  char* recbuf = take((size_t)NE * 16);
  int4* rec    = (int4*)recbuf;
  unsigned short* xA1b = (unsigned short*)recbuf;                       // 12.8MB
  unsigned short* xB1b = (unsigned short*)(recbuf + (size_t)NN * 64 * 2); // 12.8MB
  // region Z (128MB): vec96b/xA0/xB0b early -> agg320b [0,64) mid;
  // hgsb/dinv at +64MB (written by mm384g); hb at +96MB.
  char* Z = take((size_t)NN * 320 * 4);
  unsigned short* vec96b  = (unsigned short*)Z;                         // 19.2MB
  float* xA0    = (float*)(Z + (size_t)NN * 96 * 2);                    // 6.4MB
  unsigned short* xB0b = (unsigned short*)(Z + (size_t)NN * 96 * 2 + (size_t)NN * 16 * 4);
  unsigned short* agg320b = (unsigned short*)Z;                         // 64MB
  unsigned short* hgsb = (unsigned short*)(Z + (size_t)64 * 1024 * 1024); // 3.2MB
  float* dinv   = (float*)(Z + (size_t)64 * 1024 * 1024 + (size_t)NN * 16 * 2);
  unsigned short* hb = (unsigned short*)(Z + (size_t)96 * 1024 * 1024); // 12.8MB

  hipMemsetAsync(bcnt, 0, 256 * 4, stream);
  k_prep<<<(PREP_TOT + 255) / 256, 256, 0, stream>>>(
      We0, be0, Wpre0, bpre0, Wpost0, bpost0, Wlin0, blin0,
      We1, be1, Wpre1, bpre1, Wpost1, bpost1, Wlin1, blin1, wbuf, Bt);
  k_bcnt<<<256, 256, 0, stream>>>(dstI, bcnt);
  k_bscan<<<1, 256, 0, stream>>>(bcnt, gbase, gfill);
  k_bin16<<<256, 256, 0, stream>>>(dstI, srcI, (const float4*)eattr, gfill, rec);
  k_scatter2b<<<NB, 256, 0, stream>>>(rec, gbase, rowptr, col, eapb);
  k_pre0<<<NN * 32 / 256, 256, 0, stream>>>(x, Wpre0, xA0, xB0b);
  k_agg0<<<NN / 4, 256, 0, stream>>>(x, xA0, xB0b, rowptr, col, eapb, wbuf, vec96b);
  k_mmf<96, true, 1><<<(NN + 63) / 64, 256, 0, stream>>>(
      vec96b, Bt + BT0_OFF, wbuf + OFF_BPL0, hb, NN);
  k_mmf64d<<<(NN + 63) / 64, 256, 0, stream>>>(
      hb, Bt + BTA_OFF, Bt + BTB_OFF, xA1b, xB1b, NN);
  k_agg1<<<NN, 64, 0, stream>>>(xA1b, xB1b, rowptr, col, eapb, wbuf, agg320b);
  k_mm384g<<<(NN + 63) / 64, 256, 0, stream>>>(
      hb, agg320b, Bt + BT1_OFF, wbuf, Wg, rowptr, hgsb, dinv, NN);
  k_head<<<NN / 4, 256, 0, stream>>>(x, hgsb, dinv, rowptr, col, bg, Wh1, bh1,
                                     Wh2, bh2, out);
}